// Round 5
// baseline (1483.583 us; speedup 1.0000x reference)
//
#include <hip/hip_runtime.h>
#include <math.h>

// ---- problem constants ----
static constexpr int CB   = 64;      // groups
static constexpr int CH   = 8;       // heads
static constexpr int CEH  = 16;      // per-head dim
static constexpr int CHD  = 128;     // hidden dim
static constexpr int CNDA = 100000;
static constexpr int CNQ  = 20000;
static constexpr int CEDA = 1000000;
static constexpr int CEQ  = 200000;
static constexpr float CEPS = 1e-5f;
static constexpr float CSLOPE = 2.0f;

typedef unsigned short ushortt;
typedef __attribute__((ext_vector_type(8))) short bf16x8;
typedef __attribute__((ext_vector_type(4))) float f32x4;

// ---------- bf16 helpers ----------
__device__ __forceinline__ float ldf(const float* p) { return *p; }
__device__ __forceinline__ float ldf(const ushortt* p) {
  return __uint_as_float(((unsigned)*p) << 16);
}
__device__ __forceinline__ void stf(float* p, float v) { *p = v; }
__device__ __forceinline__ void stf(ushortt* p, float v) {
  unsigned u = __float_as_uint(v);
  u += 0x7fff + ((u >> 16) & 1);  // RNE
  *p = (ushortt)(u >> 16);
}
__device__ __forceinline__ short f2bf(float v) {
  unsigned u = __float_as_uint(v);
  u += 0x7fff + ((u >> 16) & 1);
  return (short)(u >> 16);
}
__device__ __forceinline__ float bf2f(short b) {
  return __uint_as_float(((unsigned)(ushortt)b) << 16);
}

// ---------- utility ----------
__global__ void k_zero(float* __restrict__ p, long n) {
  long i = (long)blockIdx.x * blockDim.x + threadIdx.x;
  long stride = (long)gridDim.x * blockDim.x;
  for (; i < n; i += stride) p[i] = 0.f;
}
static inline void zero_launch(void* p, long n, hipStream_t s) {
  long b = (n + 255) / 256;
  int blocks = (int)(b > 4096 ? 4096 : (b < 1 ? 1 : b));
  hipLaunchKernelGGL(k_zero, dim3(blocks), dim3(256), 0, s, (float*)p, n);
}

// ---------- group boundaries (gid sorted) ----------
__global__ void k_binit(int* start, int n) {
  int i = threadIdx.x;
  if (i <= CB) start[i] = n;
}
__global__ void k_bmark(const int* __restrict__ gid, int n, int* __restrict__ start) {
  int i = blockIdx.x * blockDim.x + threadIdx.x;
  if (i >= n) return;
  int g = gid[i];
  if (i == 0 || gid[i - 1] != g) atomicMin(&start[g], i);
}
__global__ void k_bfix(int* start) {
  if (threadIdx.x == 0) {
    for (int g = CB - 1; g >= 0; --g)
      if (start[g] > start[g + 1]) start[g] = start[g + 1];
  }
}

// ---------- gate dot (one gate) ----------
__global__ void k_gate_dot(const float* __restrict__ feat, const float* __restrict__ gw,
                           const float* __restrict__ gb, float* __restrict__ g, int n) {
  int wave = (blockIdx.x * blockDim.x + threadIdx.x) >> 6;
  int lane = threadIdx.x & 63;
  if (wave >= n) return;
  const float* row = feat + (size_t)wave * CHD;
  float v = row[lane] * gw[lane] + row[lane + 64] * gw[lane + 64];
  for (int off = 32; off > 0; off >>= 1) v += __shfl_down(v, off, 64);
  if (lane == 0) g[wave] = v + gb[0];
}

// ---------- gate dot (two gates, shared feat read) ----------
__global__ void k_gate_dot2(const float* __restrict__ feat,
                            const float* __restrict__ w1, const float* __restrict__ b1,
                            const float* __restrict__ w2, const float* __restrict__ b2,
                            float* __restrict__ g1, float* __restrict__ g2, int n) {
  int wave = (blockIdx.x * blockDim.x + threadIdx.x) >> 6;
  int lane = threadIdx.x & 63;
  if (wave >= n) return;
  const float* row = feat + (size_t)wave * CHD;
  float r0 = row[lane], r1 = row[lane + 64];
  float v1 = r0 * w1[lane] + r1 * w1[lane + 64];
  float v2 = r0 * w2[lane] + r1 * w2[lane + 64];
  for (int off = 32; off > 0; off >>= 1) {
    v1 += __shfl_down(v1, off, 64);
    v2 += __shfl_down(v2, off, 64);
  }
  if (lane == 0) {
    g1[wave] = v1 + b1[0];
    g2[wave] = v2 + b2[0];
  }
}

// ---------- GAP phase 1: per-group max of g, all 5 jobs in one launch ----------
__global__ void k_gmax5(const float* __restrict__ gq, const int* __restrict__ startq,
                        const int* __restrict__ startda, float* __restrict__ m) {
  int job = blockIdx.x >> 6, grp = blockIdx.x & 63;
  const float* g;
  const int* start;
  if (job == 0)      { g = gq;                              start = startq; }
  else if (job == 1) { g = gq + 2 * (size_t)CNQ;            start = startq; }   // g2q
  else if (job == 2) { g = gq + (size_t)CNQ;                start = startq; }   // g1q
  else if (job == 3) { g = gq + 3 * (size_t)CNQ;            start = startda; }  // g1da
  else               { g = gq + 3 * (size_t)CNQ + CNDA;     start = startda; }  // g2da
  int s0 = start[grp], s1 = start[grp + 1];
  int t = threadIdx.x;  // 256
  __shared__ float red[256];
  float v = -1e30f;
  for (int i = s0 + t; i < s1; i += 256) v = fmaxf(v, g[i]);
  red[t] = v;
  __syncthreads();
  for (int o = 128; o > 0; o >>= 1) {
    if (t < o) red[t] = fmaxf(red[t], red[t + o]);
    __syncthreads();
  }
  if (t == 0) m[job * 64 + grp] = red[0];
}

// ---------- GAP phase 2: partial weighted sums (grid = groups x chunks) ----------
template <int NG>
__global__ __launch_bounds__(128) void k_gap_partial(
    const float* __restrict__ g0, const float* __restrict__ g1,
    const float* __restrict__ feat, const int* __restrict__ start,
    const float* __restrict__ m,
    float* __restrict__ acc0, float* __restrict__ acc1,
    float* __restrict__ sums) {
  int grp = blockIdx.x;
  int s0 = start[grp], s1 = start[grp + 1];
  int len = s1 - s0;
  if (len <= 0) return;
  int NC = gridDim.y;
  int per = (len + NC - 1) / NC;
  int r0 = s0 + blockIdx.y * per;
  int r1 = min(s1, r0 + per);
  if (r0 >= r1) return;
  int t = threadIdx.x;  // 128 = column
  float m0 = m[grp];
  float m1 = (NG == 2) ? m[64 + grp] : 0.f;
  float a0 = 0.f, a1 = 0.f, sum0 = 0.f, sum1 = 0.f;
  for (int i = r0; i < r1; ++i) {
    float f = feat[(size_t)i * CHD + t];
    float e0 = expf(g0[i] - m0);
    sum0 += e0;
    a0 += e0 * f;
    if (NG == 2) {
      float e1 = expf(g1[i] - m1);
      sum1 += e1;
      a1 += e1 * f;
    }
  }
  atomicAdd(&acc0[grp * CHD + t], a0);
  if (NG == 2) atomicAdd(&acc1[grp * CHD + t], a1);
  if (t == 0) {
    atomicAdd(&sums[grp], sum0);
    if (NG == 2) atomicAdd(&sums[64 + grp], sum1);
  }
}

// ---------- GAP phase 3: normalize, all 5 jobs in one launch ----------
__global__ void k_gap_norm5(float* __restrict__ glq, const float* __restrict__ sbuf) {
  int job = blockIdx.x >> 6, grp = blockIdx.x & 63;
  int t = threadIdx.x;  // 128
  int smap = (job == 1) ? 2 : ((job == 2) ? 1 : job);
  float sv = sbuf[smap * 64 + grp];
  float* acc = glq + (size_t)job * CB * CHD + grp * CHD;
  float v = acc[t];
  acc[t] = (sv > 0.f) ? v / sv : 0.f;
}

// ---------- small matmul ----------
__global__ void k_mm_small(const float* __restrict__ X, const float* __restrict__ W,
                           const float* __restrict__ bias, float* __restrict__ Y,
                           int m, int k, int p) {
  int idx = blockIdx.x * blockDim.x + threadIdx.x;
  if (idx >= m * p) return;
  int r = idx / p, c = idx % p;
  float acc = bias[c];
  for (int kk = 0; kk < k; ++kk) acc += X[r * k + kk] * W[kk * p + c];
  Y[idx] = acc;
}

// ---------- BN+elu small ----------
__global__ void k_bn_elu_small(float* __restrict__ Y, int m, int p) {
  int c = blockIdx.x * blockDim.x + threadIdx.x;
  if (c >= p) return;
  float s = 0.f, s2 = 0.f;
  for (int i = 0; i < m; ++i) {
    float v = Y[i * p + c];
    s += v; s2 += v * v;
  }
  float mu = s / m;
  float var = s2 / m - mu * mu;
  float inv = rsqrtf(var + CEPS);
  for (int i = 0; i < m; ++i) {
    float v = (Y[i * p + c] - mu) * inv;
    Y[i * p + c] = v > 0.f ? v : expm1f(v);
  }
}

// ---------- att_comb ----------
__global__ void k_attcomb(const float* __restrict__ k1, const float* __restrict__ k2,
                          const float* __restrict__ Qc, float* __restrict__ a) {
  int grp = blockIdx.x;
  int t = threadIdx.x;  // 64 threads
  float v1 = Qc[t] * k1[grp * CHD + t] + Qc[t + 64] * k1[grp * CHD + t + 64];
  float v2 = Qc[t] * k2[grp * CHD + t] + Qc[t + 64] * k2[grp * CHD + t + 64];
  for (int off = 32; off > 0; off >>= 1) {
    v1 += __shfl_down(v1, off, 64);
    v2 += __shfl_down(v2, off, 64);
  }
  if (t == 0) {
    float mx = fmaxf(v1, v2);
    float e1 = expf(v1 - mx), e2 = expf(v2 - mx);
    float s = e1 + e2;
    a[grp * 2] = e1 / s;
    a[grp * 2 + 1] = e2 / s;
  }
}

// ---------- WQ precompute ----------
__global__ void k_wq(const float* __restrict__ W_L, const float* __restrict__ b_L,
                     const float* __restrict__ Qm, float* __restrict__ WQ,
                     float* __restrict__ bQ) {
  int g = blockIdx.x;  // 64 blocks, 256 threads
  int t = threadIdx.x;
  for (int j = 0; j < 8; ++j) {
    int idx = t + j * 256;
    int d = idx >> 4, c = idx & 15;
    int h = c & 7, off = (c >= 8) ? CEH : 0;
    const float* w = W_L + d * CHD + h * CEH;
    const float* q = Qm + g * 256 + h * 32 + off;
    float acc = 0.f;
#pragma unroll
    for (int e = 0; e < CEH; ++e) acc += w[e] * q[e];
    WQ[g * 2048 + idx] = acc;
  }
  if (t < 16) {
    int c = t, h = c & 7, off = (c >= 8) ? CEH : 0;
    const float* b = b_L + h * CEH;
    const float* q = Qm + g * 256 + h * 32 + off;
    float acc = 0.f;
#pragma unroll
    for (int e = 0; e < CEH; ++e) acc += b[e] * q[e];
    bQ[g * 16 + c] = acc;
  }
}

// ---------- elr ----------
__global__ void k_eler(const float* __restrict__ tmp, const float* __restrict__ WQ,
                       const float* __restrict__ bQ, const int* __restrict__ gid,
                       float* __restrict__ elr, int n) {
  int idx = blockIdx.x * blockDim.x + threadIdx.x;
  if (idx >= n * 16) return;
  int i = idx >> 4, c = idx & 15;
  int g = gid[i];
  const float* wq = WQ + g * 2048 + c;
  const float* row = tmp + (size_t)i * CHD;
  float acc = bQ[g * 16 + c];
#pragma unroll 4
  for (int d = 0; d < CHD; ++d) acc += row[d] * wq[d * 16];
  elr[idx] = acc;
}

// ---------- transpose+cast weights: WT[p][k] = bf16(W[k][p]) ----------
__global__ void k_tcast(const float* __restrict__ W, ushortt* __restrict__ WT,
                        int K, int P) {
  int i = blockIdx.x * blockDim.x + threadIdx.x;
  if (i >= K * P) return;
  int p = i / K, k = i % K;
  stf(&WT[i], W[(size_t)k * P + p]);
}

// ---------- BN prep: stats -> mu / inv ----------
template <int P>
__global__ void k_bn_prep(const float* __restrict__ stats, float* __restrict__ pr, int n) {
  int c = threadIdx.x;
  if (c >= P) return;
  float invn = 1.f / (float)n;
  float mu = stats[c] * invn;
  float var = stats[P + c] * invn - mu * mu;
  pr[c] = mu;
  pr[P + c] = rsqrtf(var + CEPS);
}

// ---------- stats reduce: fold per-wave partials into stats (16 atomics/addr) ----------
template <int TP>
__global__ void k_stats_reduce(const float* __restrict__ pstat, float* __restrict__ stats,
                               int nb) {
  int c = blockIdx.x * blockDim.x + threadIdx.x;
  if (c >= TP) return;
  int NC = gridDim.y;
  int per = (nb + NC - 1) / NC;
  int r0 = blockIdx.y * per;
  int r1 = min(nb, r0 + per);
  float s = 0.f;
  for (int r = r0; r < r1; ++r) s += pstat[(size_t)r * TP + c];
  atomicAdd(&stats[c], s);
}

// ---------- MFMA GEMM: Y(nxP) = X(nxK) @ B + bias; BT is PxK bf16 ----------
// XM: 0 = fp32 plain, 1 = fp32 comb (a0*X0 + a1*X1), 2 = bf16 plain,
//     3 = bf16 with fused BN(mu/inv)+elu on load
// STATS: epilogue writes per-WAVE column sum/sumsq partials to pstat[(bid*4+wave)*2P..]
template <int K, int P, int XM, bool STATS, typename OT>
__global__ __launch_bounds__(256, 2) void k_gemm_mfma(
    const void* __restrict__ X0v, const void* __restrict__ X1v,
    const float* __restrict__ acomb, const int* __restrict__ gid,
    const float* __restrict__ bnmu, const float* __restrict__ bninv,
    const ushortt* __restrict__ BT, const float* __restrict__ bias,
    OT* __restrict__ Y, float* __restrict__ pstat, int n) {
  constexpr int NT = P / 16;
  const int wave = threadIdx.x >> 6, lane = threadIdx.x & 63;
  const int quad = lane >> 4, l16 = lane & 15;
  const int r0w = blockIdx.x * 64 + wave * 16;
  const int rA = r0w + l16;
  const bool rowok = rA < n;
  f32x4 acc[NT];
#pragma unroll
  for (int t = 0; t < NT; ++t) acc[t] = f32x4{0.f, 0.f, 0.f, 0.f};
  float a0 = 0.f, a1 = 0.f;
  if (XM == 1 && rowok) {
    int g = gid[rA];
    a0 = acomb[2 * g];
    a1 = acomb[2 * g + 1];
  }
  for (int k0 = 0; k0 < K; k0 += 32) {
    const int kk = k0 + quad * 8;
    bf16x8 af = {};
    if (rowok) {
      if constexpr (XM == 2) {
        af = *(const bf16x8*)((const ushortt*)X0v + (size_t)rA * K + kk);
      } else if constexpr (XM == 3) {
        bf16x8 raw = *(const bf16x8*)((const ushortt*)X0v + (size_t)rA * K + kk);
#pragma unroll
        for (int j = 0; j < 8; ++j) {
          float v = bf2f(raw[j]);
          v = (v - bnmu[kk + j]) * bninv[kk + j];
          v = v > 0.f ? v : (__expf(v) - 1.f);
          af[j] = f2bf(v);
        }
      } else {
        const float* px = (const float*)X0v + (size_t)rA * K + kk;
        float v[8];
        if constexpr (XM == 1) {
          const float* py = (const float*)X1v + (size_t)rA * K + kk;
#pragma unroll
          for (int j = 0; j < 8; ++j) v[j] = a0 * px[j] + a1 * py[j];
        } else {
#pragma unroll
          for (int j = 0; j < 8; ++j) v[j] = px[j];
        }
#pragma unroll
        for (int j = 0; j < 8; ++j) af[j] = f2bf(v[j]);
      }
    }
    // batch-load all B fragments (keeps NT loads in flight), then MFMA
    bf16x8 bfr[NT];
#pragma unroll
    for (int t = 0; t < NT; ++t)
      bfr[t] = *(const bf16x8*)(BT + (size_t)(t * 16 + l16) * K + kk);
#pragma unroll
    for (int t = 0; t < NT; ++t)
      acc[t] = __builtin_amdgcn_mfma_f32_16x16x32_bf16(af, bfr[t], acc[t], 0, 0, 0);
  }
  float* pw = STATS ? (pstat + ((size_t)blockIdx.x * 4 + wave) * (2 * P)) : nullptr;
#pragma unroll
  for (int t = 0; t < NT; ++t) {
    const int c = t * 16 + l16;
    float b = bias[c];
    float s = 0.f, s2 = 0.f;
#pragma unroll
    for (int r = 0; r < 4; ++r) {
      int gr = r0w + quad * 4 + r;
      if (gr < n) {
        float val = acc[t][r] + b;
        stf(Y + (size_t)gr * P + c, val);
        if constexpr (STATS) {
          float vq = (sizeof(OT) == 2) ? bf2f(f2bf(val)) : val;
          s += vq;
          s2 += vq * vq;
        }
      }
    }
    if constexpr (STATS) {
      s += __shfl_xor(s, 16, 64);
      s += __shfl_xor(s, 32, 64);
      s2 += __shfl_xor(s2, 16, 64);
      s2 += __shfl_xor(s2, 32, 64);
      if (quad == 0) {
        pw[c] = s;
        pw[P + c] = s2;
      }
    }
  }
}

// ---------- CSR build ----------
__global__ void k_count(const int* __restrict__ dst, int* __restrict__ counts, int E) {
  int e = blockIdx.x * blockDim.x + threadIdx.x;
  if (e < E) atomicAdd(&counts[dst[e]], 1);
}
__global__ void k_scan_reduce(const int* __restrict__ counts, int* __restrict__ bsum, int n) {
  __shared__ int red[256];
  int t = threadIdx.x;
  int base = blockIdx.x * 1024;
  int s = 0;
  for (int j = 0; j < 4; ++j) {
    int i = base + t * 4 + j;
    if (i < n) s += counts[i];
  }
  red[t] = s;
  __syncthreads();
  for (int o = 128; o > 0; o >>= 1) {
    if (t < o) red[t] += red[t + o];
    __syncthreads();
  }
  if (t == 0) bsum[blockIdx.x] = red[0];
}
__global__ void k_scan_top(int* __restrict__ bsum, int nb) {
  __shared__ int sh[128];
  int t = threadIdx.x;  // 128 threads
  int v = (t < nb) ? bsum[t] : 0;
  sh[t] = v;
  __syncthreads();
  for (int o = 1; o < 128; o <<= 1) {
    int x = (t >= o) ? sh[t - o] : 0;
    __syncthreads();
    sh[t] += x;
    __syncthreads();
  }
  if (t < nb) bsum[t] = sh[t] - v;  // exclusive
}
__global__ void k_scan_final(const int* __restrict__ counts, const int* __restrict__ bsum,
                             int* __restrict__ rowptr, int n, int E) {
  __shared__ int sh[256];
  int t = threadIdx.x;
  int base = blockIdx.x * 1024;
  int v[4];
  int s = 0;
  for (int j = 0; j < 4; ++j) {
    int i = base + t * 4 + j;
    v[j] = (i < n) ? counts[i] : 0;
    s += v[j];
  }
  sh[t] = s;
  __syncthreads();
  for (int o = 1; o < 256; o <<= 1) {
    int x = (t >= o) ? sh[t - o] : 0;
    __syncthreads();
    sh[t] += x;
    __syncthreads();
  }
  int off = bsum[blockIdx.x] + sh[t] - s;
  for (int j = 0; j < 4; ++j) {
    int i = base + t * 4 + j;
    if (i < n) rowptr[i] = off;
    off += v[j];
  }
  if (blockIdx.x == 0 && t == 0) rowptr[n] = E;
}
__global__ void k_copy_int(const int* __restrict__ a, int* __restrict__ b, int n) {
  int i = blockIdx.x * blockDim.x + threadIdx.x;
  if (i < n) b[i] = a[i];
}
__global__ void k_scatter(const int* __restrict__ dst, const int* __restrict__ srcA,
                          int* __restrict__ cursor, int* __restrict__ csr_src, int E) {
  int e = blockIdx.x * blockDim.x + threadIdx.x;
  if (e >= E) return;
  int d = dst[e];
  int pos = atomicAdd(&cursor[d], 1);
  csr_src[pos] = srcA[e];
}

// ---------- fused softmax aggregation: one wave per node ----------
__global__ __launch_bounds__(256) void k_node_agg(
    const int* __restrict__ rowptr, const int* __restrict__ csr_src,
    const float* __restrict__ elr, const ushortt* __restrict__ ft,
    float* __restrict__ agg, float* __restrict__ mOut, float* __restrict__ sOut, int n) {
  int node = blockIdx.x * 4 + (threadIdx.x >> 6);
  if (node >= n) return;
  int lane = threadIdx.x & 63;
  int h_p = lane & 7;    // head for p-compute role
  int e_loc = lane >> 3; // edge slot (0..7)
  int h_a = lane >> 3;   // head for accumulation role (cols 2*lane, 2*lane+1)
  int s0 = rowptr[node], s1 = rowptr[node + 1];
  if (s1 <= s0) {
    *(float2*)(agg + (size_t)node * CHD + lane * 2) = make_float2(0.f, 0.f);
    if (lane < 8) {
      mOut[(size_t)node * CH + lane] = -1e30f;
      sOut[(size_t)node * CH + lane] = 0.f;
    }
    return;
  }
  float erd_p = elr[(size_t)node * 16 + 8 + h_p];
  // ---- pass 1: max of el over in-edges, per head h_p ----
  float mx = -1e30f;
  for (int base = s0; base < s1; base += 8) {
    int e = base + e_loc;
    if (e < s1) {
      int sj = csr_src[e];
      mx = fmaxf(mx, elr[(size_t)sj * 16 + h_p]);
    }
  }
  mx = fmaxf(mx, __shfl_xor(mx, 8, 64));
  mx = fmaxf(mx, __shfl_xor(mx, 16, 64));
  mx = fmaxf(mx, __shfl_xor(mx, 32, 64));
  float xm = mx + erd_p;
  float m_p = xm >= 0.f ? xm : CSLOPE * xm;  // max of leaky(x) over edges
  // ---- pass 2: p = exp(x - m), weighted feature accumulation ----
  float s_part = 0.f, a0 = 0.f, a1 = 0.f;
  int base = s0;
  // full 8-edge batches: compile-time unrolled -> gather loads batched
  for (; base + 8 <= s1; base += 8) {
    int sj = csr_src[base + e_loc];
    float x = elr[(size_t)sj * 16 + h_p] + erd_p;
    x = x >= 0.f ? x : CSLOPE * x;
    float p = __expf(x - m_p);
    s_part += p;
#pragma unroll
    for (int e = 0; e < 8; ++e) {
      float pe = __shfl(p, e * 8 + h_a, 64);
      int se = __shfl(sj, e * 8, 64);
      unsigned ftv = *(const unsigned*)(ft + (size_t)se * CHD + lane * 2);
      a0 += pe * __uint_as_float(ftv << 16);
      a1 += pe * __uint_as_float(ftv & 0xffff0000u);
    }
  }
  // tail batch (guarded)
  if (base < s1) {
    int cnt = s1 - base;
    int sj = 0;
    float p = 0.f;
    if (e_loc < cnt) {
      sj = csr_src[base + e_loc];
      float x = elr[(size_t)sj * 16 + h_p] + erd_p;
      x = x >= 0.f ? x : CSLOPE * x;
      p = __expf(x - m_p);
      s_part += p;
    }
    for (int e = 0; e < cnt; ++e) {
      float pe = __shfl(p, e * 8 + h_a, 64);
      int se = __shfl(sj, e * 8, 64);
      unsigned ftv = *(const unsigned*)(ft + (size_t)se * CHD + lane * 2);
      a0 += pe * __uint_as_float(ftv << 16);
      a1 += pe * __uint_as_float(ftv & 0xffff0000u);
    }
  }
  s_part += __shfl_xor(s_part, 8, 64);
  s_part += __shfl_xor(s_part, 16, 64);
  s_part += __shfl_xor(s_part, 32, 64);
  float s_acc = __shfl(s_part, h_a, 64);  // lane h_a holds head h_p == h_a
  float inv = 1.f / s_acc;
  float2 o;
  o.x = a0 * inv;
  o.y = a1 * inv;
  *(float2*)(agg + (size_t)node * CHD + lane * 2) = o;
  if (lane < 8) {
    mOut[(size_t)node * CH + lane] = m_p;
    sOut[(size_t)node * CH + lane] = s_part;
  }
}

// ---------- BN apply + elu (+ residual) ----------
template <int P, bool RESID, typename T>
__global__ void k_bn_apply(T* __restrict__ Y, const float* __restrict__ stats,
                           const float* __restrict__ hlast, int n) {
  size_t idx = (size_t)blockIdx.x * blockDim.x + threadIdx.x;
  if (idx >= (size_t)n * P) return;
  int c = (int)(idx % P);
  float invn = 1.f / (float)n;
  float mu = stats[c] * invn;
  float var = stats[P + c] * invn - mu * mu;
  float v = (ldf(Y + idx) - mu) * rsqrtf(var + CEPS);
  v = v > 0.f ? v : expm1f(v);
  if (RESID) v += hlast[idx];
  stf(Y + idx, v);
}

// ---------- attention recompute for loss ----------
__device__ __forceinline__ float attn_val(int e, int h, const int* __restrict__ src,
                                          const int* __restrict__ dst,
                                          const float* __restrict__ elr,
                                          const float* __restrict__ mOut,
                                          const float* __restrict__ sOut) {
  int ss = src[e], sd = dst[e];
  float x = elr[(size_t)ss * 16 + h] + elr[(size_t)sd * 16 + 8 + h];
  x = x >= 0.f ? x : CSLOPE * x;
  return expf(x - mOut[(size_t)sd * CH + h]) / sOut[(size_t)sd * CH + h];
}

// per-block partials (no global atomics)
__global__ void k_pd(const int* __restrict__ src, const int* __restrict__ dst,
                     const float* __restrict__ elr, const float* __restrict__ mOut,
                     const float* __restrict__ sOut, const int* __restrict__ PEid,
                     const int* __restrict__ DEid, float* __restrict__ pdp,
                     int nPE, int nDE) {
  __shared__ float part[CH];
  if (threadIdx.x < CH) part[threadIdx.x] = 0.f;
  __syncthreads();
  int idx = blockIdx.x * blockDim.x + threadIdx.x;
  int j = idx >> 3, h = idx & 7;
  float acc = 0.f;
  if (j < nPE) acc += attn_val(PEid[j], h, src, dst, elr, mOut, sOut);
  if (j < nDE) acc -= attn_val(DEid[j], h, src, dst, elr, mOut, sOut);
  atomicAdd(&part[h], acc);
  __syncthreads();
  if (threadIdx.x < CH) pdp[(size_t)blockIdx.x * CH + threadIdx.x] = part[threadIdx.x];
}
__global__ void k_loss(const float* __restrict__ pdp, int nb,
                       const int* __restrict__ lenMn, float* __restrict__ out) {
  __shared__ float part[CH];
  int t = threadIdx.x;  // 256
  if (t < CH) part[t] = 0.f;
  __syncthreads();
  int h = t & 7;
  float acc = 0.f;
  for (int j = t >> 3; j < nb; j += 32) acc += pdp[(size_t)j * CH + h];
  atomicAdd(&part[h], acc);
  __syncthreads();
  if (t == 0) {
    float len = (float)lenMn[0];
    float s = 0.f;
    for (int hh = 0; hh < CH; ++hh) s += part[hh] / len;
    out[0] = -s / (float)CH;
  }
}

// ---------- branch driver ----------
static void run_branch(int n, int E, const float* h_last, const float* h0,
                       const int* src, const int* dst, const int* gid,
                       const float* acomb, const float* WQ, const float* bQ,
                       const ushortt* W_LT, const float* b_L,
                       const ushortt* W1T, const float* end_b1,
                       const ushortt* W2T, const float* end_b2,
                       float* U, float* elr, float* mOut, float* sOut,
                       int* counts, int* rowptr, int* cursor, int* csr_src, int* bsum,
                       float* stats /*1024: [0..511]=BN256, [512..1023]=BN128*/,
                       float* bnpr /*512*/, float* pstat, float* out, hipStream_t stream) {
  ushortt* ftB = (ushortt*)U;   // n x 128 bf16
  ushortt* y1B = (ushortt*)U;   // n x 256 bf16 (ft dead by then)
  float* stats1 = stats;
  float* stats2 = stats + 512;
  int nChunks = (n + 1023) / 1024;
  int nbG = (n + 63) / 64;      // gemm grid blocks
  int nbW = nbG * 4;            // per-wave stats partial rows
  // CSR build
  zero_launch(counts, n, stream);
  zero_launch(stats, 1024, stream);
  hipLaunchKernelGGL(k_count, dim3((E + 255) / 256), dim3(256), 0, stream, dst, counts, E);
  hipLaunchKernelGGL(k_scan_reduce, dim3(nChunks), dim3(256), 0, stream, counts, bsum, n);
  hipLaunchKernelGGL(k_scan_top, dim3(1), dim3(128), 0, stream, bsum, nChunks);
  hipLaunchKernelGGL(k_scan_final, dim3(nChunks), dim3(256), 0, stream, counts, bsum, rowptr, n, E);
  hipLaunchKernelGGL(k_copy_int, dim3((n + 255) / 256), dim3(256), 0, stream, rowptr, cursor, n);
  hipLaunchKernelGGL(k_scatter, dim3((E + 255) / 256), dim3(256), 0, stream, dst, src, cursor, csr_src, E);
  // elr
  hipLaunchKernelGGL(k_eler, dim3((n * 16 + 255) / 256), dim3(256), 0, stream,
                     h_last, WQ, bQ, gid, elr, n);
  // ft = (a0*h0 + a1*h_last) @ W_L + b_L -> bf16
  hipLaunchKernelGGL((k_gemm_mfma<128, 128, 1, false, ushortt>), dim3(nbG),
                     dim3(256), 0, stream, h0, h_last, acomb, gid,
                     (const float*)nullptr, (const float*)nullptr,
                     W_LT, b_L, ftB, (float*)nullptr, n);
  // fused softmax aggregation
  hipLaunchKernelGGL(k_node_agg, dim3((n + 3) / 4), dim3(256), 0, stream,
                     rowptr, csr_src, elr, ftB, out, mOut, sOut, n);
  // end FNN layer 1 (raw pre-BN bf16 out; per-wave stats partials in epilogue)
  hipLaunchKernelGGL((k_gemm_mfma<128, 256, 0, true, ushortt>), dim3(nbG),
                     dim3(256), 0, stream, out, (const void*)nullptr,
                     (const float*)nullptr, (const int*)nullptr,
                     (const float*)nullptr, (const float*)nullptr,
                     W1T, end_b1, y1B, pstat, n);
  hipLaunchKernelGGL((k_stats_reduce<512>), dim3(2, 16), dim3(256), 0, stream,
                     pstat, stats1, nbW);
  hipLaunchKernelGGL((k_bn_prep<256>), dim3(1), dim3(256), 0, stream, stats1, bnpr, n);
  // layer 2 with fused BN+elu on load; per-wave stats partials for final BN
  hipLaunchKernelGGL((k_gemm_mfma<256, 128, 3, true, float>), dim3(nbG),
                     dim3(256), 0, stream, y1B, (const void*)nullptr,
                     (const float*)nullptr, (const int*)nullptr,
                     bnpr, bnpr + 256,
                     W2T, end_b2, out, pstat, n);
  hipLaunchKernelGGL((k_stats_reduce<256>), dim3(1, 16), dim3(256), 0, stream,
                     pstat, stats2, nbW);
  hipLaunchKernelGGL((k_bn_apply<128, true, float>),
                     dim3((int)(((size_t)n * 128 + 255) / 256)), dim3(256), 0, stream,
                     out, stats2, h_last, n);
}

extern "C" void kernel_launch(void* const* d_in, const int* in_sizes, int n_in,
                              void* d_out, int out_size, void* d_ws, size_t ws_size,
                              hipStream_t stream) {
  const float* h_da_last = (const float*)d_in[0];
  const float* h_q_last  = (const float*)d_in[1];
  const float* h_da_0    = (const float*)d_in[2];
  const float* h_q_0     = (const float*)d_in[3];
  const float* W_L       = (const float*)d_in[4];
  const float* b_L       = (const float*)d_in[5];
  const float* gateq_W   = (const float*)d_in[6];
  const float* gateq_b   = (const float*)d_in[7];
  const float* gate1_W   = (const float*)d_in[8];
  const float* gate1_b   = (const float*)d_in[9];
  const float* gate2_W   = (const float*)d_in[10];
  const float* gate2_b   = (const float*)d_in[11];
  const float* Q_comb    = (const float*)d_in[12];
  const float* Qf_W1     = (const float*)d_in[13];
  const float* Qf_b1     = (const float*)d_in[14];
  const float* Qf_W2     = (const float*)d_in[15];
  const float* Qf_b2     = (const float*)d_in[16];
  const float* end_W1    = (const float*)d_in[17];
  const float* end_b1    = (const float*)d_in[18];
  const float* end_W2    = (const float*)d_in[19];
  const float* end_b2    = (const float*)d_in[20];
  const int* src_da = (const int*)d_in[21];
  const int* dst_da = (const int*)d_in[22];
  const int* src_q  = (const int*)d_in[23];
  const int* dst_q  = (const int*)d_in[24];
  const int* gid_da = (const int*)d_in[25];
  const int* gid_q  = (const int*)d_in[26];
  const int* PEid   = (const int*)d_in[27];
  const int* DEid   = (const int*)d_in[28];
  const int* len_Mn = (const int*)d_in[29];

  float* out_da   = (float*)d_out;
  float* out_q    = (float*)d_out + (size_t)CNDA * CHD;
  float* out_loss = (float*)d_out + (size_t)CNDA * CHD + (size_t)CNQ * CHD;

  // ---- workspace arena (float units), ~84 MB ----
  float* ws = (float*)d_ws;
  size_t off = 0;
  auto alloc = [&](size_t cnt) { float* p = ws + off; off += cnt; return p; };
  float* U    = alloc((size_t)CNDA * 128);   // ft bf16 n*128 / y1 bf16 n*256 union
  float* elr  = alloc((size_t)CNDA * 16);
  float* mOut = alloc((size_t)CNDA * CH);
  float* sOut = alloc((size_t)CNDA * CH);
  int* counts  = (int*)alloc(CNDA);
  int* rowptr  = (int*)alloc(CNDA + 4);
  int* cursor  = (int*)alloc(CNDA);
  int* csr_src = (int*)alloc(CEDA);
  int* bsum    = (int*)alloc(128);
  ushortt* W_LT = (ushortt*)alloc(128 * 128 / 2);
  ushortt* W1T  = (ushortt*)alloc(128 * 256 / 2);
  ushortt* W2T  = (ushortt*)alloc(256 * 128 / 2);
  float* WQ   = alloc((size_t)CB * 2048);
  float* bQ   = alloc((size_t)CB * 16);
  // NOTE: gq..g2da must stay consecutive (k_gmax5 indexes off gq)
  float* gq   = alloc(CNQ);
  float* g1q  = alloc(CNQ);
  float* g2q  = alloc(CNQ);
  float* g1da = alloc(CNDA);
  float* g2da = alloc(CNDA);
  // NOTE: glq..k2da must stay consecutive (zeroed as one region; k_gap_norm5)
  float* glq  = alloc(CB * CHD);
  float* k1q  = alloc(CB * CHD);
  float* k2q  = alloc(CB * CHD);
  float* k1da = alloc(CB * CHD);
  float* k2da = alloc(CB * CHD);
  float* Qt   = alloc(CB * 256);
  float* Qm   = alloc(CB * 256);
  float* acq  = alloc(CB * 2);
  float* acda = alloc(CB * 2);
  float* stats = alloc(1024);     // [0..511] BN256 stats, [512..1023] BN128 stats
  float* bnpr  = alloc(512);      // mu/inv for BN256
  float* mbuf  = alloc(5 * 64);   // [gq, g2q, g1q, g1da, g2da]
  float* sbuf  = alloc(5 * 64);   // same order
  int* startq  = (int*)alloc(68);
  int* startda = (int*)alloc(68);
  float* pstat = alloc(((size_t)(CNDA + 63) / 64) * 4 * 512);  // per-WAVE stats partials
  float* pdp   = alloc(((size_t)CNDA * CH + 255) / 256 * CH);  // k_pd partials
  (void)ws_size; (void)n_in; (void)out_size;

  // ---- weight transposes (bf16) ----
  hipLaunchKernelGGL(k_tcast, dim3((128 * 128 + 255) / 256), dim3(256), 0, stream, W_L, W_LT, 128, 128);
  hipLaunchKernelGGL(k_tcast, dim3((128 * 256 + 255) / 256), dim3(256), 0, stream, end_W1, W1T, 128, 256);
  hipLaunchKernelGGL(k_tcast, dim3((256 * 128 + 255) / 256), dim3(256), 0, stream, end_W2, W2T, 256, 128);

  // ---- group boundaries ----
  hipLaunchKernelGGL(k_binit, dim3(1), dim3(128), 0, stream, startq, CNQ);
  hipLaunchKernelGGL(k_binit, dim3(1), dim3(128), 0, stream, startda, CNDA);
  hipLaunchKernelGGL(k_bmark, dim3((CNQ + 255) / 256), dim3(256), 0, stream, gid_q, CNQ, startq);
  hipLaunchKernelGGL(k_bmark, dim3((CNDA + 255) / 256), dim3(256), 0, stream, gid_da, CNDA, startda);
  hipLaunchKernelGGL(k_bfix, dim3(1), dim3(64), 0, stream, startq);
  hipLaunchKernelGGL(k_bfix, dim3(1), dim3(64), 0, stream, startda);

  // ---- gate dots ----
  hipLaunchKernelGGL(k_gate_dot2, dim3((CNQ + 3) / 4), dim3(256), 0, stream,
                     h_q_last, gateq_W, gateq_b, gate2_W, gate2_b, gq, g2q, CNQ);
  hipLaunchKernelGGL(k_gate_dot, dim3((CNQ + 3) / 4), dim3(256), 0, stream, h_q_0, gate1_W, gate1_b, g1q, CNQ);
  hipLaunchKernelGGL(k_gate_dot, dim3((CNDA + 3) / 4), dim3(256), 0, stream, h_da_0, gate1_W, gate1_b, g1da, CNDA);
  hipLaunchKernelGGL(k_gate_dot, dim3((CNDA + 3) / 4), dim3(256), 0, stream, h_da_last, gate2_W, gate2_b, g2da, CNDA);

  // ---- GAPs (parallel 3-phase segmented softmax-pool) ----
  hipLaunchKernelGGL(k_gmax5, dim3(5 * CB), dim3(256), 0, stream, gq, startq, startda, mbuf);
  zero_launch(glq, 5 * (size_t)CB * CHD, stream);
  zero_launch(sbuf, 5 * 64, stream);
  hipLaunchKernelGGL((k_gap_partial<2>), dim3(CB, 32), dim3(128), 0, stream,
                     gq, g2q, h_q_last, startq, mbuf + 0, glq, k2q, sbuf + 0);
  hipLaunchKernelGGL((k_gap_partial<1>), dim3(CB, 32), dim3(128), 0, stream,
                     g1q, (const float*)nullptr, h_q_0, startq, mbuf + 128,
                     k1q, (float*)nullptr, sbuf + 128);
  hipLaunchKernelGGL((k_gap_partial<1>), dim3(CB, 32), dim3(128), 0, stream,
                     g1da, (const float*)nullptr, h_da_0, startda, mbuf + 192,
                     k1da, (float*)nullptr, sbuf + 192);
  hipLaunchKernelGGL((k_gap_partial<1>), dim3(CB, 32), dim3(128), 0, stream,
                     g2da, (const float*)nullptr, h_da_last, startda, mbuf + 256,
                     k2da, (float*)nullptr, sbuf + 256);
  hipLaunchKernelGGL(k_gap_norm5, dim3(5 * CB), dim3(128), 0, stream, glq, sbuf);

  // ---- Q = fnn(glq) ----
  hipLaunchKernelGGL(k_mm_small, dim3((CB * 256 + 255) / 256), dim3(256), 0, stream,
                     glq, Qf_W1, Qf_b1, Qt, CB, 128, 256);
  hipLaunchKernelGGL(k_bn_elu_small, dim3(1), dim3(256), 0, stream, Qt, CB, 256);
  hipLaunchKernelGGL(k_mm_small, dim3((CB * 256 + 255) / 256), dim3(256), 0, stream,
                     Qt, Qf_W2, Qf_b2, Qm, CB, 256, 256);
  hipLaunchKernelGGL(k_bn_elu_small, dim3(1), dim3(256), 0, stream, Qm, CB, 256);

  // ---- projected per-group Q matrices ----
  hipLaunchKernelGGL(k_wq, dim3(CB), dim3(256), 0, stream, W_L, b_L, Qm, WQ, bQ);

  // ---- att_comb scalars ----
  hipLaunchKernelGGL(k_attcomb, dim3(CB), dim3(64), 0, stream, k1q, k2q, Q_comb, acq);
  hipLaunchKernelGGL(k_attcomb, dim3(CB), dim3(64), 0, stream, k1da, k2da, Q_comb, acda);

  // ---- q branch ----
  run_branch(CNQ, CEQ, h_q_last, h_q_0, src_q, dst_q, gid_q, acq, WQ, bQ,
             W_LT, b_L, W1T, end_b1, W2T, end_b2,
             U, elr, mOut, sOut, counts, rowptr, cursor, csr_src, bsum,
             stats, bnpr, pstat, out_q, stream);

  // ---- da branch (elr/mOut/sOut end holding da state for the loss) ----
  run_branch(CNDA, CEDA, h_da_last, h_da_0, src_da, dst_da, gid_da, acda, WQ, bQ,
             W_LT, b_L, W1T, end_b1, W2T, end_b2,
             U, elr, mOut, sOut, counts, rowptr, cursor, csr_src, bsum,
             stats, bnpr, pstat, out_da, stream);

  // ---- loss from recomputed a_da ----
  int nPE = in_sizes[27], nDE = in_sizes[28];
  int nMax = nPE > nDE ? nPE : nDE;
  int nbPD = (nMax * CH + 255) / 256;
  hipLaunchKernelGGL(k_pd, dim3(nbPD), dim3(256), 0, stream,
                     src_da, dst_da, elr, mOut, sOut, PEid, DEid, pdp, nPE, nDE);
  hipLaunchKernelGGL(k_loss, dim3(1), dim3(256), 0, stream, pdp, nbPD, len_Mn, out_loss);
}

// Round 6
// 1283.494 us; speedup vs baseline: 1.1559x; 1.1559x over previous
//
#include <hip/hip_runtime.h>
#include <math.h>

// ---- problem constants ----
static constexpr int CB   = 64;      // groups
static constexpr int CH   = 8;       // heads
static constexpr int CEH  = 16;      // per-head dim
static constexpr int CHD  = 128;     // hidden dim
static constexpr int CNDA = 100000;
static constexpr int CNQ  = 20000;
static constexpr int CEDA = 1000000;
static constexpr int CEQ  = 200000;
static constexpr float CEPS = 1e-5f;
static constexpr float CSLOPE = 2.0f;

typedef unsigned short ushortt;
typedef __attribute__((ext_vector_type(8))) short bf16x8;
typedef __attribute__((ext_vector_type(4))) float f32x4;

// ---------- bf16 helpers ----------
__device__ __forceinline__ float ldf(const float* p) { return *p; }
__device__ __forceinline__ float ldf(const ushortt* p) {
  return __uint_as_float(((unsigned)*p) << 16);
}
__device__ __forceinline__ void stf(float* p, float v) { *p = v; }
__device__ __forceinline__ void stf(ushortt* p, float v) {
  unsigned u = __float_as_uint(v);
  u += 0x7fff + ((u >> 16) & 1);  // RNE
  *p = (ushortt)(u >> 16);
}
__device__ __forceinline__ short f2bf(float v) {
  unsigned u = __float_as_uint(v);
  u += 0x7fff + ((u >> 16) & 1);
  return (short)(u >> 16);
}
__device__ __forceinline__ float bf2f(short b) {
  return __uint_as_float(((unsigned)(ushortt)b) << 16);
}

// ---------- utility ----------
__global__ void k_zero(float* __restrict__ p, long n) {
  long i = (long)blockIdx.x * blockDim.x + threadIdx.x;
  long stride = (long)gridDim.x * blockDim.x;
  for (; i < n; i += stride) p[i] = 0.f;
}
static inline void zero_launch(void* p, long n, hipStream_t s) {
  long b = (n + 255) / 256;
  int blocks = (int)(b > 4096 ? 4096 : (b < 1 ? 1 : b));
  hipLaunchKernelGGL(k_zero, dim3(blocks), dim3(256), 0, s, (float*)p, n);
}

// ---------- group boundaries (gid sorted) ----------
__global__ void k_binit(int* start, int n) {
  int i = threadIdx.x;
  if (i <= CB) start[i] = n;
}
__global__ void k_bmark(const int* __restrict__ gid, int n, int* __restrict__ start) {
  int i = blockIdx.x * blockDim.x + threadIdx.x;
  if (i >= n) return;
  int g = gid[i];
  if (i == 0 || gid[i - 1] != g) atomicMin(&start[g], i);
}
__global__ void k_bfix(int* start) {
  if (threadIdx.x == 0) {
    for (int g = CB - 1; g >= 0; --g)
      if (start[g] > start[g + 1]) start[g] = start[g + 1];
  }
}

// ---------- gate dot (one gate) ----------
__global__ void k_gate_dot(const float* __restrict__ feat, const float* __restrict__ gw,
                           const float* __restrict__ gb, float* __restrict__ g, int n) {
  int wave = (blockIdx.x * blockDim.x + threadIdx.x) >> 6;
  int lane = threadIdx.x & 63;
  if (wave >= n) return;
  const float* row = feat + (size_t)wave * CHD;
  float v = row[lane] * gw[lane] + row[lane + 64] * gw[lane + 64];
  for (int off = 32; off > 0; off >>= 1) v += __shfl_down(v, off, 64);
  if (lane == 0) g[wave] = v + gb[0];
}

// ---------- gate dot (two gates, shared feat read) ----------
__global__ void k_gate_dot2(const float* __restrict__ feat,
                            const float* __restrict__ w1, const float* __restrict__ b1,
                            const float* __restrict__ w2, const float* __restrict__ b2,
                            float* __restrict__ g1, float* __restrict__ g2, int n) {
  int wave = (blockIdx.x * blockDim.x + threadIdx.x) >> 6;
  int lane = threadIdx.x & 63;
  if (wave >= n) return;
  const float* row = feat + (size_t)wave * CHD;
  float r0 = row[lane], r1 = row[lane + 64];
  float v1 = r0 * w1[lane] + r1 * w1[lane + 64];
  float v2 = r0 * w2[lane] + r1 * w2[lane + 64];
  for (int off = 32; off > 0; off >>= 1) {
    v1 += __shfl_down(v1, off, 64);
    v2 += __shfl_down(v2, off, 64);
  }
  if (lane == 0) {
    g1[wave] = v1 + b1[0];
    g2[wave] = v2 + b2[0];
  }
}

// ---------- GAP phase 1: per-group max of g, all 5 jobs in one launch ----------
__global__ void k_gmax5(const float* __restrict__ gq, const int* __restrict__ startq,
                        const int* __restrict__ startda, float* __restrict__ m) {
  int job = blockIdx.x >> 6, grp = blockIdx.x & 63;
  const float* g;
  const int* start;
  if (job == 0)      { g = gq;                              start = startq; }
  else if (job == 1) { g = gq + 2 * (size_t)CNQ;            start = startq; }   // g2q
  else if (job == 2) { g = gq + (size_t)CNQ;                start = startq; }   // g1q
  else if (job == 3) { g = gq + 3 * (size_t)CNQ;            start = startda; }  // g1da
  else               { g = gq + 3 * (size_t)CNQ + CNDA;     start = startda; }  // g2da
  int s0 = start[grp], s1 = start[grp + 1];
  int t = threadIdx.x;  // 256
  __shared__ float red[256];
  float v = -1e30f;
  for (int i = s0 + t; i < s1; i += 256) v = fmaxf(v, g[i]);
  red[t] = v;
  __syncthreads();
  for (int o = 128; o > 0; o >>= 1) {
    if (t < o) red[t] = fmaxf(red[t], red[t + o]);
    __syncthreads();
  }
  if (t == 0) m[job * 64 + grp] = red[0];
}

// ---------- GAP phase 2: partial weighted sums (grid = groups x chunks) ----------
template <int NG>
__global__ __launch_bounds__(128) void k_gap_partial(
    const float* __restrict__ g0, const float* __restrict__ g1,
    const float* __restrict__ feat, const int* __restrict__ start,
    const float* __restrict__ m,
    float* __restrict__ acc0, float* __restrict__ acc1,
    float* __restrict__ sums) {
  int grp = blockIdx.x;
  int s0 = start[grp], s1 = start[grp + 1];
  int len = s1 - s0;
  if (len <= 0) return;
  int NC = gridDim.y;
  int per = (len + NC - 1) / NC;
  int r0 = s0 + blockIdx.y * per;
  int r1 = min(s1, r0 + per);
  if (r0 >= r1) return;
  int t = threadIdx.x;  // 128 = column
  float m0 = m[grp];
  float m1 = (NG == 2) ? m[64 + grp] : 0.f;
  float a0 = 0.f, a1 = 0.f, sum0 = 0.f, sum1 = 0.f;
  for (int i = r0; i < r1; ++i) {
    float f = feat[(size_t)i * CHD + t];
    float e0 = expf(g0[i] - m0);
    sum0 += e0;
    a0 += e0 * f;
    if (NG == 2) {
      float e1 = expf(g1[i] - m1);
      sum1 += e1;
      a1 += e1 * f;
    }
  }
  atomicAdd(&acc0[grp * CHD + t], a0);
  if (NG == 2) atomicAdd(&acc1[grp * CHD + t], a1);
  if (t == 0) {
    atomicAdd(&sums[grp], sum0);
    if (NG == 2) atomicAdd(&sums[64 + grp], sum1);
  }
}

// ---------- GAP phase 3: normalize, all 5 jobs in one launch ----------
__global__ void k_gap_norm5(float* __restrict__ glq, const float* __restrict__ sbuf) {
  int job = blockIdx.x >> 6, grp = blockIdx.x & 63;
  int t = threadIdx.x;  // 128
  int smap = (job == 1) ? 2 : ((job == 2) ? 1 : job);
  float sv = sbuf[smap * 64 + grp];
  float* acc = glq + (size_t)job * CB * CHD + grp * CHD;
  float v = acc[t];
  acc[t] = (sv > 0.f) ? v / sv : 0.f;
}

// ---------- small matmul ----------
__global__ void k_mm_small(const float* __restrict__ X, const float* __restrict__ W,
                           const float* __restrict__ bias, float* __restrict__ Y,
                           int m, int k, int p) {
  int idx = blockIdx.x * blockDim.x + threadIdx.x;
  if (idx >= m * p) return;
  int r = idx / p, c = idx % p;
  float acc = bias[c];
  for (int kk = 0; kk < k; ++kk) acc += X[r * k + kk] * W[kk * p + c];
  Y[idx] = acc;
}

// ---------- BN+elu small ----------
__global__ void k_bn_elu_small(float* __restrict__ Y, int m, int p) {
  int c = blockIdx.x * blockDim.x + threadIdx.x;
  if (c >= p) return;
  float s = 0.f, s2 = 0.f;
  for (int i = 0; i < m; ++i) {
    float v = Y[i * p + c];
    s += v; s2 += v * v;
  }
  float mu = s / m;
  float var = s2 / m - mu * mu;
  float inv = rsqrtf(var + CEPS);
  for (int i = 0; i < m; ++i) {
    float v = (Y[i * p + c] - mu) * inv;
    Y[i * p + c] = v > 0.f ? v : expm1f(v);
  }
}

// ---------- att_comb ----------
__global__ void k_attcomb(const float* __restrict__ k1, const float* __restrict__ k2,
                          const float* __restrict__ Qc, float* __restrict__ a) {
  int grp = blockIdx.x;
  int t = threadIdx.x;  // 64 threads
  float v1 = Qc[t] * k1[grp * CHD + t] + Qc[t + 64] * k1[grp * CHD + t + 64];
  float v2 = Qc[t] * k2[grp * CHD + t] + Qc[t + 64] * k2[grp * CHD + t + 64];
  for (int off = 32; off > 0; off >>= 1) {
    v1 += __shfl_down(v1, off, 64);
    v2 += __shfl_down(v2, off, 64);
  }
  if (t == 0) {
    float mx = fmaxf(v1, v2);
    float e1 = expf(v1 - mx), e2 = expf(v2 - mx);
    float s = e1 + e2;
    a[grp * 2] = e1 / s;
    a[grp * 2 + 1] = e2 / s;
  }
}

// ---------- WQ precompute ----------
__global__ void k_wq(const float* __restrict__ W_L, const float* __restrict__ b_L,
                     const float* __restrict__ Qm, float* __restrict__ WQ,
                     float* __restrict__ bQ) {
  int g = blockIdx.x;  // 64 blocks, 256 threads
  int t = threadIdx.x;
  for (int j = 0; j < 8; ++j) {
    int idx = t + j * 256;
    int d = idx >> 4, c = idx & 15;
    int h = c & 7, off = (c >= 8) ? CEH : 0;
    const float* w = W_L + d * CHD + h * CEH;
    const float* q = Qm + g * 256 + h * 32 + off;
    float acc = 0.f;
#pragma unroll
    for (int e = 0; e < CEH; ++e) acc += w[e] * q[e];
    WQ[g * 2048 + idx] = acc;
  }
  if (t < 16) {
    int c = t, h = c & 7, off = (c >= 8) ? CEH : 0;
    const float* b = b_L + h * CEH;
    const float* q = Qm + g * 256 + h * 32 + off;
    float acc = 0.f;
#pragma unroll
    for (int e = 0; e < CEH; ++e) acc += b[e] * q[e];
    bQ[g * 16 + c] = acc;
  }
}

// ---------- elr ----------
__global__ void k_eler(const float* __restrict__ tmp, const float* __restrict__ WQ,
                       const float* __restrict__ bQ, const int* __restrict__ gid,
                       float* __restrict__ elr, int n) {
  int idx = blockIdx.x * blockDim.x + threadIdx.x;
  if (idx >= n * 16) return;
  int i = idx >> 4, c = idx & 15;
  int g = gid[i];
  const float* wq = WQ + g * 2048 + c;
  const float* row = tmp + (size_t)i * CHD;
  float acc = bQ[g * 16 + c];
#pragma unroll 4
  for (int d = 0; d < CHD; ++d) acc += row[d] * wq[d * 16];
  elr[idx] = acc;
}

// ---------- transpose+cast weights: WT[p][k] = bf16(W[k][p]) ----------
__global__ void k_tcast(const float* __restrict__ W, ushortt* __restrict__ WT,
                        int K, int P) {
  int i = blockIdx.x * blockDim.x + threadIdx.x;
  if (i >= K * P) return;
  int p = i / K, k = i % K;
  stf(&WT[i], W[(size_t)k * P + p]);
}

// ---------- BN prep: stats -> mu / inv ----------
template <int P>
__global__ void k_bn_prep(const float* __restrict__ stats, float* __restrict__ pr, int n) {
  int c = threadIdx.x;
  if (c >= P) return;
  float invn = 1.f / (float)n;
  float mu = stats[c] * invn;
  float var = stats[P + c] * invn - mu * mu;
  pr[c] = mu;
  pr[P + c] = rsqrtf(var + CEPS);
}

// ---------- stats reduce: fold per-wave partials into stats ----------
// grid (TP/256, 64); 4-way unrolled independent accumulators keep loads in flight
template <int TP>
__global__ void k_stats_reduce(const float* __restrict__ pstat, float* __restrict__ stats,
                               int nb) {
  int c = blockIdx.x * blockDim.x + threadIdx.x;
  if (c >= TP) return;
  int NC = gridDim.y;
  int per = (nb + NC - 1) / NC;
  int r0 = blockIdx.y * per;
  int r1 = min(nb, r0 + per);
  if (r0 >= r1) return;
  float s0 = 0.f, s1 = 0.f, s2 = 0.f, s3 = 0.f;
  int r = r0;
  for (; r + 4 <= r1; r += 4) {
    s0 += pstat[(size_t)(r + 0) * TP + c];
    s1 += pstat[(size_t)(r + 1) * TP + c];
    s2 += pstat[(size_t)(r + 2) * TP + c];
    s3 += pstat[(size_t)(r + 3) * TP + c];
  }
  for (; r < r1; ++r) s0 += pstat[(size_t)r * TP + c];
  atomicAdd(&stats[c], (s0 + s1) + (s2 + s3));
}

// ---------- MFMA GEMM: Y(nxP) = X(nxK) @ B + bias; BT is PxK bf16 ----------
// XM: 0 = fp32 plain, 1 = fp32 comb (a0*X0 + a1*X1), 2 = bf16 plain,
//     3 = bf16 with fused BN(mu/inv)+elu on load
// STATS: epilogue writes per-WAVE column sum/sumsq partials to pstat[(bid*4+wave)*2P..]
template <int K, int P, int XM, bool STATS, typename OT>
__global__ __launch_bounds__(256, 2) void k_gemm_mfma(
    const void* __restrict__ X0v, const void* __restrict__ X1v,
    const float* __restrict__ acomb, const int* __restrict__ gid,
    const float* __restrict__ bnmu, const float* __restrict__ bninv,
    const ushortt* __restrict__ BT, const float* __restrict__ bias,
    OT* __restrict__ Y, float* __restrict__ pstat, int n) {
  constexpr int NT = P / 16;
  const int wave = threadIdx.x >> 6, lane = threadIdx.x & 63;
  const int quad = lane >> 4, l16 = lane & 15;
  const int r0w = blockIdx.x * 64 + wave * 16;
  const int rA = r0w + l16;
  const bool rowok = rA < n;
  f32x4 acc[NT];
#pragma unroll
  for (int t = 0; t < NT; ++t) acc[t] = f32x4{0.f, 0.f, 0.f, 0.f};
  float a0 = 0.f, a1 = 0.f;
  if (XM == 1 && rowok) {
    int g = gid[rA];
    a0 = acomb[2 * g];
    a1 = acomb[2 * g + 1];
  }
  for (int k0 = 0; k0 < K; k0 += 32) {
    const int kk = k0 + quad * 8;
    bf16x8 af = {};
    if (rowok) {
      if constexpr (XM == 2) {
        af = *(const bf16x8*)((const ushortt*)X0v + (size_t)rA * K + kk);
      } else if constexpr (XM == 3) {
        bf16x8 raw = *(const bf16x8*)((const ushortt*)X0v + (size_t)rA * K + kk);
#pragma unroll
        for (int j = 0; j < 8; ++j) {
          float v = bf2f(raw[j]);
          v = (v - bnmu[kk + j]) * bninv[kk + j];
          v = v > 0.f ? v : (__expf(v) - 1.f);
          af[j] = f2bf(v);
        }
      } else {
        const float* px = (const float*)X0v + (size_t)rA * K + kk;
        float v[8];
        if constexpr (XM == 1) {
          const float* py = (const float*)X1v + (size_t)rA * K + kk;
#pragma unroll
          for (int j = 0; j < 8; ++j) v[j] = a0 * px[j] + a1 * py[j];
        } else {
#pragma unroll
          for (int j = 0; j < 8; ++j) v[j] = px[j];
        }
#pragma unroll
        for (int j = 0; j < 8; ++j) af[j] = f2bf(v[j]);
      }
    }
    // batch-load all B fragments (keeps NT loads in flight), then MFMA
    bf16x8 bfr[NT];
#pragma unroll
    for (int t = 0; t < NT; ++t)
      bfr[t] = *(const bf16x8*)(BT + (size_t)(t * 16 + l16) * K + kk);
#pragma unroll
    for (int t = 0; t < NT; ++t)
      acc[t] = __builtin_amdgcn_mfma_f32_16x16x32_bf16(af, bfr[t], acc[t], 0, 0, 0);
  }
  float* pw = STATS ? (pstat + ((size_t)blockIdx.x * 4 + wave) * (2 * P)) : nullptr;
#pragma unroll
  for (int t = 0; t < NT; ++t) {
    const int c = t * 16 + l16;
    float b = bias[c];
    float s = 0.f, s2 = 0.f;
#pragma unroll
    for (int r = 0; r < 4; ++r) {
      int gr = r0w + quad * 4 + r;
      if (gr < n) {
        float val = acc[t][r] + b;
        stf(Y + (size_t)gr * P + c, val);
        if constexpr (STATS) {
          float vq = (sizeof(OT) == 2) ? bf2f(f2bf(val)) : val;
          s += vq;
          s2 += vq * vq;
        }
      }
    }
    if constexpr (STATS) {
      s += __shfl_xor(s, 16, 64);
      s += __shfl_xor(s, 32, 64);
      s2 += __shfl_xor(s2, 16, 64);
      s2 += __shfl_xor(s2, 32, 64);
      if (quad == 0) {
        pw[c] = s;
        pw[P + c] = s2;
      }
    }
  }
}

// ---------- CSR build ----------
__global__ void k_count(const int* __restrict__ dst, int* __restrict__ counts, int E) {
  int e = blockIdx.x * blockDim.x + threadIdx.x;
  if (e < E) atomicAdd(&counts[dst[e]], 1);
}
__global__ void k_scan_reduce(const int* __restrict__ counts, int* __restrict__ bsum, int n) {
  __shared__ int red[256];
  int t = threadIdx.x;
  int base = blockIdx.x * 1024;
  int s = 0;
  for (int j = 0; j < 4; ++j) {
    int i = base + t * 4 + j;
    if (i < n) s += counts[i];
  }
  red[t] = s;
  __syncthreads();
  for (int o = 128; o > 0; o >>= 1) {
    if (t < o) red[t] += red[t + o];
    __syncthreads();
  }
  if (t == 0) bsum[blockIdx.x] = red[0];
}
__global__ void k_scan_top(int* __restrict__ bsum, int nb) {
  __shared__ int sh[128];
  int t = threadIdx.x;  // 128 threads
  int v = (t < nb) ? bsum[t] : 0;
  sh[t] = v;
  __syncthreads();
  for (int o = 1; o < 128; o <<= 1) {
    int x = (t >= o) ? sh[t - o] : 0;
    __syncthreads();
    sh[t] += x;
    __syncthreads();
  }
  if (t < nb) bsum[t] = sh[t] - v;  // exclusive
}
__global__ void k_scan_final(const int* __restrict__ counts, const int* __restrict__ bsum,
                             int* __restrict__ rowptr, int n, int E) {
  __shared__ int sh[256];
  int t = threadIdx.x;
  int base = blockIdx.x * 1024;
  int v[4];
  int s = 0;
  for (int j = 0; j < 4; ++j) {
    int i = base + t * 4 + j;
    v[j] = (i < n) ? counts[i] : 0;
    s += v[j];
  }
  sh[t] = s;
  __syncthreads();
  for (int o = 1; o < 256; o <<= 1) {
    int x = (t >= o) ? sh[t - o] : 0;
    __syncthreads();
    sh[t] += x;
    __syncthreads();
  }
  int off = bsum[blockIdx.x] + sh[t] - s;
  for (int j = 0; j < 4; ++j) {
    int i = base + t * 4 + j;
    if (i < n) rowptr[i] = off;
    off += v[j];
  }
  if (blockIdx.x == 0 && t == 0) rowptr[n] = E;
}
__global__ void k_copy_int(const int* __restrict__ a, int* __restrict__ b, int n) {
  int i = blockIdx.x * blockDim.x + threadIdx.x;
  if (i < n) b[i] = a[i];
}
__global__ void k_scatter(const int* __restrict__ dst, const int* __restrict__ srcA,
                          int* __restrict__ cursor, int* __restrict__ csr_src, int E) {
  int e = blockIdx.x * blockDim.x + threadIdx.x;
  if (e >= E) return;
  int d = dst[e];
  int pos = atomicAdd(&cursor[d], 1);
  csr_src[pos] = srcA[e];
}

// ---------- fused softmax aggregation: one wave per node ----------
__global__ __launch_bounds__(256) void k_node_agg(
    const int* __restrict__ rowptr, const int* __restrict__ csr_src,
    const float* __restrict__ elr, const ushortt* __restrict__ ft,
    float* __restrict__ agg, float* __restrict__ mOut, float* __restrict__ sOut, int n) {
  int node = blockIdx.x * 4 + (threadIdx.x >> 6);
  if (node >= n) return;
  int lane = threadIdx.x & 63;
  int h_p = lane & 7;    // head for p-compute role
  int e_loc = lane >> 3; // edge slot (0..7)
  int h_a = lane >> 3;   // head for accumulation role (cols 2*lane, 2*lane+1)
  int s0 = rowptr[node], s1 = rowptr[node + 1];
  if (s1 <= s0) {
    *(float2*)(agg + (size_t)node * CHD + lane * 2) = make_float2(0.f, 0.f);
    if (lane < 8) {
      mOut[(size_t)node * CH + lane] = -1e30f;
      sOut[(size_t)node * CH + lane] = 0.f;
    }
    return;
  }
  float erd_p = elr[(size_t)node * 16 + 8 + h_p];
  // ---- pass 1: max of el over in-edges, per head h_p ----
  float mx = -1e30f;
  for (int base = s0; base < s1; base += 8) {
    int e = base + e_loc;
    if (e < s1) {
      int sj = csr_src[e];
      mx = fmaxf(mx, elr[(size_t)sj * 16 + h_p]);
    }
  }
  mx = fmaxf(mx, __shfl_xor(mx, 8, 64));
  mx = fmaxf(mx, __shfl_xor(mx, 16, 64));
  mx = fmaxf(mx, __shfl_xor(mx, 32, 64));
  float xm = mx + erd_p;
  float m_p = xm >= 0.f ? xm : CSLOPE * xm;  // max of leaky(x) over edges
  // ---- pass 2: p = exp(x - m), weighted feature accumulation ----
  float s_part = 0.f, a0 = 0.f, a1 = 0.f;
  int base = s0;
  // full 8-edge batches: compile-time unrolled -> gather loads batched
  for (; base + 8 <= s1; base += 8) {
    int sj = csr_src[base + e_loc];
    float x = elr[(size_t)sj * 16 + h_p] + erd_p;
    x = x >= 0.f ? x : CSLOPE * x;
    float p = __expf(x - m_p);
    s_part += p;
#pragma unroll
    for (int e = 0; e < 8; ++e) {
      float pe = __shfl(p, e * 8 + h_a, 64);
      int se = __shfl(sj, e * 8, 64);
      unsigned ftv = *(const unsigned*)(ft + (size_t)se * CHD + lane * 2);
      a0 += pe * __uint_as_float(ftv << 16);
      a1 += pe * __uint_as_float(ftv & 0xffff0000u);
    }
  }
  // tail batch (guarded)
  if (base < s1) {
    int cnt = s1 - base;
    int sj = 0;
    float p = 0.f;
    if (e_loc < cnt) {
      sj = csr_src[base + e_loc];
      float x = elr[(size_t)sj * 16 + h_p] + erd_p;
      x = x >= 0.f ? x : CSLOPE * x;
      p = __expf(x - m_p);
      s_part += p;
    }
    for (int e = 0; e < cnt; ++e) {
      float pe = __shfl(p, e * 8 + h_a, 64);
      int se = __shfl(sj, e * 8, 64);
      unsigned ftv = *(const unsigned*)(ft + (size_t)se * CHD + lane * 2);
      a0 += pe * __uint_as_float(ftv << 16);
      a1 += pe * __uint_as_float(ftv & 0xffff0000u);
    }
  }
  s_part += __shfl_xor(s_part, 8, 64);
  s_part += __shfl_xor(s_part, 16, 64);
  s_part += __shfl_xor(s_part, 32, 64);
  float s_acc = __shfl(s_part, h_a, 64);  // lane h_a holds head h_p == h_a
  float inv = 1.f / s_acc;
  float2 o;
  o.x = a0 * inv;
  o.y = a1 * inv;
  *(float2*)(agg + (size_t)node * CHD + lane * 2) = o;
  if (lane < 8) {
    mOut[(size_t)node * CH + lane] = m_p;
    sOut[(size_t)node * CH + lane] = s_part;
  }
}

// ---------- BN apply + elu (+ residual) ----------
template <int P, bool RESID, typename T>
__global__ void k_bn_apply(T* __restrict__ Y, const float* __restrict__ stats,
                           const float* __restrict__ hlast, int n) {
  size_t idx = (size_t)blockIdx.x * blockDim.x + threadIdx.x;
  if (idx >= (size_t)n * P) return;
  int c = (int)(idx % P);
  float invn = 1.f / (float)n;
  float mu = stats[c] * invn;
  float var = stats[P + c] * invn - mu * mu;
  float v = (ldf(Y + idx) - mu) * rsqrtf(var + CEPS);
  v = v > 0.f ? v : expm1f(v);
  if (RESID) v += hlast[idx];
  stf(Y + idx, v);
}

// ---------- attention recompute for loss ----------
__device__ __forceinline__ float attn_val(int e, int h, const int* __restrict__ src,
                                          const int* __restrict__ dst,
                                          const float* __restrict__ elr,
                                          const float* __restrict__ mOut,
                                          const float* __restrict__ sOut) {
  int ss = src[e], sd = dst[e];
  float x = elr[(size_t)ss * 16 + h] + elr[(size_t)sd * 16 + 8 + h];
  x = x >= 0.f ? x : CSLOPE * x;
  return expf(x - mOut[(size_t)sd * CH + h]) / sOut[(size_t)sd * CH + h];
}

// per-block partials (no global atomics)
__global__ void k_pd(const int* __restrict__ src, const int* __restrict__ dst,
                     const float* __restrict__ elr, const float* __restrict__ mOut,
                     const float* __restrict__ sOut, const int* __restrict__ PEid,
                     const int* __restrict__ DEid, float* __restrict__ pdp,
                     int nPE, int nDE) {
  __shared__ float part[CH];
  if (threadIdx.x < CH) part[threadIdx.x] = 0.f;
  __syncthreads();
  int idx = blockIdx.x * blockDim.x + threadIdx.x;
  int j = idx >> 3, h = idx & 7;
  float acc = 0.f;
  if (j < nPE) acc += attn_val(PEid[j], h, src, dst, elr, mOut, sOut);
  if (j < nDE) acc -= attn_val(DEid[j], h, src, dst, elr, mOut, sOut);
  atomicAdd(&part[h], acc);
  __syncthreads();
  if (threadIdx.x < CH) pdp[(size_t)blockIdx.x * CH + threadIdx.x] = part[threadIdx.x];
}
__global__ void k_loss(const float* __restrict__ pdp, int nb,
                       const int* __restrict__ lenMn, float* __restrict__ out) {
  __shared__ float part[CH];
  int t = threadIdx.x;  // 256
  if (t < CH) part[t] = 0.f;
  __syncthreads();
  int h = t & 7;
  float acc = 0.f;
  for (int j = t >> 3; j < nb; j += 32) acc += pdp[(size_t)j * CH + h];
  atomicAdd(&part[h], acc);
  __syncthreads();
  if (t == 0) {
    float len = (float)lenMn[0];
    float s = 0.f;
    for (int hh = 0; hh < CH; ++hh) s += part[hh] / len;
    out[0] = -s / (float)CH;
  }
}

// ---------- branch driver ----------
static void run_branch(int n, int E, const float* h_last, const float* h0,
                       const int* src, const int* dst, const int* gid,
                       const float* acomb, const float* WQ, const float* bQ,
                       const ushortt* W_LT, const float* b_L,
                       const ushortt* W1T, const float* end_b1,
                       const ushortt* W2T, const float* end_b2,
                       float* U, float* elr, float* mOut, float* sOut,
                       int* counts, int* rowptr, int* cursor, int* csr_src, int* bsum,
                       float* stats /*1024: [0..511]=BN256, [512..1023]=BN128*/,
                       float* bnpr /*512*/, float* pstat, float* out, hipStream_t stream) {
  ushortt* ftB = (ushortt*)U;   // n x 128 bf16
  ushortt* y1B = (ushortt*)U;   // n x 256 bf16 (ft dead by then)
  float* stats1 = stats;
  float* stats2 = stats + 512;
  int nChunks = (n + 1023) / 1024;
  int nbG = (n + 63) / 64;      // gemm grid blocks
  int nbW = nbG * 4;            // per-wave stats partial rows
  // CSR build
  zero_launch(counts, n, stream);
  zero_launch(stats, 1024, stream);
  hipLaunchKernelGGL(k_count, dim3((E + 255) / 256), dim3(256), 0, stream, dst, counts, E);
  hipLaunchKernelGGL(k_scan_reduce, dim3(nChunks), dim3(256), 0, stream, counts, bsum, n);
  hipLaunchKernelGGL(k_scan_top, dim3(1), dim3(128), 0, stream, bsum, nChunks);
  hipLaunchKernelGGL(k_scan_final, dim3(nChunks), dim3(256), 0, stream, counts, bsum, rowptr, n, E);
  hipLaunchKernelGGL(k_copy_int, dim3((n + 255) / 256), dim3(256), 0, stream, rowptr, cursor, n);
  hipLaunchKernelGGL(k_scatter, dim3((E + 255) / 256), dim3(256), 0, stream, dst, src, cursor, csr_src, E);
  // elr
  hipLaunchKernelGGL(k_eler, dim3((n * 16 + 255) / 256), dim3(256), 0, stream,
                     h_last, WQ, bQ, gid, elr, n);
  // ft = (a0*h0 + a1*h_last) @ W_L + b_L -> bf16
  hipLaunchKernelGGL((k_gemm_mfma<128, 128, 1, false, ushortt>), dim3(nbG),
                     dim3(256), 0, stream, h0, h_last, acomb, gid,
                     (const float*)nullptr, (const float*)nullptr,
                     W_LT, b_L, ftB, (float*)nullptr, n);
  // fused softmax aggregation
  hipLaunchKernelGGL(k_node_agg, dim3((n + 3) / 4), dim3(256), 0, stream,
                     rowptr, csr_src, elr, ftB, out, mOut, sOut, n);
  // end FNN layer 1 (raw pre-BN bf16 out; per-wave stats partials in epilogue)
  hipLaunchKernelGGL((k_gemm_mfma<128, 256, 0, true, ushortt>), dim3(nbG),
                     dim3(256), 0, stream, out, (const void*)nullptr,
                     (const float*)nullptr, (const int*)nullptr,
                     (const float*)nullptr, (const float*)nullptr,
                     W1T, end_b1, y1B, pstat, n);
  hipLaunchKernelGGL((k_stats_reduce<512>), dim3(2, 64), dim3(256), 0, stream,
                     pstat, stats1, nbW);
  hipLaunchKernelGGL((k_bn_prep<256>), dim3(1), dim3(256), 0, stream, stats1, bnpr, n);
  // layer 2 with fused BN+elu on load; per-wave stats partials for final BN
  hipLaunchKernelGGL((k_gemm_mfma<256, 128, 3, true, float>), dim3(nbG),
                     dim3(256), 0, stream, y1B, (const void*)nullptr,
                     (const float*)nullptr, (const int*)nullptr,
                     bnpr, bnpr + 256,
                     W2T, end_b2, out, pstat, n);
  hipLaunchKernelGGL((k_stats_reduce<256>), dim3(1, 64), dim3(256), 0, stream,
                     pstat, stats2, nbW);
  hipLaunchKernelGGL((k_bn_apply<128, true, float>),
                     dim3((int)(((size_t)n * 128 + 255) / 256)), dim3(256), 0, stream,
                     out, stats2, h_last, n);
}

extern "C" void kernel_launch(void* const* d_in, const int* in_sizes, int n_in,
                              void* d_out, int out_size, void* d_ws, size_t ws_size,
                              hipStream_t stream) {
  const float* h_da_last = (const float*)d_in[0];
  const float* h_q_last  = (const float*)d_in[1];
  const float* h_da_0    = (const float*)d_in[2];
  const float* h_q_0     = (const float*)d_in[3];
  const float* W_L       = (const float*)d_in[4];
  const float* b_L       = (const float*)d_in[5];
  const float* gateq_W   = (const float*)d_in[6];
  const float* gateq_b   = (const float*)d_in[7];
  const float* gate1_W   = (const float*)d_in[8];
  const float* gate1_b   = (const float*)d_in[9];
  const float* gate2_W   = (const float*)d_in[10];
  const float* gate2_b   = (const float*)d_in[11];
  const float* Q_comb    = (const float*)d_in[12];
  const float* Qf_W1     = (const float*)d_in[13];
  const float* Qf_b1     = (const float*)d_in[14];
  const float* Qf_W2     = (const float*)d_in[15];
  const float* Qf_b2     = (const float*)d_in[16];
  const float* end_W1    = (const float*)d_in[17];
  const float* end_b1    = (const float*)d_in[18];
  const float* end_W2    = (const float*)d_in[19];
  const float* end_b2    = (const float*)d_in[20];
  const int* src_da = (const int*)d_in[21];
  const int* dst_da = (const int*)d_in[22];
  const int* src_q  = (const int*)d_in[23];
  const int* dst_q  = (const int*)d_in[24];
  const int* gid_da = (const int*)d_in[25];
  const int* gid_q  = (const int*)d_in[26];
  const int* PEid   = (const int*)d_in[27];
  const int* DEid   = (const int*)d_in[28];
  const int* len_Mn = (const int*)d_in[29];

  float* out_da   = (float*)d_out;
  float* out_q    = (float*)d_out + (size_t)CNDA * CHD;
  float* out_loss = (float*)d_out + (size_t)CNDA * CHD + (size_t)CNQ * CHD;

  // ---- workspace arena (float units), ~84 MB ----
  float* ws = (float*)d_ws;
  size_t off = 0;
  auto alloc = [&](size_t cnt) { float* p = ws + off; off += cnt; return p; };
  float* U    = alloc((size_t)CNDA * 128);   // ft bf16 n*128 / y1 bf16 n*256 union
  float* elr  = alloc((size_t)CNDA * 16);
  float* mOut = alloc((size_t)CNDA * CH);
  float* sOut = alloc((size_t)CNDA * CH);
  int* counts  = (int*)alloc(CNDA);
  int* rowptr  = (int*)alloc(CNDA + 4);
  int* cursor  = (int*)alloc(CNDA);
  int* csr_src = (int*)alloc(CEDA);
  int* bsum    = (int*)alloc(128);
  ushortt* W_LT = (ushortt*)alloc(128 * 128 / 2);
  ushortt* W1T  = (ushortt*)alloc(128 * 256 / 2);
  ushortt* W2T  = (ushortt*)alloc(256 * 128 / 2);
  float* WQ   = alloc((size_t)CB * 2048);
  float* bQ   = alloc((size_t)CB * 16);
  // NOTE: gq..g2da must stay consecutive (k_gmax5 indexes off gq)
  float* gq   = alloc(CNQ);
  float* g1q  = alloc(CNQ);
  float* g2q  = alloc(CNQ);
  float* g1da = alloc(CNDA);
  float* g2da = alloc(CNDA);
  // NOTE: glq..k2da must stay consecutive (zeroed as one region; k_gap_norm5)
  float* glq  = alloc(CB * CHD);
  float* k1q  = alloc(CB * CHD);
  float* k2q  = alloc(CB * CHD);
  float* k1da = alloc(CB * CHD);
  float* k2da = alloc(CB * CHD);
  float* Qt   = alloc(CB * 256);
  float* Qm   = alloc(CB * 256);
  float* acq  = alloc(CB * 2);
  float* acda = alloc(CB * 2);
  float* stats = alloc(1024);     // [0..511] BN256 stats, [512..1023] BN128 stats
  float* bnpr  = alloc(512);      // mu/inv for BN256
  float* mbuf  = alloc(5 * 64);   // [gq, g2q, g1q, g1da, g2da]
  float* sbuf  = alloc(5 * 64);   // same order
  int* startq  = (int*)alloc(68);
  int* startda = (int*)alloc(68);
  float* pstat = alloc(((size_t)(CNDA + 63) / 64) * 4 * 512);  // per-WAVE stats partials
  float* pdp   = alloc(((size_t)CNDA * CH + 255) / 256 * CH);  // k_pd partials
  (void)ws_size; (void)n_in; (void)out_size;

  // ---- weight transposes (bf16) ----
  hipLaunchKernelGGL(k_tcast, dim3((128 * 128 + 255) / 256), dim3(256), 0, stream, W_L, W_LT, 128, 128);
  hipLaunchKernelGGL(k_tcast, dim3((128 * 256 + 255) / 256), dim3(256), 0, stream, end_W1, W1T, 128, 256);
  hipLaunchKernelGGL(k_tcast, dim3((256 * 128 + 255) / 256), dim3(256), 0, stream, end_W2, W2T, 256, 128);

  // ---- group boundaries ----
  hipLaunchKernelGGL(k_binit, dim3(1), dim3(128), 0, stream, startq, CNQ);
  hipLaunchKernelGGL(k_binit, dim3(1), dim3(128), 0, stream, startda, CNDA);
  hipLaunchKernelGGL(k_bmark, dim3((CNQ + 255) / 256), dim3(256), 0, stream, gid_q, CNQ, startq);
  hipLaunchKernelGGL(k_bmark, dim3((CNDA + 255) / 256), dim3(256), 0, stream, gid_da, CNDA, startda);
  hipLaunchKernelGGL(k_bfix, dim3(1), dim3(64), 0, stream, startq);
  hipLaunchKernelGGL(k_bfix, dim3(1), dim3(64), 0, stream, startda);

  // ---- gate dots ----
  hipLaunchKernelGGL(k_gate_dot2, dim3((CNQ + 3) / 4), dim3(256), 0, stream,
                     h_q_last, gateq_W, gateq_b, gate2_W, gate2_b, gq, g2q, CNQ);
  hipLaunchKernelGGL(k_gate_dot, dim3((CNQ + 3) / 4), dim3(256), 0, stream, h_q_0, gate1_W, gate1_b, g1q, CNQ);
  hipLaunchKernelGGL(k_gate_dot, dim3((CNDA + 3) / 4), dim3(256), 0, stream, h_da_0, gate1_W, gate1_b, g1da, CNDA);
  hipLaunchKernelGGL(k_gate_dot, dim3((CNDA + 3) / 4), dim3(256), 0, stream, h_da_last, gate2_W, gate2_b, g2da, CNDA);

  // ---- GAPs (parallel 3-phase segmented softmax-pool) ----
  hipLaunchKernelGGL(k_gmax5, dim3(5 * CB), dim3(256), 0, stream, gq, startq, startda, mbuf);
  zero_launch(glq, 5 * (size_t)CB * CHD, stream);
  zero_launch(sbuf, 5 * 64, stream);
  hipLaunchKernelGGL((k_gap_partial<2>), dim3(CB, 32), dim3(128), 0, stream,
                     gq, g2q, h_q_last, startq, mbuf + 0, glq, k2q, sbuf + 0);
  hipLaunchKernelGGL((k_gap_partial<1>), dim3(CB, 32), dim3(128), 0, stream,
                     g1q, (const float*)nullptr, h_q_0, startq, mbuf + 128,
                     k1q, (float*)nullptr, sbuf + 128);
  hipLaunchKernelGGL((k_gap_partial<1>), dim3(CB, 32), dim3(128), 0, stream,
                     g1da, (const float*)nullptr, h_da_0, startda, mbuf + 192,
                     k1da, (float*)nullptr, sbuf + 192);
  hipLaunchKernelGGL((k_gap_partial<1>), dim3(CB, 32), dim3(128), 0, stream,
                     g2da, (const float*)nullptr, h_da_last, startda, mbuf + 256,
                     k2da, (float*)nullptr, sbuf + 256);
  hipLaunchKernelGGL(k_gap_norm5, dim3(5 * CB), dim3(128), 0, stream, glq, sbuf);

  // ---- Q = fnn(glq) ----
  hipLaunchKernelGGL(k_mm_small, dim3((CB * 256 + 255) / 256), dim3(256), 0, stream,
                     glq, Qf_W1, Qf_b1, Qt, CB, 128, 256);
  hipLaunchKernelGGL(k_bn_elu_small, dim3(1), dim3(256), 0, stream, Qt, CB, 256);
  hipLaunchKernelGGL(k_mm_small, dim3((CB * 256 + 255) / 256), dim3(256), 0, stream,
                     Qt, Qf_W2, Qf_b2, Qm, CB, 256, 256);
  hipLaunchKernelGGL(k_bn_elu_small, dim3(1), dim3(256), 0, stream, Qm, CB, 256);

  // ---- projected per-group Q matrices ----
  hipLaunchKernelGGL(k_wq, dim3(CB), dim3(256), 0, stream, W_L, b_L, Qm, WQ, bQ);

  // ---- att_comb scalars ----
  hipLaunchKernelGGL(k_attcomb, dim3(CB), dim3(64), 0, stream, k1q, k2q, Q_comb, acq);
  hipLaunchKernelGGL(k_attcomb, dim3(CB), dim3(64), 0, stream, k1da, k2da, Q_comb, acda);

  // ---- q branch ----
  run_branch(CNQ, CEQ, h_q_last, h_q_0, src_q, dst_q, gid_q, acq, WQ, bQ,
             W_LT, b_L, W1T, end_b1, W2T, end_b2,
             U, elr, mOut, sOut, counts, rowptr, cursor, csr_src, bsum,
             stats, bnpr, pstat, out_q, stream);

  // ---- da branch (elr/mOut/sOut end holding da state for the loss) ----
  run_branch(CNDA, CEDA, h_da_last, h_da_0, src_da, dst_da, gid_da, acda, WQ, bQ,
             W_LT, b_L, W1T, end_b1, W2T, end_b2,
             U, elr, mOut, sOut, counts, rowptr, cursor, csr_src, bsum,
             stats, bnpr, pstat, out_da, stream);

  // ---- loss from recomputed a_da ----
  int nPE = in_sizes[27], nDE = in_sizes[28];
  int nMax = nPE > nDE ? nPE : nDE;
  int nbPD = (nMax * CH + 255) / 256;
  hipLaunchKernelGGL(k_pd, dim3(nbPD), dim3(256), 0, stream,
                     src_da, dst_da, elr, mOut, sOut, PEid, DEid, pdp, nPE, nDE);
  hipLaunchKernelGGL(k_loss, dim3(1), dim3(256), 0, stream, pdp, nbPD, len_Mn, out_loss);
}

// Round 7
// 1142.901 us; speedup vs baseline: 1.2981x; 1.1230x over previous
//
#include <hip/hip_runtime.h>
#include <math.h>

// ---- problem constants ----
static constexpr int CB   = 64;      // groups
static constexpr int CH   = 8;       // heads
static constexpr int CEH  = 16;      // per-head dim
static constexpr int CHD  = 128;     // hidden dim
static constexpr int CNDA = 100000;
static constexpr int CNQ  = 20000;
static constexpr int CEDA = 1000000;
static constexpr int CEQ  = 200000;
static constexpr float CEPS = 1e-5f;
static constexpr float CSLOPE = 2.0f;

typedef unsigned short ushortt;
typedef __attribute__((ext_vector_type(8))) short bf16x8;
typedef __attribute__((ext_vector_type(4))) float f32x4;

// ---------- bf16 helpers ----------
__device__ __forceinline__ float ldf(const float* p) { return *p; }
__device__ __forceinline__ float ldf(const ushortt* p) {
  return __uint_as_float(((unsigned)*p) << 16);
}
__device__ __forceinline__ void stf(float* p, float v) { *p = v; }
__device__ __forceinline__ void stf(ushortt* p, float v) {
  unsigned u = __float_as_uint(v);
  u += 0x7fff + ((u >> 16) & 1);  // RNE
  *p = (ushortt)(u >> 16);
}
__device__ __forceinline__ short f2bf(float v) {
  unsigned u = __float_as_uint(v);
  u += 0x7fff + ((u >> 16) & 1);
  return (short)(u >> 16);
}
__device__ __forceinline__ float bf2f(short b) {
  return __uint_as_float(((unsigned)(ushortt)b) << 16);
}

// ---------- utility ----------
__global__ void k_zero(float* __restrict__ p, long n) {
  long i = (long)blockIdx.x * blockDim.x + threadIdx.x;
  long stride = (long)gridDim.x * blockDim.x;
  for (; i < n; i += stride) p[i] = 0.f;
}
static inline void zero_launch(void* p, long n, hipStream_t s) {
  long b = (n + 255) / 256;
  int blocks = (int)(b > 4096 ? 4096 : (b < 1 ? 1 : b));
  hipLaunchKernelGGL(k_zero, dim3(blocks), dim3(256), 0, s, (float*)p, n);
}

// ---------- group boundaries (gid sorted) ----------
__global__ void k_binit(int* start, int n) {
  int i = threadIdx.x;
  if (i <= CB) start[i] = n;
}
__global__ void k_bmark(const int* __restrict__ gid, int n, int* __restrict__ start) {
  int i = blockIdx.x * blockDim.x + threadIdx.x;
  if (i >= n) return;
  int g = gid[i];
  if (i == 0 || gid[i - 1] != g) atomicMin(&start[g], i);
}
__global__ void k_bfix(int* start) {
  if (threadIdx.x == 0) {
    for (int g = CB - 1; g >= 0; --g)
      if (start[g] > start[g + 1]) start[g] = start[g + 1];
  }
}

// ---------- gate dot (one gate) ----------
__global__ void k_gate_dot(const float* __restrict__ feat, const float* __restrict__ gw,
                           const float* __restrict__ gb, float* __restrict__ g, int n) {
  int wave = (blockIdx.x * blockDim.x + threadIdx.x) >> 6;
  int lane = threadIdx.x & 63;
  if (wave >= n) return;
  const float* row = feat + (size_t)wave * CHD;
  float v = row[lane] * gw[lane] + row[lane + 64] * gw[lane + 64];
  for (int off = 32; off > 0; off >>= 1) v += __shfl_down(v, off, 64);
  if (lane == 0) g[wave] = v + gb[0];
}

// ---------- gate dot (two gates, shared feat read) ----------
__global__ void k_gate_dot2(const float* __restrict__ feat,
                            const float* __restrict__ w1, const float* __restrict__ b1,
                            const float* __restrict__ w2, const float* __restrict__ b2,
                            float* __restrict__ g1, float* __restrict__ g2, int n) {
  int wave = (blockIdx.x * blockDim.x + threadIdx.x) >> 6;
  int lane = threadIdx.x & 63;
  if (wave >= n) return;
  const float* row = feat + (size_t)wave * CHD;
  float r0 = row[lane], r1 = row[lane + 64];
  float v1 = r0 * w1[lane] + r1 * w1[lane + 64];
  float v2 = r0 * w2[lane] + r1 * w2[lane + 64];
  for (int off = 32; off > 0; off >>= 1) {
    v1 += __shfl_down(v1, off, 64);
    v2 += __shfl_down(v2, off, 64);
  }
  if (lane == 0) {
    g1[wave] = v1 + b1[0];
    g2[wave] = v2 + b2[0];
  }
}

// ---------- GAP phase 1: per-group max of g, all 5 jobs in one launch ----------
__global__ void k_gmax5(const float* __restrict__ gq, const int* __restrict__ startq,
                        const int* __restrict__ startda, float* __restrict__ m) {
  int job = blockIdx.x >> 6, grp = blockIdx.x & 63;
  const float* g;
  const int* start;
  if (job == 0)      { g = gq;                              start = startq; }
  else if (job == 1) { g = gq + 2 * (size_t)CNQ;            start = startq; }   // g2q
  else if (job == 2) { g = gq + (size_t)CNQ;                start = startq; }   // g1q
  else if (job == 3) { g = gq + 3 * (size_t)CNQ;            start = startda; }  // g1da
  else               { g = gq + 3 * (size_t)CNQ + CNDA;     start = startda; }  // g2da
  int s0 = start[grp], s1 = start[grp + 1];
  int t = threadIdx.x;  // 256
  __shared__ float red[256];
  float v = -1e30f;
  for (int i = s0 + t; i < s1; i += 256) v = fmaxf(v, g[i]);
  red[t] = v;
  __syncthreads();
  for (int o = 128; o > 0; o >>= 1) {
    if (t < o) red[t] = fmaxf(red[t], red[t + o]);
    __syncthreads();
  }
  if (t == 0) m[job * 64 + grp] = red[0];
}

// ---------- GAP phase 2: partial weighted sums (grid = groups x chunks) ----------
template <int NG>
__global__ __launch_bounds__(128) void k_gap_partial(
    const float* __restrict__ g0, const float* __restrict__ g1,
    const float* __restrict__ feat, const int* __restrict__ start,
    const float* __restrict__ m,
    float* __restrict__ acc0, float* __restrict__ acc1,
    float* __restrict__ sums) {
  int grp = blockIdx.x;
  int s0 = start[grp], s1 = start[grp + 1];
  int len = s1 - s0;
  if (len <= 0) return;
  int NC = gridDim.y;
  int per = (len + NC - 1) / NC;
  int r0 = s0 + blockIdx.y * per;
  int r1 = min(s1, r0 + per);
  if (r0 >= r1) return;
  int t = threadIdx.x;  // 128 = column
  float m0 = m[grp];
  float m1 = (NG == 2) ? m[64 + grp] : 0.f;
  float a0 = 0.f, a1 = 0.f, sum0 = 0.f, sum1 = 0.f;
  for (int i = r0; i < r1; ++i) {
    float f = feat[(size_t)i * CHD + t];
    float e0 = expf(g0[i] - m0);
    sum0 += e0;
    a0 += e0 * f;
    if (NG == 2) {
      float e1 = expf(g1[i] - m1);
      sum1 += e1;
      a1 += e1 * f;
    }
  }
  atomicAdd(&acc0[grp * CHD + t], a0);
  if (NG == 2) atomicAdd(&acc1[grp * CHD + t], a1);
  if (t == 0) {
    atomicAdd(&sums[grp], sum0);
    if (NG == 2) atomicAdd(&sums[64 + grp], sum1);
  }
}

// ---------- GAP phase 3: normalize, all 5 jobs in one launch ----------
__global__ void k_gap_norm5(float* __restrict__ glq, const float* __restrict__ sbuf) {
  int job = blockIdx.x >> 6, grp = blockIdx.x & 63;
  int t = threadIdx.x;  // 128
  int smap = (job == 1) ? 2 : ((job == 2) ? 1 : job);
  float sv = sbuf[smap * 64 + grp];
  float* acc = glq + (size_t)job * CB * CHD + grp * CHD;
  float v = acc[t];
  acc[t] = (sv > 0.f) ? v / sv : 0.f;
}

// ---------- small matmul (latency-optimized: 8-way batched loads) ----------
__global__ void k_mm_small(const float* __restrict__ X, const float* __restrict__ W,
                           const float* __restrict__ bias, float* __restrict__ Y,
                           int m, int k, int p) {
  int idx = blockIdx.x * blockDim.x + threadIdx.x;
  if (idx >= m * p) return;
  int r = idx / p, c = idx % p;
  const float* xr = X + (size_t)r * k;
  const float* wc = W + c;
  float acc = bias[c];
  int kk = 0;
  for (; kk + 8 <= k; kk += 8) {
    float xv[8], wv[8];
#pragma unroll
    for (int j = 0; j < 8; ++j) {
      xv[j] = xr[kk + j];
      wv[j] = wc[(size_t)(kk + j) * p];
    }
#pragma unroll
    for (int j = 0; j < 8; ++j) acc += xv[j] * wv[j];
  }
  for (; kk < k; ++kk) acc += xr[kk] * wc[(size_t)kk * p];
  Y[idx] = acc;
}

// ---------- BN+elu small (8-way batched row loads) ----------
__global__ void k_bn_elu_small(float* __restrict__ Y, int m, int p) {
  int c = blockIdx.x * blockDim.x + threadIdx.x;
  if (c >= p) return;
  float s = 0.f, s2 = 0.f;
  int i = 0;
  for (; i + 8 <= m; i += 8) {
    float v[8];
#pragma unroll
    for (int j = 0; j < 8; ++j) v[j] = Y[(size_t)(i + j) * p + c];
#pragma unroll
    for (int j = 0; j < 8; ++j) { s += v[j]; s2 += v[j] * v[j]; }
  }
  for (; i < m; ++i) {
    float v = Y[(size_t)i * p + c];
    s += v; s2 += v * v;
  }
  float mu = s / m;
  float var = s2 / m - mu * mu;
  float inv = rsqrtf(var + CEPS);
  i = 0;
  for (; i + 8 <= m; i += 8) {
    float v[8];
#pragma unroll
    for (int j = 0; j < 8; ++j) v[j] = Y[(size_t)(i + j) * p + c];
#pragma unroll
    for (int j = 0; j < 8; ++j) {
      float x = (v[j] - mu) * inv;
      Y[(size_t)(i + j) * p + c] = x > 0.f ? x : expm1f(x);
    }
  }
  for (; i < m; ++i) {
    float x = (Y[(size_t)i * p + c] - mu) * inv;
    Y[(size_t)i * p + c] = x > 0.f ? x : expm1f(x);
  }
}

// ---------- att_comb ----------
__global__ void k_attcomb(const float* __restrict__ k1, const float* __restrict__ k2,
                          const float* __restrict__ Qc, float* __restrict__ a) {
  int grp = blockIdx.x;
  int t = threadIdx.x;  // 64 threads
  float v1 = Qc[t] * k1[grp * CHD + t] + Qc[t + 64] * k1[grp * CHD + t + 64];
  float v2 = Qc[t] * k2[grp * CHD + t] + Qc[t + 64] * k2[grp * CHD + t + 64];
  for (int off = 32; off > 0; off >>= 1) {
    v1 += __shfl_down(v1, off, 64);
    v2 += __shfl_down(v2, off, 64);
  }
  if (t == 0) {
    float mx = fmaxf(v1, v2);
    float e1 = expf(v1 - mx), e2 = expf(v2 - mx);
    float s = e1 + e2;
    a[grp * 2] = e1 / s;
    a[grp * 2 + 1] = e2 / s;
  }
}

// ---------- WQ precompute ----------
__global__ void k_wq(const float* __restrict__ W_L, const float* __restrict__ b_L,
                     const float* __restrict__ Qm, float* __restrict__ WQ,
                     float* __restrict__ bQ) {
  int g = blockIdx.x;  // 64 blocks, 256 threads
  int t = threadIdx.x;
  for (int j = 0; j < 8; ++j) {
    int idx = t + j * 256;
    int d = idx >> 4, c = idx & 15;
    int h = c & 7, off = (c >= 8) ? CEH : 0;
    const float* w = W_L + d * CHD + h * CEH;
    const float* q = Qm + g * 256 + h * 32 + off;
    float acc = 0.f;
#pragma unroll
    for (int e = 0; e < CEH; ++e) acc += w[e] * q[e];
    WQ[g * 2048 + idx] = acc;
  }
  if (t < 16) {
    int c = t, h = c & 7, off = (c >= 8) ? CEH : 0;
    const float* b = b_L + h * CEH;
    const float* q = Qm + g * 256 + h * 32 + off;
    float acc = 0.f;
#pragma unroll
    for (int e = 0; e < CEH; ++e) acc += b[e] * q[e];
    bQ[g * 16 + c] = acc;
  }
}

// ---------- elr ----------
__global__ void k_eler(const float* __restrict__ tmp, const float* __restrict__ WQ,
                       const float* __restrict__ bQ, const int* __restrict__ gid,
                       float* __restrict__ elr, int n) {
  int idx = blockIdx.x * blockDim.x + threadIdx.x;
  if (idx >= n * 16) return;
  int i = idx >> 4, c = idx & 15;
  int g = gid[i];
  const float* wq = WQ + g * 2048 + c;
  const float* row = tmp + (size_t)i * CHD;
  float acc = bQ[g * 16 + c];
#pragma unroll 4
  for (int d = 0; d < CHD; ++d) acc += row[d] * wq[d * 16];
  elr[idx] = acc;
}

// ---------- transpose+cast weights: WT[p][k] = bf16(W[k][p]) ----------
__global__ void k_tcast(const float* __restrict__ W, ushortt* __restrict__ WT,
                        int K, int P) {
  int i = blockIdx.x * blockDim.x + threadIdx.x;
  if (i >= K * P) return;
  int p = i / K, k = i % K;
  stf(&WT[i], W[(size_t)k * P + p]);
}

// ---------- BN prep: stats -> mu / inv ----------
template <int P>
__global__ void k_bn_prep(const float* __restrict__ stats, float* __restrict__ pr, int n) {
  int c = threadIdx.x;
  if (c >= P) return;
  float invn = 1.f / (float)n;
  float mu = stats[c] * invn;
  float var = stats[P + c] * invn - mu * mu;
  pr[c] = mu;
  pr[P + c] = rsqrtf(var + CEPS);
}

// ---------- stats reduce: fold per-wave partials into stats ----------
// grid (TP/256, 64); 4-way unrolled independent accumulators keep loads in flight
template <int TP>
__global__ void k_stats_reduce(const float* __restrict__ pstat, float* __restrict__ stats,
                               int nb) {
  int c = blockIdx.x * blockDim.x + threadIdx.x;
  if (c >= TP) return;
  int NC = gridDim.y;
  int per = (nb + NC - 1) / NC;
  int r0 = blockIdx.y * per;
  int r1 = min(nb, r0 + per);
  if (r0 >= r1) return;
  float s0 = 0.f, s1 = 0.f, s2 = 0.f, s3 = 0.f;
  int r = r0;
  for (; r + 4 <= r1; r += 4) {
    s0 += pstat[(size_t)(r + 0) * TP + c];
    s1 += pstat[(size_t)(r + 1) * TP + c];
    s2 += pstat[(size_t)(r + 2) * TP + c];
    s3 += pstat[(size_t)(r + 3) * TP + c];
  }
  for (; r < r1; ++r) s0 += pstat[(size_t)r * TP + c];
  atomicAdd(&stats[c], (s0 + s1) + (s2 + s3));
}

// ---------- MFMA GEMM: Y(nxP) = X(nxK) @ B + bias; BT is PxK bf16 ----------
// XM: 0 = fp32 plain, 1 = fp32 comb (a0*X0 + a1*X1), 2 = bf16 plain,
//     3 = bf16 with fused BN(mu/inv)+elu on load
// STATS: epilogue writes per-WAVE column sum/sumsq partials to pstat[(bid*4+wave)*2P..]
template <int K, int P, int XM, bool STATS, typename OT>
__global__ __launch_bounds__(256, 2) void k_gemm_mfma(
    const void* __restrict__ X0v, const void* __restrict__ X1v,
    const float* __restrict__ acomb, const int* __restrict__ gid,
    const float* __restrict__ bnmu, const float* __restrict__ bninv,
    const ushortt* __restrict__ BT, const float* __restrict__ bias,
    OT* __restrict__ Y, float* __restrict__ pstat, int n) {
  constexpr int NT = P / 16;
  const int wave = threadIdx.x >> 6, lane = threadIdx.x & 63;
  const int quad = lane >> 4, l16 = lane & 15;
  const int r0w = blockIdx.x * 64 + wave * 16;
  const int rA = r0w + l16;
  const bool rowok = rA < n;
  f32x4 acc[NT];
#pragma unroll
  for (int t = 0; t < NT; ++t) acc[t] = f32x4{0.f, 0.f, 0.f, 0.f};
  float a0 = 0.f, a1 = 0.f;
  if (XM == 1 && rowok) {
    int g = gid[rA];
    a0 = acomb[2 * g];
    a1 = acomb[2 * g + 1];
  }
  for (int k0 = 0; k0 < K; k0 += 32) {
    const int kk = k0 + quad * 8;
    bf16x8 af = {};
    if (rowok) {
      if constexpr (XM == 2) {
        af = *(const bf16x8*)((const ushortt*)X0v + (size_t)rA * K + kk);
      } else if constexpr (XM == 3) {
        bf16x8 raw = *(const bf16x8*)((const ushortt*)X0v + (size_t)rA * K + kk);
#pragma unroll
        for (int j = 0; j < 8; ++j) {
          float v = bf2f(raw[j]);
          v = (v - bnmu[kk + j]) * bninv[kk + j];
          v = v > 0.f ? v : (__expf(v) - 1.f);
          af[j] = f2bf(v);
        }
      } else {
        const float* px = (const float*)X0v + (size_t)rA * K + kk;
        float v[8];
        if constexpr (XM == 1) {
          const float* py = (const float*)X1v + (size_t)rA * K + kk;
#pragma unroll
          for (int j = 0; j < 8; ++j) v[j] = a0 * px[j] + a1 * py[j];
        } else {
#pragma unroll
          for (int j = 0; j < 8; ++j) v[j] = px[j];
        }
#pragma unroll
        for (int j = 0; j < 8; ++j) af[j] = f2bf(v[j]);
      }
    }
    // batch-load all B fragments (keeps NT loads in flight), then MFMA
    bf16x8 bfr[NT];
#pragma unroll
    for (int t = 0; t < NT; ++t)
      bfr[t] = *(const bf16x8*)(BT + (size_t)(t * 16 + l16) * K + kk);
#pragma unroll
    for (int t = 0; t < NT; ++t)
      acc[t] = __builtin_amdgcn_mfma_f32_16x16x32_bf16(af, bfr[t], acc[t], 0, 0, 0);
  }
  float* pw = STATS ? (pstat + ((size_t)blockIdx.x * 4 + wave) * (2 * P)) : nullptr;
#pragma unroll
  for (int t = 0; t < NT; ++t) {
    const int c = t * 16 + l16;
    float b = bias[c];
    float s = 0.f, s2 = 0.f;
#pragma unroll
    for (int r = 0; r < 4; ++r) {
      int gr = r0w + quad * 4 + r;
      if (gr < n) {
        float val = acc[t][r] + b;
        stf(Y + (size_t)gr * P + c, val);
        if constexpr (STATS) {
          float vq = (sizeof(OT) == 2) ? bf2f(f2bf(val)) : val;
          s += vq;
          s2 += vq * vq;
        }
      }
    }
    if constexpr (STATS) {
      s += __shfl_xor(s, 16, 64);
      s += __shfl_xor(s, 32, 64);
      s2 += __shfl_xor(s2, 16, 64);
      s2 += __shfl_xor(s2, 32, 64);
      if (quad == 0) {
        pw[c] = s;
        pw[P + c] = s2;
      }
    }
  }
}

// ---------- CSR build ----------
__global__ void k_count(const int* __restrict__ dst, int* __restrict__ counts, int E) {
  int e = blockIdx.x * blockDim.x + threadIdx.x;
  if (e < E) atomicAdd(&counts[dst[e]], 1);
}
__global__ void k_scan_reduce(const int* __restrict__ counts, int* __restrict__ bsum, int n) {
  __shared__ int red[256];
  int t = threadIdx.x;
  int base = blockIdx.x * 1024;
  int s = 0;
  for (int j = 0; j < 4; ++j) {
    int i = base + t * 4 + j;
    if (i < n) s += counts[i];
  }
  red[t] = s;
  __syncthreads();
  for (int o = 128; o > 0; o >>= 1) {
    if (t < o) red[t] += red[t + o];
    __syncthreads();
  }
  if (t == 0) bsum[blockIdx.x] = red[0];
}
__global__ void k_scan_top(int* __restrict__ bsum, int nb) {
  __shared__ int sh[128];
  int t = threadIdx.x;  // 128 threads
  int v = (t < nb) ? bsum[t] : 0;
  sh[t] = v;
  __syncthreads();
  for (int o = 1; o < 128; o <<= 1) {
    int x = (t >= o) ? sh[t - o] : 0;
    __syncthreads();
    sh[t] += x;
    __syncthreads();
  }
  if (t < nb) bsum[t] = sh[t] - v;  // exclusive
}
__global__ void k_scan_final(const int* __restrict__ counts, const int* __restrict__ bsum,
                             int* __restrict__ rowptr, int n, int E) {
  __shared__ int sh[256];
  int t = threadIdx.x;
  int base = blockIdx.x * 1024;
  int v[4];
  int s = 0;
  for (int j = 0; j < 4; ++j) {
    int i = base + t * 4 + j;
    v[j] = (i < n) ? counts[i] : 0;
    s += v[j];
  }
  sh[t] = s;
  __syncthreads();
  for (int o = 1; o < 256; o <<= 1) {
    int x = (t >= o) ? sh[t - o] : 0;
    __syncthreads();
    sh[t] += x;
    __syncthreads();
  }
  int off = bsum[blockIdx.x] + sh[t] - s;
  for (int j = 0; j < 4; ++j) {
    int i = base + t * 4 + j;
    if (i < n) rowptr[i] = off;
    off += v[j];
  }
  if (blockIdx.x == 0 && t == 0) rowptr[n] = E;
}
__global__ void k_copy_int(const int* __restrict__ a, int* __restrict__ b, int n) {
  int i = blockIdx.x * blockDim.x + threadIdx.x;
  if (i < n) b[i] = a[i];
}
__global__ void k_scatter(const int* __restrict__ dst, const int* __restrict__ srcA,
                          int* __restrict__ cursor, int* __restrict__ csr_src, int E) {
  int e = blockIdx.x * blockDim.x + threadIdx.x;
  if (e >= E) return;
  int d = dst[e];
  int pos = atomicAdd(&cursor[d], 1);
  csr_src[pos] = srcA[e];
}

// ---------- fused softmax aggregation: one wave per node ----------
__global__ __launch_bounds__(256) void k_node_agg(
    const int* __restrict__ rowptr, const int* __restrict__ csr_src,
    const float* __restrict__ elr, const ushortt* __restrict__ ft,
    float* __restrict__ agg, float* __restrict__ mOut, float* __restrict__ sOut, int n) {
  int node = blockIdx.x * 4 + (threadIdx.x >> 6);
  if (node >= n) return;
  int lane = threadIdx.x & 63;
  int h_p = lane & 7;    // head for p-compute role
  int e_loc = lane >> 3; // edge slot (0..7)
  int h_a = lane >> 3;   // head for accumulation role (cols 2*lane, 2*lane+1)
  int s0 = rowptr[node], s1 = rowptr[node + 1];
  if (s1 <= s0) {
    *(float2*)(agg + (size_t)node * CHD + lane * 2) = make_float2(0.f, 0.f);
    if (lane < 8) {
      mOut[(size_t)node * CH + lane] = -1e30f;
      sOut[(size_t)node * CH + lane] = 0.f;
    }
    return;
  }
  float erd_p = elr[(size_t)node * 16 + 8 + h_p];
  // ---- pass 1: max of el over in-edges, per head h_p ----
  float mx = -1e30f;
  for (int base = s0; base < s1; base += 8) {
    int e = base + e_loc;
    if (e < s1) {
      int sj = csr_src[e];
      mx = fmaxf(mx, elr[(size_t)sj * 16 + h_p]);
    }
  }
  mx = fmaxf(mx, __shfl_xor(mx, 8, 64));
  mx = fmaxf(mx, __shfl_xor(mx, 16, 64));
  mx = fmaxf(mx, __shfl_xor(mx, 32, 64));
  float xm = mx + erd_p;
  float m_p = xm >= 0.f ? xm : CSLOPE * xm;  // max of leaky(x) over edges
  // ---- pass 2: p = exp(x - m), weighted feature accumulation ----
  float s_part = 0.f, a0 = 0.f, a1 = 0.f;
  int base = s0;
  // full 8-edge batches: compile-time unrolled -> gather loads batched
  for (; base + 8 <= s1; base += 8) {
    int sj = csr_src[base + e_loc];
    float x = elr[(size_t)sj * 16 + h_p] + erd_p;
    x = x >= 0.f ? x : CSLOPE * x;
    float p = __expf(x - m_p);
    s_part += p;
#pragma unroll
    for (int e = 0; e < 8; ++e) {
      float pe = __shfl(p, e * 8 + h_a, 64);
      int se = __shfl(sj, e * 8, 64);
      unsigned ftv = *(const unsigned*)(ft + (size_t)se * CHD + lane * 2);
      a0 += pe * __uint_as_float(ftv << 16);
      a1 += pe * __uint_as_float(ftv & 0xffff0000u);
    }
  }
  // tail batch (guarded)
  if (base < s1) {
    int cnt = s1 - base;
    int sj = 0;
    float p = 0.f;
    if (e_loc < cnt) {
      sj = csr_src[base + e_loc];
      float x = elr[(size_t)sj * 16 + h_p] + erd_p;
      x = x >= 0.f ? x : CSLOPE * x;
      p = __expf(x - m_p);
      s_part += p;
    }
    for (int e = 0; e < cnt; ++e) {
      float pe = __shfl(p, e * 8 + h_a, 64);
      int se = __shfl(sj, e * 8, 64);
      unsigned ftv = *(const unsigned*)(ft + (size_t)se * CHD + lane * 2);
      a0 += pe * __uint_as_float(ftv << 16);
      a1 += pe * __uint_as_float(ftv & 0xffff0000u);
    }
  }
  s_part += __shfl_xor(s_part, 8, 64);
  s_part += __shfl_xor(s_part, 16, 64);
  s_part += __shfl_xor(s_part, 32, 64);
  float s_acc = __shfl(s_part, h_a, 64);  // lane h_a holds head h_p == h_a
  float inv = 1.f / s_acc;
  float2 o;
  o.x = a0 * inv;
  o.y = a1 * inv;
  *(float2*)(agg + (size_t)node * CHD + lane * 2) = o;
  if (lane < 8) {
    mOut[(size_t)node * CH + lane] = m_p;
    sOut[(size_t)node * CH + lane] = s_part;
  }
}

// ---------- BN apply + elu (+ residual) ----------
template <int P, bool RESID, typename T>
__global__ void k_bn_apply(T* __restrict__ Y, const float* __restrict__ stats,
                           const float* __restrict__ hlast, int n) {
  size_t idx = (size_t)blockIdx.x * blockDim.x + threadIdx.x;
  if (idx >= (size_t)n * P) return;
  int c = (int)(idx % P);
  float invn = 1.f / (float)n;
  float mu = stats[c] * invn;
  float var = stats[P + c] * invn - mu * mu;
  float v = (ldf(Y + idx) - mu) * rsqrtf(var + CEPS);
  v = v > 0.f ? v : expm1f(v);
  if (RESID) v += hlast[idx];
  stf(Y + idx, v);
}

// ---------- attention recompute for loss ----------
__device__ __forceinline__ float attn_val(int e, int h, const int* __restrict__ src,
                                          const int* __restrict__ dst,
                                          const float* __restrict__ elr,
                                          const float* __restrict__ mOut,
                                          const float* __restrict__ sOut) {
  int ss = src[e], sd = dst[e];
  float x = elr[(size_t)ss * 16 + h] + elr[(size_t)sd * 16 + 8 + h];
  x = x >= 0.f ? x : CSLOPE * x;
  return expf(x - mOut[(size_t)sd * CH + h]) / sOut[(size_t)sd * CH + h];
}

// per-block partials (no global atomics)
__global__ void k_pd(const int* __restrict__ src, const int* __restrict__ dst,
                     const float* __restrict__ elr, const float* __restrict__ mOut,
                     const float* __restrict__ sOut, const int* __restrict__ PEid,
                     const int* __restrict__ DEid, float* __restrict__ pdp,
                     int nPE, int nDE) {
  __shared__ float part[CH];
  if (threadIdx.x < CH) part[threadIdx.x] = 0.f;
  __syncthreads();
  int idx = blockIdx.x * blockDim.x + threadIdx.x;
  int j = idx >> 3, h = idx & 7;
  float acc = 0.f;
  if (j < nPE) acc += attn_val(PEid[j], h, src, dst, elr, mOut, sOut);
  if (j < nDE) acc -= attn_val(DEid[j], h, src, dst, elr, mOut, sOut);
  atomicAdd(&part[h], acc);
  __syncthreads();
  if (threadIdx.x < CH) pdp[(size_t)blockIdx.x * CH + threadIdx.x] = part[threadIdx.x];
}
__global__ void k_loss(const float* __restrict__ pdp, int nb,
                       const int* __restrict__ lenMn, float* __restrict__ out) {
  __shared__ float part[CH];
  int t = threadIdx.x;  // 256
  if (t < CH) part[t] = 0.f;
  __syncthreads();
  int h = t & 7;
  float acc = 0.f;
  for (int j = t >> 3; j < nb; j += 32) acc += pdp[(size_t)j * CH + h];
  atomicAdd(&part[h], acc);
  __syncthreads();
  if (t == 0) {
    float len = (float)lenMn[0];
    float s = 0.f;
    for (int hh = 0; hh < CH; ++hh) s += part[hh] / len;
    out[0] = -s / (float)CH;
  }
}

// ---------- branch driver ----------
static void run_branch(int n, int E, const float* h_last, const float* h0,
                       const int* src, const int* dst, const int* gid,
                       const float* acomb, const float* WQ, const float* bQ,
                       const ushortt* W_LT, const float* b_L,
                       const ushortt* W1T, const float* end_b1,
                       const ushortt* W2T, const float* end_b2,
                       float* U, float* elr, float* mOut, float* sOut,
                       int* counts, int* rowptr, int* cursor, int* csr_src, int* bsum,
                       float* stats /*1024: [0..511]=BN256, [512..1023]=BN128*/,
                       float* bnpr /*512*/, float* pstat, float* out, hipStream_t stream) {
  ushortt* ftB = (ushortt*)U;   // n x 128 bf16
  ushortt* y1B = (ushortt*)U;   // n x 256 bf16 (ft dead by then)
  float* stats1 = stats;
  float* stats2 = stats + 512;
  int nChunks = (n + 1023) / 1024;
  int nbG = (n + 63) / 64;      // gemm grid blocks
  int nbW = nbG * 4;            // per-wave stats partial rows
  // CSR build
  zero_launch(counts, n, stream);
  zero_launch(stats, 1024, stream);
  hipLaunchKernelGGL(k_count, dim3((E + 255) / 256), dim3(256), 0, stream, dst, counts, E);
  hipLaunchKernelGGL(k_scan_reduce, dim3(nChunks), dim3(256), 0, stream, counts, bsum, n);
  hipLaunchKernelGGL(k_scan_top, dim3(1), dim3(128), 0, stream, bsum, nChunks);
  hipLaunchKernelGGL(k_scan_final, dim3(nChunks), dim3(256), 0, stream, counts, bsum, rowptr, n, E);
  hipLaunchKernelGGL(k_copy_int, dim3((n + 255) / 256), dim3(256), 0, stream, rowptr, cursor, n);
  hipLaunchKernelGGL(k_scatter, dim3((E + 255) / 256), dim3(256), 0, stream, dst, src, cursor, csr_src, E);
  // elr
  hipLaunchKernelGGL(k_eler, dim3((n * 16 + 255) / 256), dim3(256), 0, stream,
                     h_last, WQ, bQ, gid, elr, n);
  // ft = (a0*h0 + a1*h_last) @ W_L + b_L -> bf16
  hipLaunchKernelGGL((k_gemm_mfma<128, 128, 1, false, ushortt>), dim3(nbG),
                     dim3(256), 0, stream, h0, h_last, acomb, gid,
                     (const float*)nullptr, (const float*)nullptr,
                     W_LT, b_L, ftB, (float*)nullptr, n);
  // fused softmax aggregation
  hipLaunchKernelGGL(k_node_agg, dim3((n + 3) / 4), dim3(256), 0, stream,
                     rowptr, csr_src, elr, ftB, out, mOut, sOut, n);
  // end FNN layer 1 (raw pre-BN bf16 out; per-wave stats partials in epilogue)
  hipLaunchKernelGGL((k_gemm_mfma<128, 256, 0, true, ushortt>), dim3(nbG),
                     dim3(256), 0, stream, out, (const void*)nullptr,
                     (const float*)nullptr, (const int*)nullptr,
                     (const float*)nullptr, (const float*)nullptr,
                     W1T, end_b1, y1B, pstat, n);
  hipLaunchKernelGGL((k_stats_reduce<512>), dim3(2, 64), dim3(256), 0, stream,
                     pstat, stats1, nbW);
  hipLaunchKernelGGL((k_bn_prep<256>), dim3(1), dim3(256), 0, stream, stats1, bnpr, n);
  // layer 2 with fused BN+elu on load; per-wave stats partials for final BN
  hipLaunchKernelGGL((k_gemm_mfma<256, 128, 3, true, float>), dim3(nbG),
                     dim3(256), 0, stream, y1B, (const void*)nullptr,
                     (const float*)nullptr, (const int*)nullptr,
                     bnpr, bnpr + 256,
                     W2T, end_b2, out, pstat, n);
  hipLaunchKernelGGL((k_stats_reduce<256>), dim3(1, 64), dim3(256), 0, stream,
                     pstat, stats2, nbW);
  hipLaunchKernelGGL((k_bn_apply<128, true, float>),
                     dim3((int)(((size_t)n * 128 + 255) / 256)), dim3(256), 0, stream,
                     out, stats2, h_last, n);
}

extern "C" void kernel_launch(void* const* d_in, const int* in_sizes, int n_in,
                              void* d_out, int out_size, void* d_ws, size_t ws_size,
                              hipStream_t stream) {
  const float* h_da_last = (const float*)d_in[0];
  const float* h_q_last  = (const float*)d_in[1];
  const float* h_da_0    = (const float*)d_in[2];
  const float* h_q_0     = (const float*)d_in[3];
  const float* W_L       = (const float*)d_in[4];
  const float* b_L       = (const float*)d_in[5];
  const float* gateq_W   = (const float*)d_in[6];
  const float* gateq_b   = (const float*)d_in[7];
  const float* gate1_W   = (const float*)d_in[8];
  const float* gate1_b   = (const float*)d_in[9];
  const float* gate2_W   = (const float*)d_in[10];
  const float* gate2_b   = (const float*)d_in[11];
  const float* Q_comb    = (const float*)d_in[12];
  const float* Qf_W1     = (const float*)d_in[13];
  const float* Qf_b1     = (const float*)d_in[14];
  const float* Qf_W2     = (const float*)d_in[15];
  const float* Qf_b2     = (const float*)d_in[16];
  const float* end_W1    = (const float*)d_in[17];
  const float* end_b1    = (const float*)d_in[18];
  const float* end_W2    = (const float*)d_in[19];
  const float* end_b2    = (const float*)d_in[20];
  const int* src_da = (const int*)d_in[21];
  const int* dst_da = (const int*)d_in[22];
  const int* src_q  = (const int*)d_in[23];
  const int* dst_q  = (const int*)d_in[24];
  const int* gid_da = (const int*)d_in[25];
  const int* gid_q  = (const int*)d_in[26];
  const int* PEid   = (const int*)d_in[27];
  const int* DEid   = (const int*)d_in[28];
  const int* len_Mn = (const int*)d_in[29];

  float* out_da   = (float*)d_out;
  float* out_q    = (float*)d_out + (size_t)CNDA * CHD;
  float* out_loss = (float*)d_out + (size_t)CNDA * CHD + (size_t)CNQ * CHD;

  // ---- workspace arena (float units), ~84 MB ----
  float* ws = (float*)d_ws;
  size_t off = 0;
  auto alloc = [&](size_t cnt) { float* p = ws + off; off += cnt; return p; };
  float* U    = alloc((size_t)CNDA * 128);   // ft bf16 n*128 / y1 bf16 n*256 union
  float* elr  = alloc((size_t)CNDA * 16);
  float* mOut = alloc((size_t)CNDA * CH);
  float* sOut = alloc((size_t)CNDA * CH);
  int* counts  = (int*)alloc(CNDA);
  int* rowptr  = (int*)alloc(CNDA + 4);
  int* cursor  = (int*)alloc(CNDA);
  int* csr_src = (int*)alloc(CEDA);
  int* bsum    = (int*)alloc(128);
  ushortt* W_LT = (ushortt*)alloc(128 * 128 / 2);
  ushortt* W1T  = (ushortt*)alloc(128 * 256 / 2);
  ushortt* W2T  = (ushortt*)alloc(256 * 128 / 2);
  float* WQ   = alloc((size_t)CB * 2048);
  float* bQ   = alloc((size_t)CB * 16);
  // NOTE: gq..g2da must stay consecutive (k_gmax5 indexes off gq)
  float* gq   = alloc(CNQ);
  float* g1q  = alloc(CNQ);
  float* g2q  = alloc(CNQ);
  float* g1da = alloc(CNDA);
  float* g2da = alloc(CNDA);
  // NOTE: glq..k2da must stay consecutive (zeroed as one region; k_gap_norm5)
  float* glq  = alloc(CB * CHD);
  float* k1q  = alloc(CB * CHD);
  float* k2q  = alloc(CB * CHD);
  float* k1da = alloc(CB * CHD);
  float* k2da = alloc(CB * CHD);
  float* Qt   = alloc(CB * 256);
  float* Qm   = alloc(CB * 256);
  float* acq  = alloc(CB * 2);
  float* acda = alloc(CB * 2);
  float* stats = alloc(1024);     // [0..511] BN256 stats, [512..1023] BN128 stats
  float* bnpr  = alloc(512);      // mu/inv for BN256
  float* mbuf  = alloc(5 * 64);   // [gq, g2q, g1q, g1da, g2da]
  float* sbuf  = alloc(5 * 64);   // same order
  int* startq  = (int*)alloc(68);
  int* startda = (int*)alloc(68);
  float* pstat = alloc(((size_t)(CNDA + 63) / 64) * 4 * 512);  // per-WAVE stats partials
  float* pdp   = alloc(((size_t)CNDA * CH + 255) / 256 * CH);  // k_pd partials
  (void)ws_size; (void)n_in; (void)out_size;

  // ---- weight transposes (bf16) ----
  hipLaunchKernelGGL(k_tcast, dim3((128 * 128 + 255) / 256), dim3(256), 0, stream, W_L, W_LT, 128, 128);
  hipLaunchKernelGGL(k_tcast, dim3((128 * 256 + 255) / 256), dim3(256), 0, stream, end_W1, W1T, 128, 256);
  hipLaunchKernelGGL(k_tcast, dim3((256 * 128 + 255) / 256), dim3(256), 0, stream, end_W2, W2T, 256, 128);

  // ---- group boundaries ----
  hipLaunchKernelGGL(k_binit, dim3(1), dim3(128), 0, stream, startq, CNQ);
  hipLaunchKernelGGL(k_binit, dim3(1), dim3(128), 0, stream, startda, CNDA);
  hipLaunchKernelGGL(k_bmark, dim3((CNQ + 255) / 256), dim3(256), 0, stream, gid_q, CNQ, startq);
  hipLaunchKernelGGL(k_bmark, dim3((CNDA + 255) / 256), dim3(256), 0, stream, gid_da, CNDA, startda);
  hipLaunchKernelGGL(k_bfix, dim3(1), dim3(64), 0, stream, startq);
  hipLaunchKernelGGL(k_bfix, dim3(1), dim3(64), 0, stream, startda);

  // ---- gate dots ----
  hipLaunchKernelGGL(k_gate_dot2, dim3((CNQ + 3) / 4), dim3(256), 0, stream,
                     h_q_last, gateq_W, gateq_b, gate2_W, gate2_b, gq, g2q, CNQ);
  hipLaunchKernelGGL(k_gate_dot, dim3((CNQ + 3) / 4), dim3(256), 0, stream, h_q_0, gate1_W, gate1_b, g1q, CNQ);
  hipLaunchKernelGGL(k_gate_dot, dim3((CNDA + 3) / 4), dim3(256), 0, stream, h_da_0, gate1_W, gate1_b, g1da, CNDA);
  hipLaunchKernelGGL(k_gate_dot, dim3((CNDA + 3) / 4), dim3(256), 0, stream, h_da_last, gate2_W, gate2_b, g2da, CNDA);

  // ---- GAPs (parallel 3-phase segmented softmax-pool) ----
  hipLaunchKernelGGL(k_gmax5, dim3(5 * CB), dim3(256), 0, stream, gq, startq, startda, mbuf);
  zero_launch(glq, 5 * (size_t)CB * CHD, stream);
  zero_launch(sbuf, 5 * 64, stream);
  hipLaunchKernelGGL((k_gap_partial<2>), dim3(CB, 32), dim3(128), 0, stream,
                     gq, g2q, h_q_last, startq, mbuf + 0, glq, k2q, sbuf + 0);
  hipLaunchKernelGGL((k_gap_partial<1>), dim3(CB, 32), dim3(128), 0, stream,
                     g1q, (const float*)nullptr, h_q_0, startq, mbuf + 128,
                     k1q, (float*)nullptr, sbuf + 128);
  hipLaunchKernelGGL((k_gap_partial<1>), dim3(CB, 32), dim3(128), 0, stream,
                     g1da, (const float*)nullptr, h_da_0, startda, mbuf + 192,
                     k1da, (float*)nullptr, sbuf + 192);
  hipLaunchKernelGGL((k_gap_partial<1>), dim3(CB, 32), dim3(128), 0, stream,
                     g2da, (const float*)nullptr, h_da_last, startda, mbuf + 256,
                     k2da, (float*)nullptr, sbuf + 256);
  hipLaunchKernelGGL(k_gap_norm5, dim3(5 * CB), dim3(128), 0, stream, glq, sbuf);

  // ---- Q = fnn(glq) ----
  hipLaunchKernelGGL(k_mm_small, dim3((CB * 256 + 255) / 256), dim3(256), 0, stream,
                     glq, Qf_W1, Qf_b1, Qt, CB, 128, 256);
  hipLaunchKernelGGL(k_bn_elu_small, dim3(1), dim3(256), 0, stream, Qt, CB, 256);
  hipLaunchKernelGGL(k_mm_small, dim3((CB * 256 + 255) / 256), dim3(256), 0, stream,
                     Qt, Qf_W2, Qf_b2, Qm, CB, 256, 256);
  hipLaunchKernelGGL(k_bn_elu_small, dim3(1), dim3(256), 0, stream, Qm, CB, 256);

  // ---- projected per-group Q matrices ----
  hipLaunchKernelGGL(k_wq, dim3(CB), dim3(256), 0, stream, W_L, b_L, Qm, WQ, bQ);

  // ---- att_comb scalars ----
  hipLaunchKernelGGL(k_attcomb, dim3(CB), dim3(64), 0, stream, k1q, k2q, Q_comb, acq);
  hipLaunchKernelGGL(k_attcomb, dim3(CB), dim3(64), 0, stream, k1da, k2da, Q_comb, acda);

  // ---- q branch ----
  run_branch(CNQ, CEQ, h_q_last, h_q_0, src_q, dst_q, gid_q, acq, WQ, bQ,
             W_LT, b_L, W1T, end_b1, W2T, end_b2,
             U, elr, mOut, sOut, counts, rowptr, cursor, csr_src, bsum,
             stats, bnpr, pstat, out_q, stream);

  // ---- da branch (elr/mOut/sOut end holding da state for the loss) ----
  run_branch(CNDA, CEDA, h_da_last, h_da_0, src_da, dst_da, gid_da, acda, WQ, bQ,
             W_LT, b_L, W1T, end_b1, W2T, end_b2,
             U, elr, mOut, sOut, counts, rowptr, cursor, csr_src, bsum,
             stats, bnpr, pstat, out_da, stream);

  // ---- loss from recomputed a_da ----
  int nPE = in_sizes[27], nDE = in_sizes[28];
  int nMax = nPE > nDE ? nPE : nDE;
  int nbPD = (nMax * CH + 255) / 256;
  hipLaunchKernelGGL(k_pd, dim3(nbPD), dim3(256), 0, stream,
                     src_da, dst_da, elr, mOut, sOut, PEid, DEid, pdp, nPE, nDE);
  hipLaunchKernelGGL(k_loss, dim3(1), dim3(256), 0, stream, pdp, nbPD, len_Mn, out_loss);
}

// Round 8
// 1102.035 us; speedup vs baseline: 1.3462x; 1.0371x over previous
//
#include <hip/hip_runtime.h>
#include <math.h>

// ---- problem constants ----
static constexpr int CB   = 64;      // groups
static constexpr int CH   = 8;       // heads
static constexpr int CEH  = 16;      // per-head dim
static constexpr int CHD  = 128;     // hidden dim
static constexpr int CNDA = 100000;
static constexpr int CNQ  = 20000;
static constexpr int CEDA = 1000000;
static constexpr int CEQ  = 200000;
static constexpr float CEPS = 1e-5f;
static constexpr float CSLOPE = 2.0f;

typedef unsigned short ushortt;
typedef __attribute__((ext_vector_type(8))) short bf16x8;
typedef __attribute__((ext_vector_type(4))) float f32x4;

// ---------- bf16 helpers ----------
__device__ __forceinline__ float ldf(const float* p) { return *p; }
__device__ __forceinline__ float ldf(const ushortt* p) {
  return __uint_as_float(((unsigned)*p) << 16);
}
__device__ __forceinline__ void stf(float* p, float v) { *p = v; }
__device__ __forceinline__ void stf(ushortt* p, float v) {
  unsigned u = __float_as_uint(v);
  u += 0x7fff + ((u >> 16) & 1);  // RNE
  *p = (ushortt)(u >> 16);
}
__device__ __forceinline__ short f2bf(float v) {
  unsigned u = __float_as_uint(v);
  u += 0x7fff + ((u >> 16) & 1);
  return (short)(u >> 16);
}
__device__ __forceinline__ float bf2f(short b) {
  return __uint_as_float(((unsigned)(ushortt)b) << 16);
}
// order-preserving float<->uint encoding (for atomicMax on floats)
__device__ __forceinline__ unsigned fenc(float f) {
  unsigned b = __float_as_uint(f);
  return (b & 0x80000000u) ? ~b : (b | 0x80000000u);
}
__device__ __forceinline__ float fdec(unsigned u) {
  unsigned b = (u & 0x80000000u) ? (u ^ 0x80000000u) : ~u;
  return __uint_as_float(b);
}

// ---------- utility ----------
__global__ void k_zero(float* __restrict__ p, long n) {
  long i = (long)blockIdx.x * blockDim.x + threadIdx.x;
  long stride = (long)gridDim.x * blockDim.x;
  for (; i < n; i += stride) p[i] = 0.f;
}
static inline void zero_launch(void* p, long n, hipStream_t s) {
  long b = (n + 255) / 256;
  int blocks = (int)(b > 4096 ? 4096 : (b < 1 ? 1 : b));
  hipLaunchKernelGGL(k_zero, dim3(blocks), dim3(256), 0, s, (float*)p, n);
}

// ---------- group boundaries (gid sorted) ----------
__global__ void k_binit(int* start, int n) {
  int i = threadIdx.x;
  if (i <= CB) start[i] = n;
}
__global__ void k_bmark(const int* __restrict__ gid, int n, int* __restrict__ start) {
  int i = blockIdx.x * blockDim.x + threadIdx.x;
  if (i >= n) return;
  int g = gid[i];
  if (i == 0 || gid[i - 1] != g) atomicMin(&start[g], i);
}
__global__ void k_bfix(int* start) {
  if (threadIdx.x == 0) {
    for (int g = CB - 1; g >= 0; --g)
      if (start[g] > start[g + 1]) start[g] = start[g + 1];
  }
}

// ---------- gate dot (one gate) ----------
__global__ void k_gate_dot(const float* __restrict__ feat, const float* __restrict__ gw,
                           const float* __restrict__ gb, float* __restrict__ g, int n) {
  int wave = (blockIdx.x * blockDim.x + threadIdx.x) >> 6;
  int lane = threadIdx.x & 63;
  if (wave >= n) return;
  const float* row = feat + (size_t)wave * CHD;
  float v = row[lane] * gw[lane] + row[lane + 64] * gw[lane + 64];
  for (int off = 32; off > 0; off >>= 1) v += __shfl_down(v, off, 64);
  if (lane == 0) g[wave] = v + gb[0];
}

// ---------- gate dot (two gates, shared feat read) ----------
__global__ void k_gate_dot2(const float* __restrict__ feat,
                            const float* __restrict__ w1, const float* __restrict__ b1,
                            const float* __restrict__ w2, const float* __restrict__ b2,
                            float* __restrict__ g1, float* __restrict__ g2, int n) {
  int wave = (blockIdx.x * blockDim.x + threadIdx.x) >> 6;
  int lane = threadIdx.x & 63;
  if (wave >= n) return;
  const float* row = feat + (size_t)wave * CHD;
  float r0 = row[lane], r1 = row[lane + 64];
  float v1 = r0 * w1[lane] + r1 * w1[lane + 64];
  float v2 = r0 * w2[lane] + r1 * w2[lane + 64];
  for (int off = 32; off > 0; off >>= 1) {
    v1 += __shfl_down(v1, off, 64);
    v2 += __shfl_down(v2, off, 64);
  }
  if (lane == 0) {
    g1[wave] = v1 + b1[0];
    g2[wave] = v2 + b2[0];
  }
}

// ---------- GAP phase 1: per-group max of g, all 5 jobs in one launch ----------
__global__ void k_gmax5(const float* __restrict__ gq, const int* __restrict__ startq,
                        const int* __restrict__ startda, float* __restrict__ m) {
  int job = blockIdx.x >> 6, grp = blockIdx.x & 63;
  const float* g;
  const int* start;
  if (job == 0)      { g = gq;                              start = startq; }
  else if (job == 1) { g = gq + 2 * (size_t)CNQ;            start = startq; }   // g2q
  else if (job == 2) { g = gq + (size_t)CNQ;                start = startq; }   // g1q
  else if (job == 3) { g = gq + 3 * (size_t)CNQ;            start = startda; }  // g1da
  else               { g = gq + 3 * (size_t)CNQ + CNDA;     start = startda; }  // g2da
  int s0 = start[grp], s1 = start[grp + 1];
  int t = threadIdx.x;  // 256
  __shared__ float red[256];
  float v = -1e30f;
  for (int i = s0 + t; i < s1; i += 256) v = fmaxf(v, g[i]);
  red[t] = v;
  __syncthreads();
  for (int o = 128; o > 0; o >>= 1) {
    if (t < o) red[t] = fmaxf(red[t], red[t + o]);
    __syncthreads();
  }
  if (t == 0) m[job * 64 + grp] = red[0];
}

// ---------- GAP phase 2: partial weighted sums (grid = groups x chunks) ----------
template <int NG>
__global__ __launch_bounds__(128) void k_gap_partial(
    const float* __restrict__ g0, const float* __restrict__ g1,
    const float* __restrict__ feat, const int* __restrict__ start,
    const float* __restrict__ m,
    float* __restrict__ acc0, float* __restrict__ acc1,
    float* __restrict__ sums) {
  int grp = blockIdx.x;
  int s0 = start[grp], s1 = start[grp + 1];
  int len = s1 - s0;
  if (len <= 0) return;
  int NC = gridDim.y;
  int per = (len + NC - 1) / NC;
  int r0 = s0 + blockIdx.y * per;
  int r1 = min(s1, r0 + per);
  if (r0 >= r1) return;
  int t = threadIdx.x;  // 128 = column
  float m0 = m[grp];
  float m1 = (NG == 2) ? m[64 + grp] : 0.f;
  float a0 = 0.f, a1 = 0.f, sum0 = 0.f, sum1 = 0.f;
  for (int i = r0; i < r1; ++i) {
    float f = feat[(size_t)i * CHD + t];
    float e0 = __expf(g0[i] - m0);
    sum0 += e0;
    a0 += e0 * f;
    if (NG == 2) {
      float e1 = __expf(g1[i] - m1);
      sum1 += e1;
      a1 += e1 * f;
    }
  }
  atomicAdd(&acc0[grp * CHD + t], a0);
  if (NG == 2) atomicAdd(&acc1[grp * CHD + t], a1);
  if (t == 0) {
    atomicAdd(&sums[grp], sum0);
    if (NG == 2) atomicAdd(&sums[64 + grp], sum1);
  }
}

// ---------- GAP phase 3: normalize, all 5 jobs in one launch ----------
__global__ void k_gap_norm5(float* __restrict__ glq, const float* __restrict__ sbuf) {
  int job = blockIdx.x >> 6, grp = blockIdx.x & 63;
  int t = threadIdx.x;  // 128
  int smap = (job == 1) ? 2 : ((job == 2) ? 1 : job);
  float sv = sbuf[smap * 64 + grp];
  float* acc = glq + (size_t)job * CB * CHD + grp * CHD;
  float v = acc[t];
  acc[t] = (sv > 0.f) ? v / sv : 0.f;
}

// ---------- small matmul (latency-optimized: 8-way batched loads) ----------
__global__ void k_mm_small(const float* __restrict__ X, const float* __restrict__ W,
                           const float* __restrict__ bias, float* __restrict__ Y,
                           int m, int k, int p) {
  int idx = blockIdx.x * blockDim.x + threadIdx.x;
  if (idx >= m * p) return;
  int r = idx / p, c = idx % p;
  const float* xr = X + (size_t)r * k;
  const float* wc = W + c;
  float acc = bias[c];
  int kk = 0;
  for (; kk + 8 <= k; kk += 8) {
    float xv[8], wv[8];
#pragma unroll
    for (int j = 0; j < 8; ++j) {
      xv[j] = xr[kk + j];
      wv[j] = wc[(size_t)(kk + j) * p];
    }
#pragma unroll
    for (int j = 0; j < 8; ++j) acc += xv[j] * wv[j];
  }
  for (; kk < k; ++kk) acc += xr[kk] * wc[(size_t)kk * p];
  Y[idx] = acc;
}

// ---------- BN+elu small (8-way batched row loads) ----------
__global__ void k_bn_elu_small(float* __restrict__ Y, int m, int p) {
  int c = blockIdx.x * blockDim.x + threadIdx.x;
  if (c >= p) return;
  float s = 0.f, s2 = 0.f;
  int i = 0;
  for (; i + 8 <= m; i += 8) {
    float v[8];
#pragma unroll
    for (int j = 0; j < 8; ++j) v[j] = Y[(size_t)(i + j) * p + c];
#pragma unroll
    for (int j = 0; j < 8; ++j) { s += v[j]; s2 += v[j] * v[j]; }
  }
  for (; i < m; ++i) {
    float v = Y[(size_t)i * p + c];
    s += v; s2 += v * v;
  }
  float mu = s / m;
  float var = s2 / m - mu * mu;
  float inv = rsqrtf(var + CEPS);
  i = 0;
  for (; i + 8 <= m; i += 8) {
    float v[8];
#pragma unroll
    for (int j = 0; j < 8; ++j) v[j] = Y[(size_t)(i + j) * p + c];
#pragma unroll
    for (int j = 0; j < 8; ++j) {
      float x = (v[j] - mu) * inv;
      Y[(size_t)(i + j) * p + c] = x > 0.f ? x : expm1f(x);
    }
  }
  for (; i < m; ++i) {
    float x = (Y[(size_t)i * p + c] - mu) * inv;
    Y[(size_t)i * p + c] = x > 0.f ? x : expm1f(x);
  }
}

// ---------- att_comb ----------
__global__ void k_attcomb(const float* __restrict__ k1, const float* __restrict__ k2,
                          const float* __restrict__ Qc, float* __restrict__ a) {
  int grp = blockIdx.x;
  int t = threadIdx.x;  // 64 threads
  float v1 = Qc[t] * k1[grp * CHD + t] + Qc[t + 64] * k1[grp * CHD + t + 64];
  float v2 = Qc[t] * k2[grp * CHD + t] + Qc[t + 64] * k2[grp * CHD + t + 64];
  for (int off = 32; off > 0; off >>= 1) {
    v1 += __shfl_down(v1, off, 64);
    v2 += __shfl_down(v2, off, 64);
  }
  if (t == 0) {
    float mx = fmaxf(v1, v2);
    float e1 = expf(v1 - mx), e2 = expf(v2 - mx);
    float s = e1 + e2;
    a[grp * 2] = e1 / s;
    a[grp * 2 + 1] = e2 / s;
  }
}

// ---------- WQ precompute ----------
__global__ void k_wq(const float* __restrict__ W_L, const float* __restrict__ b_L,
                     const float* __restrict__ Qm, float* __restrict__ WQ,
                     float* __restrict__ bQ) {
  int g = blockIdx.x;  // 64 blocks, 256 threads
  int t = threadIdx.x;
  for (int j = 0; j < 8; ++j) {
    int idx = t + j * 256;
    int d = idx >> 4, c = idx & 15;
    int h = c & 7, off = (c >= 8) ? CEH : 0;
    const float* w = W_L + d * CHD + h * CEH;
    const float* q = Qm + g * 256 + h * 32 + off;
    float acc = 0.f;
#pragma unroll
    for (int e = 0; e < CEH; ++e) acc += w[e] * q[e];
    WQ[g * 2048 + idx] = acc;
  }
  if (t < 16) {
    int c = t, h = c & 7, off = (c >= 8) ? CEH : 0;
    const float* b = b_L + h * CEH;
    const float* q = Qm + g * 256 + h * 32 + off;
    float acc = 0.f;
#pragma unroll
    for (int e = 0; e < CEH; ++e) acc += b[e] * q[e];
    bQ[g * 16 + c] = acc;
  }
}

// ---------- elr ----------
__global__ void k_eler(const float* __restrict__ tmp, const float* __restrict__ WQ,
                       const float* __restrict__ bQ, const int* __restrict__ gid,
                       float* __restrict__ elr, int n) {
  int idx = blockIdx.x * blockDim.x + threadIdx.x;
  if (idx >= n * 16) return;
  int i = idx >> 4, c = idx & 15;
  int g = gid[i];
  const float* wq = WQ + g * 2048 + c;
  const float* row = tmp + (size_t)i * CHD;
  float acc = bQ[g * 16 + c];
#pragma unroll 4
  for (int d = 0; d < CHD; ++d) acc += row[d] * wq[d * 16];
  elr[idx] = acc;
}

// ---------- global per-head max of el (cols 0..7 of elr) ----------
__global__ void k_elmax(const float* __restrict__ elr, unsigned* __restrict__ mgl, int n) {
  int h = blockIdx.x;      // 0..7
  int chunk = blockIdx.y;  // 0..31
  int per = (n + 31) / 32;
  int i0 = chunk * per, i1 = min(n, i0 + per);
  int t = threadIdx.x;  // 256
  __shared__ float red[256];
  float v = -1e30f;
  for (int i = i0 + t; i < i1; i += 256) v = fmaxf(v, elr[(size_t)i * 16 + h]);
  red[t] = v;
  __syncthreads();
  for (int o = 128; o > 0; o >>= 1) {
    if (t < o) red[t] = fmaxf(red[t], red[t + o]);
    __syncthreads();
  }
  if (t == 0) atomicMax(&mgl[h], fenc(red[0]));
}

// ---------- transpose+cast weights: WT[p][k] = bf16(W[k][p]) ----------
__global__ void k_tcast(const float* __restrict__ W, ushortt* __restrict__ WT,
                        int K, int P) {
  int i = blockIdx.x * blockDim.x + threadIdx.x;
  if (i >= K * P) return;
  int p = i / K, k = i % K;
  stf(&WT[i], W[(size_t)k * P + p]);
}

// ---------- BN prep: stats -> mu / inv ----------
template <int P>
__global__ void k_bn_prep(const float* __restrict__ stats, float* __restrict__ pr, int n) {
  int c = threadIdx.x;
  if (c >= P) return;
  float invn = 1.f / (float)n;
  float mu = stats[c] * invn;
  float var = stats[P + c] * invn - mu * mu;
  pr[c] = mu;
  pr[P + c] = rsqrtf(var + CEPS);
}

// ---------- stats reduce: fold per-wave partials into stats ----------
template <int TP>
__global__ void k_stats_reduce(const float* __restrict__ pstat, float* __restrict__ stats,
                               int nb) {
  int c = blockIdx.x * blockDim.x + threadIdx.x;
  if (c >= TP) return;
  int NC = gridDim.y;
  int per = (nb + NC - 1) / NC;
  int r0 = blockIdx.y * per;
  int r1 = min(nb, r0 + per);
  if (r0 >= r1) return;
  float s0 = 0.f, s1 = 0.f, s2 = 0.f, s3 = 0.f;
  int r = r0;
  for (; r + 4 <= r1; r += 4) {
    s0 += pstat[(size_t)(r + 0) * TP + c];
    s1 += pstat[(size_t)(r + 1) * TP + c];
    s2 += pstat[(size_t)(r + 2) * TP + c];
    s3 += pstat[(size_t)(r + 3) * TP + c];
  }
  for (; r < r1; ++r) s0 += pstat[(size_t)r * TP + c];
  atomicAdd(&stats[c], (s0 + s1) + (s2 + s3));
}

// ---------- MFMA GEMM: Y(nxP) = X(nxK) @ B + bias; BT is PxK bf16 ----------
// XM: 0 = fp32 plain, 1 = fp32 comb (a0*X0 + a1*X1), 2 = bf16 plain,
//     3 = bf16 with fused BN(mu/inv)+elu on load
// STATS: epilogue writes per-WAVE column sum/sumsq partials to pstat[(bid*4+wave)*2P..]
template <int K, int P, int XM, bool STATS, typename OT>
__global__ __launch_bounds__(256, 2) void k_gemm_mfma(
    const void* __restrict__ X0v, const void* __restrict__ X1v,
    const float* __restrict__ acomb, const int* __restrict__ gid,
    const float* __restrict__ bnmu, const float* __restrict__ bninv,
    const ushortt* __restrict__ BT, const float* __restrict__ bias,
    OT* __restrict__ Y, float* __restrict__ pstat, int n) {
  constexpr int NT = P / 16;
  const int wave = threadIdx.x >> 6, lane = threadIdx.x & 63;
  const int quad = lane >> 4, l16 = lane & 15;
  const int r0w = blockIdx.x * 64 + wave * 16;
  const int rA = r0w + l16;
  const bool rowok = rA < n;
  f32x4 acc[NT];
#pragma unroll
  for (int t = 0; t < NT; ++t) acc[t] = f32x4{0.f, 0.f, 0.f, 0.f};
  float a0 = 0.f, a1 = 0.f;
  if (XM == 1 && rowok) {
    int g = gid[rA];
    a0 = acomb[2 * g];
    a1 = acomb[2 * g + 1];
  }
  for (int k0 = 0; k0 < K; k0 += 32) {
    const int kk = k0 + quad * 8;
    bf16x8 af = {};
    if (rowok) {
      if constexpr (XM == 2) {
        af = *(const bf16x8*)((const ushortt*)X0v + (size_t)rA * K + kk);
      } else if constexpr (XM == 3) {
        bf16x8 raw = *(const bf16x8*)((const ushortt*)X0v + (size_t)rA * K + kk);
#pragma unroll
        for (int j = 0; j < 8; ++j) {
          float v = bf2f(raw[j]);
          v = (v - bnmu[kk + j]) * bninv[kk + j];
          v = v > 0.f ? v : (__expf(v) - 1.f);
          af[j] = f2bf(v);
        }
      } else {
        const float* px = (const float*)X0v + (size_t)rA * K + kk;
        float v[8];
        if constexpr (XM == 1) {
          const float* py = (const float*)X1v + (size_t)rA * K + kk;
#pragma unroll
          for (int j = 0; j < 8; ++j) v[j] = a0 * px[j] + a1 * py[j];
        } else {
#pragma unroll
          for (int j = 0; j < 8; ++j) v[j] = px[j];
        }
#pragma unroll
        for (int j = 0; j < 8; ++j) af[j] = f2bf(v[j]);
      }
    }
    // batch-load all B fragments (keeps NT loads in flight), then MFMA
    bf16x8 bfr[NT];
#pragma unroll
    for (int t = 0; t < NT; ++t)
      bfr[t] = *(const bf16x8*)(BT + (size_t)(t * 16 + l16) * K + kk);
#pragma unroll
    for (int t = 0; t < NT; ++t)
      acc[t] = __builtin_amdgcn_mfma_f32_16x16x32_bf16(af, bfr[t], acc[t], 0, 0, 0);
  }
  float* pw = STATS ? (pstat + ((size_t)blockIdx.x * 4 + wave) * (2 * P)) : nullptr;
#pragma unroll
  for (int t = 0; t < NT; ++t) {
    const int c = t * 16 + l16;
    float b = bias[c];
    float s = 0.f, s2 = 0.f;
#pragma unroll
    for (int r = 0; r < 4; ++r) {
      int gr = r0w + quad * 4 + r;
      if (gr < n) {
        float val = acc[t][r] + b;
        stf(Y + (size_t)gr * P + c, val);
        if constexpr (STATS) {
          float vq = (sizeof(OT) == 2) ? bf2f(f2bf(val)) : val;
          s += vq;
          s2 += vq * vq;
        }
      }
    }
    if constexpr (STATS) {
      s += __shfl_xor(s, 16, 64);
      s += __shfl_xor(s, 32, 64);
      s2 += __shfl_xor(s2, 16, 64);
      s2 += __shfl_xor(s2, 32, 64);
      if (quad == 0) {
        pw[c] = s;
        pw[P + c] = s2;
      }
    }
  }
}

// ---------- CSR build ----------
__global__ void k_count(const int* __restrict__ dst, int* __restrict__ counts, int E) {
  int e = blockIdx.x * blockDim.x + threadIdx.x;
  if (e < E) atomicAdd(&counts[dst[e]], 1);
}
__global__ void k_scan_reduce(const int* __restrict__ counts, int* __restrict__ bsum, int n) {
  __shared__ int red[256];
  int t = threadIdx.x;
  int base = blockIdx.x * 1024;
  int s = 0;
  for (int j = 0; j < 4; ++j) {
    int i = base + t * 4 + j;
    if (i < n) s += counts[i];
  }
  red[t] = s;
  __syncthreads();
  for (int o = 128; o > 0; o >>= 1) {
    if (t < o) red[t] += red[t + o];
    __syncthreads();
  }
  if (t == 0) bsum[blockIdx.x] = red[0];
}
__global__ void k_scan_top(int* __restrict__ bsum, int nb) {
  __shared__ int sh[128];
  int t = threadIdx.x;  // 128 threads
  int v = (t < nb) ? bsum[t] : 0;
  sh[t] = v;
  __syncthreads();
  for (int o = 1; o < 128; o <<= 1) {
    int x = (t >= o) ? sh[t - o] : 0;
    __syncthreads();
    sh[t] += x;
    __syncthreads();
  }
  if (t < nb) bsum[t] = sh[t] - v;  // exclusive
}
__global__ void k_scan_final(const int* __restrict__ counts, const int* __restrict__ bsum,
                             int* __restrict__ rowptr, int n, int E) {
  __shared__ int sh[256];
  int t = threadIdx.x;
  int base = blockIdx.x * 1024;
  int v[4];
  int s = 0;
  for (int j = 0; j < 4; ++j) {
    int i = base + t * 4 + j;
    v[j] = (i < n) ? counts[i] : 0;
    s += v[j];
  }
  sh[t] = s;
  __syncthreads();
  for (int o = 1; o < 256; o <<= 1) {
    int x = (t >= o) ? sh[t - o] : 0;
    __syncthreads();
    sh[t] += x;
    __syncthreads();
  }
  int off = bsum[blockIdx.x] + sh[t] - s;
  for (int j = 0; j < 4; ++j) {
    int i = base + t * 4 + j;
    if (i < n) rowptr[i] = off;
    off += v[j];
  }
  if (blockIdx.x == 0 && t == 0) rowptr[n] = E;
}
__global__ void k_copy_int(const int* __restrict__ a, int* __restrict__ b, int n) {
  int i = blockIdx.x * blockDim.x + threadIdx.x;
  if (i < n) b[i] = a[i];
}
__global__ void k_scatter(const int* __restrict__ dst, const int* __restrict__ srcA,
                          int* __restrict__ cursor, int* __restrict__ csr_src, int E) {
  int e = blockIdx.x * blockDim.x + threadIdx.x;
  if (e >= E) return;
  int d = dst[e];
  int pos = atomicAdd(&cursor[d], 1);
  csr_src[pos] = srcA[e];
}

// ---------- fused softmax aggregation v3: one wave per node ----------
// m = leaky(global_head_max(el) + er) >= true row max (softmax shift-invariant),
// so the per-row max pass is eliminated. Uniform padded 8-edge batches.
__global__ __launch_bounds__(256) void k_node_agg(
    const int* __restrict__ rowptr, const int* __restrict__ csr_src,
    const float* __restrict__ elr, const unsigned* __restrict__ mgl,
    const ushortt* __restrict__ ft,
    float* __restrict__ agg, float* __restrict__ mOut, float* __restrict__ sOut, int n) {
  int node = blockIdx.x * 4 + (threadIdx.x >> 6);
  if (node >= n) return;
  int lane = threadIdx.x & 63;
  int h_p = lane & 7;    // head for p-compute role
  int e_loc = lane >> 3; // edge slot (0..7)
  int h_a = lane >> 3;   // head for accumulation role (cols 2*lane, 2*lane+1)
  int s0 = rowptr[node], s1 = rowptr[node + 1];
  if (s1 <= s0) {
    *(float2*)(agg + (size_t)node * CHD + lane * 2) = make_float2(0.f, 0.f);
    if (lane < 8) {
      mOut[(size_t)node * CH + lane] = -1e30f;
      sOut[(size_t)node * CH + lane] = 0.f;
    }
    return;
  }
  float erd_p = elr[(size_t)node * 16 + 8 + h_p];
  float xm = fdec(mgl[h_p]) + erd_p;
  float m_p = xm >= 0.f ? xm : CSLOPE * xm;  // upper bound on leaky(x) over edges
  // ---- single pass: p = exp(x - m), weighted feature accumulation ----
  float s_part = 0.f, a0 = 0.f, a1 = 0.f;
  for (int base = s0; base < s1; base += 8) {
    int cnt = s1 - base;
    int sj = 0;
    float p = 0.f;
    if (e_loc < cnt) {
      sj = csr_src[base + e_loc];
      float x = elr[(size_t)sj * 16 + h_p] + erd_p;
      x = x >= 0.f ? x : CSLOPE * x;
      p = __expf(x - m_p);
      s_part += p;
    }
#pragma unroll
    for (int e = 0; e < 8; ++e) {
      float pe = __shfl(p, e * 8 + h_a, 64);
      int se = __shfl(sj, e * 8, 64);
      unsigned ftv = *(const unsigned*)(ft + (size_t)se * CHD + lane * 2);
      a0 += pe * __uint_as_float(ftv << 16);
      a1 += pe * __uint_as_float(ftv & 0xffff0000u);
    }
  }
  s_part += __shfl_xor(s_part, 8, 64);
  s_part += __shfl_xor(s_part, 16, 64);
  s_part += __shfl_xor(s_part, 32, 64);
  float s_acc = __shfl(s_part, h_a, 64);  // lane h_a holds head h_p == h_a
  float inv = 1.f / s_acc;
  float2 o;
  o.x = a0 * inv;
  o.y = a1 * inv;
  *(float2*)(agg + (size_t)node * CHD + lane * 2) = o;
  if (lane < 8) {
    mOut[(size_t)node * CH + lane] = m_p;
    sOut[(size_t)node * CH + lane] = s_part;
  }
}

// ---------- BN apply + elu + residual, float4-vectorized (P=128) ----------
__global__ void k_bn_apply_f4(float* __restrict__ Y, const float* __restrict__ stats,
                              const float* __restrict__ hlast, int n) {
  int idx = blockIdx.x * blockDim.x + threadIdx.x;
  if (idx >= n * 32) return;  // 32 float4 groups per row
  int cg = (idx & 31) * 4;
  float invn = 1.f / (float)n;
  float4 y = ((const float4*)Y)[idx];
  float4 hl = ((const float4*)hlast)[idx];
  float yy[4] = {y.x, y.y, y.z, y.w};
  float hh[4] = {hl.x, hl.y, hl.z, hl.w};
  float o[4];
#pragma unroll
  for (int j = 0; j < 4; ++j) {
    float mu = stats[cg + j] * invn;
    float var = stats[128 + cg + j] * invn - mu * mu;
    float v = (yy[j] - mu) * rsqrtf(var + CEPS);
    v = v > 0.f ? v : (__expf(v) - 1.f);
    o[j] = v + hh[j];
  }
  ((float4*)Y)[idx] = make_float4(o[0], o[1], o[2], o[3]);
}

// ---------- attention recompute for loss ----------
__device__ __forceinline__ float attn_val(int e, int h, const int* __restrict__ src,
                                          const int* __restrict__ dst,
                                          const float* __restrict__ elr,
                                          const float* __restrict__ mOut,
                                          const float* __restrict__ sOut) {
  int ss = src[e], sd = dst[e];
  float x = elr[(size_t)ss * 16 + h] + elr[(size_t)sd * 16 + 8 + h];
  x = x >= 0.f ? x : CSLOPE * x;
  return __expf(x - mOut[(size_t)sd * CH + h]) / sOut[(size_t)sd * CH + h];
}

// per-block partials (no global atomics)
__global__ void k_pd(const int* __restrict__ src, const int* __restrict__ dst,
                     const float* __restrict__ elr, const float* __restrict__ mOut,
                     const float* __restrict__ sOut, const int* __restrict__ PEid,
                     const int* __restrict__ DEid, float* __restrict__ pdp,
                     int nPE, int nDE) {
  __shared__ float part[CH];
  if (threadIdx.x < CH) part[threadIdx.x] = 0.f;
  __syncthreads();
  int idx = blockIdx.x * blockDim.x + threadIdx.x;
  int j = idx >> 3, h = idx & 7;
  float acc = 0.f;
  if (j < nPE) acc += attn_val(PEid[j], h, src, dst, elr, mOut, sOut);
  if (j < nDE) acc -= attn_val(DEid[j], h, src, dst, elr, mOut, sOut);
  atomicAdd(&part[h], acc);
  __syncthreads();
  if (threadIdx.x < CH) pdp[(size_t)blockIdx.x * CH + threadIdx.x] = part[threadIdx.x];
}
__global__ void k_loss(const float* __restrict__ pdp, int nb,
                       const int* __restrict__ lenMn, float* __restrict__ out) {
  __shared__ float part[CH];
  int t = threadIdx.x;  // 256
  if (t < CH) part[t] = 0.f;
  __syncthreads();
  int h = t & 7;
  float acc = 0.f;
  for (int j = t >> 3; j < nb; j += 32) acc += pdp[(size_t)j * CH + h];
  atomicAdd(&part[h], acc);
  __syncthreads();
  if (t == 0) {
    float len = (float)lenMn[0];
    float s = 0.f;
    for (int hh = 0; hh < CH; ++hh) s += part[hh] / len;
    out[0] = -s / (float)CH;
  }
}

// ---------- branch driver ----------
static void run_branch(int n, int E, const float* h_last, const float* h0,
                       const int* src, const int* dst, const int* gid,
                       const float* acomb, const float* WQ, const float* bQ,
                       const ushortt* W_LT, const float* b_L,
                       const ushortt* W1T, const float* end_b1,
                       const ushortt* W2T, const float* end_b2,
                       float* U, float* elr, unsigned* mgl, float* mOut, float* sOut,
                       int* counts, int* rowptr, int* cursor, int* csr_src, int* bsum,
                       float* stats /*1024: [0..511]=BN256, [512..1023]=BN128*/,
                       float* bnpr /*512*/, float* pstat, float* out, hipStream_t stream) {
  ushortt* ftB = (ushortt*)U;   // n x 128 bf16
  ushortt* y1B = (ushortt*)U;   // n x 256 bf16 (ft dead by then)
  float* stats1 = stats;
  float* stats2 = stats + 512;
  int nChunks = (n + 1023) / 1024;
  int nbG = (n + 63) / 64;      // gemm grid blocks
  int nbW = nbG * 4;            // per-wave stats partial rows
  // CSR build
  zero_launch(counts, n, stream);
  zero_launch(stats, 1024, stream);
  zero_launch(mgl, 8, stream);
  hipLaunchKernelGGL(k_count, dim3((E + 255) / 256), dim3(256), 0, stream, dst, counts, E);
  hipLaunchKernelGGL(k_scan_reduce, dim3(nChunks), dim3(256), 0, stream, counts, bsum, n);
  hipLaunchKernelGGL(k_scan_top, dim3(1), dim3(128), 0, stream, bsum, nChunks);
  hipLaunchKernelGGL(k_scan_final, dim3(nChunks), dim3(256), 0, stream, counts, bsum, rowptr, n, E);
  hipLaunchKernelGGL(k_copy_int, dim3((n + 255) / 256), dim3(256), 0, stream, rowptr, cursor, n);
  hipLaunchKernelGGL(k_scatter, dim3((E + 255) / 256), dim3(256), 0, stream, dst, src, cursor, csr_src, E);
  // elr + global per-head el max
  hipLaunchKernelGGL(k_eler, dim3((n * 16 + 255) / 256), dim3(256), 0, stream,
                     h_last, WQ, bQ, gid, elr, n);
  hipLaunchKernelGGL(k_elmax, dim3(8, 32), dim3(256), 0, stream, elr, mgl, n);
  // ft = (a0*h0 + a1*h_last) @ W_L + b_L -> bf16
  hipLaunchKernelGGL((k_gemm_mfma<128, 128, 1, false, ushortt>), dim3(nbG),
                     dim3(256), 0, stream, h0, h_last, acomb, gid,
                     (const float*)nullptr, (const float*)nullptr,
                     W_LT, b_L, ftB, (float*)nullptr, n);
  // fused softmax aggregation
  hipLaunchKernelGGL(k_node_agg, dim3((n + 3) / 4), dim3(256), 0, stream,
                     rowptr, csr_src, elr, mgl, ftB, out, mOut, sOut, n);
  // end FNN layer 1 (raw pre-BN bf16 out; per-wave stats partials in epilogue)
  hipLaunchKernelGGL((k_gemm_mfma<128, 256, 0, true, ushortt>), dim3(nbG),
                     dim3(256), 0, stream, out, (const void*)nullptr,
                     (const float*)nullptr, (const int*)nullptr,
                     (const float*)nullptr, (const float*)nullptr,
                     W1T, end_b1, y1B, pstat, n);
  hipLaunchKernelGGL((k_stats_reduce<512>), dim3(2, 64), dim3(256), 0, stream,
                     pstat, stats1, nbW);
  hipLaunchKernelGGL((k_bn_prep<256>), dim3(1), dim3(256), 0, stream, stats1, bnpr, n);
  // layer 2 with fused BN+elu on load; per-wave stats partials for final BN
  hipLaunchKernelGGL((k_gemm_mfma<256, 128, 3, true, float>), dim3(nbG),
                     dim3(256), 0, stream, y1B, (const void*)nullptr,
                     (const float*)nullptr, (const int*)nullptr,
                     bnpr, bnpr + 256,
                     W2T, end_b2, out, pstat, n);
  hipLaunchKernelGGL((k_stats_reduce<256>), dim3(1, 64), dim3(256), 0, stream,
                     pstat, stats2, nbW);
  hipLaunchKernelGGL(k_bn_apply_f4, dim3((n * 32 + 255) / 256), dim3(256), 0, stream,
                     out, stats2, h_last, n);
}

extern "C" void kernel_launch(void* const* d_in, const int* in_sizes, int n_in,
                              void* d_out, int out_size, void* d_ws, size_t ws_size,
                              hipStream_t stream) {
  const float* h_da_last = (const float*)d_in[0];
  const float* h_q_last  = (const float*)d_in[1];
  const float* h_da_0    = (const float*)d_in[2];
  const float* h_q_0     = (const float*)d_in[3];
  const float* W_L       = (const float*)d_in[4];
  const float* b_L       = (const float*)d_in[5];
  const float* gateq_W   = (const float*)d_in[6];
  const float* gateq_b   = (const float*)d_in[7];
  const float* gate1_W   = (const float*)d_in[8];
  const float* gate1_b   = (const float*)d_in[9];
  const float* gate2_W   = (const float*)d_in[10];
  const float* gate2_b   = (const float*)d_in[11];
  const float* Q_comb    = (const float*)d_in[12];
  const float* Qf_W1     = (const float*)d_in[13];
  const float* Qf_b1     = (const float*)d_in[14];
  const float* Qf_W2     = (const float*)d_in[15];
  const float* Qf_b2     = (const float*)d_in[16];
  const float* end_W1    = (const float*)d_in[17];
  const float* end_b1    = (const float*)d_in[18];
  const float* end_W2    = (const float*)d_in[19];
  const float* end_b2    = (const float*)d_in[20];
  const int* src_da = (const int*)d_in[21];
  const int* dst_da = (const int*)d_in[22];
  const int* src_q  = (const int*)d_in[23];
  const int* dst_q  = (const int*)d_in[24];
  const int* gid_da = (const int*)d_in[25];
  const int* gid_q  = (const int*)d_in[26];
  const int* PEid   = (const int*)d_in[27];
  const int* DEid   = (const int*)d_in[28];
  const int* len_Mn = (const int*)d_in[29];

  float* out_da   = (float*)d_out;
  float* out_q    = (float*)d_out + (size_t)CNDA * CHD;
  float* out_loss = (float*)d_out + (size_t)CNDA * CHD + (size_t)CNQ * CHD;

  // ---- workspace arena (float units), ~84 MB ----
  float* ws = (float*)d_ws;
  size_t off = 0;
  auto alloc = [&](size_t cnt) { float* p = ws + off; off += cnt; return p; };
  float* U    = alloc((size_t)CNDA * 128);   // ft bf16 n*128 / y1 bf16 n*256 union
  float* elr  = alloc((size_t)CNDA * 16);
  float* mOut = alloc((size_t)CNDA * CH);
  float* sOut = alloc((size_t)CNDA * CH);
  int* counts  = (int*)alloc(CNDA);
  int* rowptr  = (int*)alloc(CNDA + 4);
  int* cursor  = (int*)alloc(CNDA);
  int* csr_src = (int*)alloc(CEDA);
  int* bsum    = (int*)alloc(128);
  ushortt* W_LT = (ushortt*)alloc(128 * 128 / 2);
  ushortt* W1T  = (ushortt*)alloc(128 * 256 / 2);
  ushortt* W2T  = (ushortt*)alloc(256 * 128 / 2);
  float* WQ   = alloc((size_t)CB * 2048);
  float* bQ   = alloc((size_t)CB * 16);
  // NOTE: gq..g2da must stay consecutive (k_gmax5 indexes off gq)
  float* gq   = alloc(CNQ);
  float* g1q  = alloc(CNQ);
  float* g2q  = alloc(CNQ);
  float* g1da = alloc(CNDA);
  float* g2da = alloc(CNDA);
  // NOTE: glq..k2da must stay consecutive (zeroed as one region; k_gap_norm5)
  float* glq  = alloc(CB * CHD);
  float* k1q  = alloc(CB * CHD);
  float* k2q  = alloc(CB * CHD);
  float* k1da = alloc(CB * CHD);
  float* k2da = alloc(CB * CHD);
  float* Qt   = alloc(CB * 256);
  float* Qm   = alloc(CB * 256);
  float* acq  = alloc(CB * 2);
  float* acda = alloc(CB * 2);
  float* stats = alloc(1024);     // [0..511] BN256 stats, [512..1023] BN128 stats
  float* bnpr  = alloc(512);      // mu/inv for BN256
  unsigned* mgl = (unsigned*)alloc(8);  // encoded global per-head el max
  float* mbuf  = alloc(5 * 64);   // [gq, g2q, g1q, g1da, g2da]
  float* sbuf  = alloc(5 * 64);   // same order
  int* startq  = (int*)alloc(68);
  int* startda = (int*)alloc(68);
  float* pstat = alloc(((size_t)(CNDA + 63) / 64) * 4 * 512);  // per-WAVE stats partials
  float* pdp   = alloc(((size_t)CNDA * CH + 255) / 256 * CH);  // k_pd partials
  (void)ws_size; (void)n_in; (void)out_size;

  // ---- weight transposes (bf16) ----
  hipLaunchKernelGGL(k_tcast, dim3((128 * 128 + 255) / 256), dim3(256), 0, stream, W_L, W_LT, 128, 128);
  hipLaunchKernelGGL(k_tcast, dim3((128 * 256 + 255) / 256), dim3(256), 0, stream, end_W1, W1T, 128, 256);
  hipLaunchKernelGGL(k_tcast, dim3((256 * 128 + 255) / 256), dim3(256), 0, stream, end_W2, W2T, 256, 128);

  // ---- group boundaries ----
  hipLaunchKernelGGL(k_binit, dim3(1), dim3(128), 0, stream, startq, CNQ);
  hipLaunchKernelGGL(k_binit, dim3(1), dim3(128), 0, stream, startda, CNDA);
  hipLaunchKernelGGL(k_bmark, dim3((CNQ + 255) / 256), dim3(256), 0, stream, gid_q, CNQ, startq);
  hipLaunchKernelGGL(k_bmark, dim3((CNDA + 255) / 256), dim3(256), 0, stream, gid_da, CNDA, startda);
  hipLaunchKernelGGL(k_bfix, dim3(1), dim3(64), 0, stream, startq);
  hipLaunchKernelGGL(k_bfix, dim3(1), dim3(64), 0, stream, startda);

  // ---- gate dots ----
  hipLaunchKernelGGL(k_gate_dot2, dim3((CNQ + 3) / 4), dim3(256), 0, stream,
                     h_q_last, gateq_W, gateq_b, gate2_W, gate2_b, gq, g2q, CNQ);
  hipLaunchKernelGGL(k_gate_dot, dim3((CNQ + 3) / 4), dim3(256), 0, stream, h_q_0, gate1_W, gate1_b, g1q, CNQ);
  hipLaunchKernelGGL(k_gate_dot, dim3((CNDA + 3) / 4), dim3(256), 0, stream, h_da_0, gate1_W, gate1_b, g1da, CNDA);
  hipLaunchKernelGGL(k_gate_dot, dim3((CNDA + 3) / 4), dim3(256), 0, stream, h_da_last, gate2_W, gate2_b, g2da, CNDA);

  // ---- GAPs (parallel 3-phase segmented softmax-pool) ----
  hipLaunchKernelGGL(k_gmax5, dim3(5 * CB), dim3(256), 0, stream, gq, startq, startda, mbuf);
  zero_launch(glq, 5 * (size_t)CB * CHD, stream);
  zero_launch(sbuf, 5 * 64, stream);
  hipLaunchKernelGGL((k_gap_partial<2>), dim3(CB, 32), dim3(128), 0, stream,
                     gq, g2q, h_q_last, startq, mbuf + 0, glq, k2q, sbuf + 0);
  hipLaunchKernelGGL((k_gap_partial<1>), dim3(CB, 32), dim3(128), 0, stream,
                     g1q, (const float*)nullptr, h_q_0, startq, mbuf + 128,
                     k1q, (float*)nullptr, sbuf + 128);
  hipLaunchKernelGGL((k_gap_partial<1>), dim3(CB, 32), dim3(128), 0, stream,
                     g1da, (const float*)nullptr, h_da_0, startda, mbuf + 192,
                     k1da, (float*)nullptr, sbuf + 192);
  hipLaunchKernelGGL((k_gap_partial<1>), dim3(CB, 32), dim3(128), 0, stream,
                     g2da, (const float*)nullptr, h_da_last, startda, mbuf + 256,
                     k2da, (float*)nullptr, sbuf + 256);
  hipLaunchKernelGGL(k_gap_norm5, dim3(5 * CB), dim3(128), 0, stream, glq, sbuf);

  // ---- Q = fnn(glq) ----
  hipLaunchKernelGGL(k_mm_small, dim3((CB * 256 + 255) / 256), dim3(256), 0, stream,
                     glq, Qf_W1, Qf_b1, Qt, CB, 128, 256);
  hipLaunchKernelGGL(k_bn_elu_small, dim3(1), dim3(256), 0, stream, Qt, CB, 256);
  hipLaunchKernelGGL(k_mm_small, dim3((CB * 256 + 255) / 256), dim3(256), 0, stream,
                     Qt, Qf_W2, Qf_b2, Qm, CB, 256, 256);
  hipLaunchKernelGGL(k_bn_elu_small, dim3(1), dim3(256), 0, stream, Qm, CB, 256);

  // ---- projected per-group Q matrices ----
  hipLaunchKernelGGL(k_wq, dim3(CB), dim3(256), 0, stream, W_L, b_L, Qm, WQ, bQ);

  // ---- att_comb scalars ----
  hipLaunchKernelGGL(k_attcomb, dim3(CB), dim3(64), 0, stream, k1q, k2q, Q_comb, acq);
  hipLaunchKernelGGL(k_attcomb, dim3(CB), dim3(64), 0, stream, k1da, k2da, Q_comb, acda);

  // ---- q branch ----
  run_branch(CNQ, CEQ, h_q_last, h_q_0, src_q, dst_q, gid_q, acq, WQ, bQ,
             W_LT, b_L, W1T, end_b1, W2T, end_b2,
             U, elr, mgl, mOut, sOut, counts, rowptr, cursor, csr_src, bsum,
             stats, bnpr, pstat, out_q, stream);

  // ---- da branch (elr/mOut/sOut end holding da state for the loss) ----
  run_branch(CNDA, CEDA, h_da_last, h_da_0, src_da, dst_da, gid_da, acda, WQ, bQ,
             W_LT, b_L, W1T, end_b1, W2T, end_b2,
             U, elr, mgl, mOut, sOut, counts, rowptr, cursor, csr_src, bsum,
             stats, bnpr, pstat, out_da, stream);

  // ---- loss from recomputed a_da ----
  int nPE = in_sizes[27], nDE = in_sizes[28];
  int nMax = nPE > nDE ? nPE : nDE;
  int nbPD = (nMax * CH + 255) / 256;
  hipLaunchKernelGGL(k_pd, dim3(nbPD), dim3(256), 0, stream,
                     src_da, dst_da, elr, mOut, sOut, PEid, DEid, pdp, nPE, nDE);
  hipLaunchKernelGGL(k_loss, dim3(1), dim3(256), 0, stream, pdp, nbPD, len_Mn, out_loss);
}

// Round 9
// 1070.159 us; speedup vs baseline: 1.3863x; 1.0298x over previous
//
#include <hip/hip_runtime.h>
#include <math.h>

// ---- problem constants ----
static constexpr int CB   = 64;      // groups
static constexpr int CH   = 8;       // heads
static constexpr int CEH  = 16;      // per-head dim
static constexpr int CHD  = 128;     // hidden dim
static constexpr int CNDA = 100000;
static constexpr int CNQ  = 20000;
static constexpr int CEDA = 1000000;
static constexpr int CEQ  = 200000;
static constexpr float CEPS = 1e-5f;
static constexpr float CSLOPE = 2.0f;

typedef unsigned short ushortt;
typedef __attribute__((ext_vector_type(8))) short bf16x8;
typedef __attribute__((ext_vector_type(4))) float f32x4;

// ---------- bf16 helpers ----------
__device__ __forceinline__ float ldf(const float* p) { return *p; }
__device__ __forceinline__ float ldf(const ushortt* p) {
  return __uint_as_float(((unsigned)*p) << 16);
}
__device__ __forceinline__ void stf(float* p, float v) { *p = v; }
__device__ __forceinline__ void stf(ushortt* p, float v) {
  unsigned u = __float_as_uint(v);
  u += 0x7fff + ((u >> 16) & 1);  // RNE
  *p = (ushortt)(u >> 16);
}
__device__ __forceinline__ short f2bf(float v) {
  unsigned u = __float_as_uint(v);
  u += 0x7fff + ((u >> 16) & 1);
  return (short)(u >> 16);
}
__device__ __forceinline__ float bf2f(short b) {
  return __uint_as_float(((unsigned)(ushortt)b) << 16);
}
// order-preserving float<->uint encoding (for atomicMax on floats)
__device__ __forceinline__ unsigned fenc(float f) {
  unsigned b = __float_as_uint(f);
  return (b & 0x80000000u) ? ~b : (b | 0x80000000u);
}
__device__ __forceinline__ float fdec(unsigned u) {
  unsigned b = (u & 0x80000000u) ? (u ^ 0x80000000u) : ~u;
  return __uint_as_float(b);
}

// ---------- utility ----------
__global__ void k_zero(float* __restrict__ p, long n) {
  long i = (long)blockIdx.x * blockDim.x + threadIdx.x;
  long stride = (long)gridDim.x * blockDim.x;
  for (; i < n; i += stride) p[i] = 0.f;
}
static inline void zero_launch(void* p, long n, hipStream_t s) {
  long b = (n + 255) / 256;
  int blocks = (int)(b > 4096 ? 4096 : (b < 1 ? 1 : b));
  hipLaunchKernelGGL(k_zero, dim3(blocks), dim3(256), 0, s, (float*)p, n);
}

// ---------- group boundaries (gid sorted) ----------
__global__ void k_binit(int* start, int n) {
  int i = threadIdx.x;
  if (i <= CB) start[i] = n;
}
__global__ void k_bmark(const int* __restrict__ gid, int n, int* __restrict__ start) {
  int i = blockIdx.x * blockDim.x + threadIdx.x;
  if (i >= n) return;
  int g = gid[i];
  if (i == 0 || gid[i - 1] != g) atomicMin(&start[g], i);
}
__global__ void k_bfix(int* start) {
  if (threadIdx.x == 0) {
    for (int g = CB - 1; g >= 0; --g)
      if (start[g] > start[g + 1]) start[g] = start[g + 1];
  }
}

// ---------- gate dot (one gate) ----------
__global__ void k_gate_dot(const float* __restrict__ feat, const float* __restrict__ gw,
                           const float* __restrict__ gb, float* __restrict__ g, int n) {
  int wave = (blockIdx.x * blockDim.x + threadIdx.x) >> 6;
  int lane = threadIdx.x & 63;
  if (wave >= n) return;
  const float* row = feat + (size_t)wave * CHD;
  float v = row[lane] * gw[lane] + row[lane + 64] * gw[lane + 64];
  for (int off = 32; off > 0; off >>= 1) v += __shfl_down(v, off, 64);
  if (lane == 0) g[wave] = v + gb[0];
}

// ---------- gate dot (two gates, shared feat read) ----------
__global__ void k_gate_dot2(const float* __restrict__ feat,
                            const float* __restrict__ w1, const float* __restrict__ b1,
                            const float* __restrict__ w2, const float* __restrict__ b2,
                            float* __restrict__ g1, float* __restrict__ g2, int n) {
  int wave = (blockIdx.x * blockDim.x + threadIdx.x) >> 6;
  int lane = threadIdx.x & 63;
  if (wave >= n) return;
  const float* row = feat + (size_t)wave * CHD;
  float r0 = row[lane], r1 = row[lane + 64];
  float v1 = r0 * w1[lane] + r1 * w1[lane + 64];
  float v2 = r0 * w2[lane] + r1 * w2[lane + 64];
  for (int off = 32; off > 0; off >>= 1) {
    v1 += __shfl_down(v1, off, 64);
    v2 += __shfl_down(v2, off, 64);
  }
  if (lane == 0) {
    g1[wave] = v1 + b1[0];
    g2[wave] = v2 + b2[0];
  }
}

// ---------- GAP phase 1: per-group max of g, all 5 jobs in one launch ----------
__global__ void k_gmax5(const float* __restrict__ gq, const int* __restrict__ startq,
                        const int* __restrict__ startda, float* __restrict__ m) {
  int job = blockIdx.x >> 6, grp = blockIdx.x & 63;
  const float* g;
  const int* start;
  if (job == 0)      { g = gq;                              start = startq; }
  else if (job == 1) { g = gq + 2 * (size_t)CNQ;            start = startq; }   // g2q
  else if (job == 2) { g = gq + (size_t)CNQ;                start = startq; }   // g1q
  else if (job == 3) { g = gq + 3 * (size_t)CNQ;            start = startda; }  // g1da
  else               { g = gq + 3 * (size_t)CNQ + CNDA;     start = startda; }  // g2da
  int s0 = start[grp], s1 = start[grp + 1];
  int t = threadIdx.x;  // 256
  __shared__ float red[256];
  float v = -1e30f;
  for (int i = s0 + t; i < s1; i += 256) v = fmaxf(v, g[i]);
  red[t] = v;
  __syncthreads();
  for (int o = 128; o > 0; o >>= 1) {
    if (t < o) red[t] = fmaxf(red[t], red[t + o]);
    __syncthreads();
  }
  if (t == 0) m[job * 64 + grp] = red[0];
}

// ---------- GAP phase 2: partial weighted sums (grid = groups x chunks) ----------
template <int NG>
__global__ __launch_bounds__(128) void k_gap_partial(
    const float* __restrict__ g0, const float* __restrict__ g1,
    const float* __restrict__ feat, const int* __restrict__ start,
    const float* __restrict__ m,
    float* __restrict__ acc0, float* __restrict__ acc1,
    float* __restrict__ sums) {
  int grp = blockIdx.x;
  int s0 = start[grp], s1 = start[grp + 1];
  int len = s1 - s0;
  if (len <= 0) return;
  int NC = gridDim.y;
  int per = (len + NC - 1) / NC;
  int r0 = s0 + blockIdx.y * per;
  int r1 = min(s1, r0 + per);
  if (r0 >= r1) return;
  int t = threadIdx.x;  // 128 = column
  float m0 = m[grp];
  float m1 = (NG == 2) ? m[64 + grp] : 0.f;
  float a0 = 0.f, a1 = 0.f, sum0 = 0.f, sum1 = 0.f;
  for (int i = r0; i < r1; ++i) {
    float f = feat[(size_t)i * CHD + t];
    float e0 = __expf(g0[i] - m0);
    sum0 += e0;
    a0 += e0 * f;
    if (NG == 2) {
      float e1 = __expf(g1[i] - m1);
      sum1 += e1;
      a1 += e1 * f;
    }
  }
  atomicAdd(&acc0[grp * CHD + t], a0);
  if (NG == 2) atomicAdd(&acc1[grp * CHD + t], a1);
  if (t == 0) {
    atomicAdd(&sums[grp], sum0);
    if (NG == 2) atomicAdd(&sums[64 + grp], sum1);
  }
}

// ---------- GAP phase 3: normalize, all 5 jobs in one launch ----------
__global__ void k_gap_norm5(float* __restrict__ glq, const float* __restrict__ sbuf) {
  int job = blockIdx.x >> 6, grp = blockIdx.x & 63;
  int t = threadIdx.x;  // 128
  int smap = (job == 1) ? 2 : ((job == 2) ? 1 : job);
  float sv = sbuf[smap * 64 + grp];
  float* acc = glq + (size_t)job * CB * CHD + grp * CHD;
  float v = acc[t];
  acc[t] = (sv > 0.f) ? v / sv : 0.f;
}

// ---------- small matmul (latency-optimized: 8-way batched loads) ----------
__global__ void k_mm_small(const float* __restrict__ X, const float* __restrict__ W,
                           const float* __restrict__ bias, float* __restrict__ Y,
                           int m, int k, int p) {
  int idx = blockIdx.x * blockDim.x + threadIdx.x;
  if (idx >= m * p) return;
  int r = idx / p, c = idx % p;
  const float* xr = X + (size_t)r * k;
  const float* wc = W + c;
  float acc = bias[c];
  int kk = 0;
  for (; kk + 8 <= k; kk += 8) {
    float xv[8], wv[8];
#pragma unroll
    for (int j = 0; j < 8; ++j) {
      xv[j] = xr[kk + j];
      wv[j] = wc[(size_t)(kk + j) * p];
    }
#pragma unroll
    for (int j = 0; j < 8; ++j) acc += xv[j] * wv[j];
  }
  for (; kk < k; ++kk) acc += xr[kk] * wc[(size_t)kk * p];
  Y[idx] = acc;
}

// ---------- BN+elu small (8-way batched row loads) ----------
__global__ void k_bn_elu_small(float* __restrict__ Y, int m, int p) {
  int c = blockIdx.x * blockDim.x + threadIdx.x;
  if (c >= p) return;
  float s = 0.f, s2 = 0.f;
  int i = 0;
  for (; i + 8 <= m; i += 8) {
    float v[8];
#pragma unroll
    for (int j = 0; j < 8; ++j) v[j] = Y[(size_t)(i + j) * p + c];
#pragma unroll
    for (int j = 0; j < 8; ++j) { s += v[j]; s2 += v[j] * v[j]; }
  }
  for (; i < m; ++i) {
    float v = Y[(size_t)i * p + c];
    s += v; s2 += v * v;
  }
  float mu = s / m;
  float var = s2 / m - mu * mu;
  float inv = rsqrtf(var + CEPS);
  i = 0;
  for (; i + 8 <= m; i += 8) {
    float v[8];
#pragma unroll
    for (int j = 0; j < 8; ++j) v[j] = Y[(size_t)(i + j) * p + c];
#pragma unroll
    for (int j = 0; j < 8; ++j) {
      float x = (v[j] - mu) * inv;
      Y[(size_t)(i + j) * p + c] = x > 0.f ? x : expm1f(x);
    }
  }
  for (; i < m; ++i) {
    float x = (Y[(size_t)i * p + c] - mu) * inv;
    Y[(size_t)i * p + c] = x > 0.f ? x : expm1f(x);
  }
}

// ---------- att_comb ----------
__global__ void k_attcomb(const float* __restrict__ k1, const float* __restrict__ k2,
                          const float* __restrict__ Qc, float* __restrict__ a) {
  int grp = blockIdx.x;
  int t = threadIdx.x;  // 64 threads
  float v1 = Qc[t] * k1[grp * CHD + t] + Qc[t + 64] * k1[grp * CHD + t + 64];
  float v2 = Qc[t] * k2[grp * CHD + t] + Qc[t + 64] * k2[grp * CHD + t + 64];
  for (int off = 32; off > 0; off >>= 1) {
    v1 += __shfl_down(v1, off, 64);
    v2 += __shfl_down(v2, off, 64);
  }
  if (t == 0) {
    float mx = fmaxf(v1, v2);
    float e1 = expf(v1 - mx), e2 = expf(v2 - mx);
    float s = e1 + e2;
    a[grp * 2] = e1 / s;
    a[grp * 2 + 1] = e2 / s;
  }
}

// ---------- WQ precompute ----------
__global__ void k_wq(const float* __restrict__ W_L, const float* __restrict__ b_L,
                     const float* __restrict__ Qm, float* __restrict__ WQ,
                     float* __restrict__ bQ) {
  int g = blockIdx.x;  // 64 blocks, 256 threads
  int t = threadIdx.x;
  for (int j = 0; j < 8; ++j) {
    int idx = t + j * 256;
    int d = idx >> 4, c = idx & 15;
    int h = c & 7, off = (c >= 8) ? CEH : 0;
    const float* w = W_L + d * CHD + h * CEH;
    const float* q = Qm + g * 256 + h * 32 + off;
    float acc = 0.f;
#pragma unroll
    for (int e = 0; e < CEH; ++e) acc += w[e] * q[e];
    WQ[g * 2048 + idx] = acc;
  }
  if (t < 16) {
    int c = t, h = c & 7, off = (c >= 8) ? CEH : 0;
    const float* b = b_L + h * CEH;
    const float* q = Qm + g * 256 + h * 32 + off;
    float acc = 0.f;
#pragma unroll
    for (int e = 0; e < CEH; ++e) acc += b[e] * q[e];
    bQ[g * 16 + c] = acc;
  }
}

// ---------- elr ----------
__global__ void k_eler(const float* __restrict__ tmp, const float* __restrict__ WQ,
                       const float* __restrict__ bQ, const int* __restrict__ gid,
                       float* __restrict__ elr, int n) {
  int idx = blockIdx.x * blockDim.x + threadIdx.x;
  if (idx >= n * 16) return;
  int i = idx >> 4, c = idx & 15;
  int g = gid[i];
  const float* wq = WQ + g * 2048 + c;
  const float* row = tmp + (size_t)i * CHD;
  float acc = bQ[g * 16 + c];
#pragma unroll 4
  for (int d = 0; d < CHD; ++d) acc += row[d] * wq[d * 16];
  elr[idx] = acc;
}

// ---------- global per-head max of el (cols 0..7 of elr) ----------
__global__ void k_elmax(const float* __restrict__ elr, unsigned* __restrict__ mgl, int n) {
  int h = blockIdx.x;      // 0..7
  int chunk = blockIdx.y;  // 0..31
  int per = (n + 31) / 32;
  int i0 = chunk * per, i1 = min(n, i0 + per);
  int t = threadIdx.x;  // 256
  __shared__ float red[256];
  float v = -1e30f;
  for (int i = i0 + t; i < i1; i += 256) v = fmaxf(v, elr[(size_t)i * 16 + h]);
  red[t] = v;
  __syncthreads();
  for (int o = 128; o > 0; o >>= 1) {
    if (t < o) red[t] = fmaxf(red[t], red[t + o]);
    __syncthreads();
  }
  if (t == 0) atomicMax(&mgl[h], fenc(red[0]));
}

// ---------- transpose+cast weights: WT[p][k] = bf16(W[k][p]) ----------
__global__ void k_tcast(const float* __restrict__ W, ushortt* __restrict__ WT,
                        int K, int P) {
  int i = blockIdx.x * blockDim.x + threadIdx.x;
  if (i >= K * P) return;
  int p = i / K, k = i % K;
  stf(&WT[i], W[(size_t)k * P + p]);
}

// ---------- BN prep: stats -> mu / inv ----------
template <int P>
__global__ void k_bn_prep(const float* __restrict__ stats, float* __restrict__ pr, int n) {
  int c = threadIdx.x;
  if (c >= P) return;
  float invn = 1.f / (float)n;
  float mu = stats[c] * invn;
  float var = stats[P + c] * invn - mu * mu;
  pr[c] = mu;
  pr[P + c] = rsqrtf(var + CEPS);
}

// ---------- stats reduce: fold per-wave partials into stats ----------
template <int TP>
__global__ void k_stats_reduce(const float* __restrict__ pstat, float* __restrict__ stats,
                               int nb) {
  int c = blockIdx.x * blockDim.x + threadIdx.x;
  if (c >= TP) return;
  int NC = gridDim.y;
  int per = (nb + NC - 1) / NC;
  int r0 = blockIdx.y * per;
  int r1 = min(nb, r0 + per);
  if (r0 >= r1) return;
  float s0 = 0.f, s1 = 0.f, s2 = 0.f, s3 = 0.f;
  int r = r0;
  for (; r + 4 <= r1; r += 4) {
    s0 += pstat[(size_t)(r + 0) * TP + c];
    s1 += pstat[(size_t)(r + 1) * TP + c];
    s2 += pstat[(size_t)(r + 2) * TP + c];
    s3 += pstat[(size_t)(r + 3) * TP + c];
  }
  for (; r < r1; ++r) s0 += pstat[(size_t)r * TP + c];
  atomicAdd(&stats[c], (s0 + s1) + (s2 + s3));
}

// ---------- MFMA GEMM: Y(nxP) = X(nxK) @ B + bias; BT is PxK bf16 ----------
// XM: 0 = fp32 plain, 1 = fp32 comb (a0*X0 + a1*X1), 2 = bf16 plain,
//     3 = bf16 with fused BN(mu/inv from bnpr[2K])+elu on load
// STATS: per-WAVE column sum/sumsq partials -> pstat[(bid*4+wave)*2P..]
// ROWS: row-fragments per wave (register blocking, shares bfr)
// LDSB: stage BT in LDS with XOR swizzle (for NT=16 VGPR relief)
template <int K, int P, int XM, bool STATS, int ROWS, bool LDSB, typename OT>
__global__ __launch_bounds__(256, 2) void k_gemm_mfma(
    const void* __restrict__ X0v, const void* __restrict__ X1v,
    const float* __restrict__ acomb, const int* __restrict__ gid,
    const float* __restrict__ bnpr, const ushortt* __restrict__ BT,
    const float* __restrict__ bias, OT* __restrict__ Y,
    float* __restrict__ pstat, int n) {
  constexpr int NT = P / 16;
  __shared__ ushortt sB[LDSB ? P * K : 1];        // 64KB for 256x128
  __shared__ float sbn[(XM == 3) ? 2 * K : 1];
  if constexpr (XM == 3) {
    for (int i = threadIdx.x; i < 2 * K; i += 256) sbn[i] = bnpr[i];
  }
  if constexpr (LDSB) {
    // XOR-swizzled stage: granule g of row goes to slot g^(row&7)
    for (int i = threadIdx.x; i < P * (K / 8); i += 256) {
      int row = i / (K / 8), seg = i % (K / 8);
      int sseg = seg ^ (row & 7);
      *(bf16x8*)&sB[row * K + sseg * 8] =
          *(const bf16x8*)(BT + (size_t)row * K + seg * 8);
    }
  }
  if constexpr (XM == 3 || LDSB) __syncthreads();
  const int wave = threadIdx.x >> 6, lane = threadIdx.x & 63;
  const int quad = lane >> 4, l16 = lane & 15;
  const int rbase = blockIdx.x * (64 * ROWS) + wave * 16;
  int rA[ROWS];
  bool rok[ROWS];
  float a0[ROWS], a1[ROWS];
#pragma unroll
  for (int rr = 0; rr < ROWS; ++rr) {
    rA[rr] = rbase + rr * 64 + l16;
    rok[rr] = rA[rr] < n;
    a0[rr] = 0.f; a1[rr] = 0.f;
    if (XM == 1 && rok[rr]) {
      int g = gid[rA[rr]];
      a0[rr] = acomb[2 * g];
      a1[rr] = acomb[2 * g + 1];
    }
  }
  f32x4 acc[ROWS][NT];
#pragma unroll
  for (int rr = 0; rr < ROWS; ++rr)
#pragma unroll
    for (int t = 0; t < NT; ++t) acc[rr][t] = f32x4{0.f, 0.f, 0.f, 0.f};
  for (int k0 = 0; k0 < K; k0 += 32) {
    const int kk = k0 + quad * 8;
    bf16x8 af[ROWS];
#pragma unroll
    for (int rr = 0; rr < ROWS; ++rr) {
      af[rr] = bf16x8{};
      if (rok[rr]) {
        if constexpr (XM == 2) {
          af[rr] = *(const bf16x8*)((const ushortt*)X0v + (size_t)rA[rr] * K + kk);
        } else if constexpr (XM == 3) {
          bf16x8 raw = *(const bf16x8*)((const ushortt*)X0v + (size_t)rA[rr] * K + kk);
#pragma unroll
          for (int j = 0; j < 8; ++j) {
            float v = bf2f(raw[j]);
            v = (v - sbn[kk + j]) * sbn[K + kk + j];
            v = v > 0.f ? v : (__expf(v) - 1.f);
            af[rr][j] = f2bf(v);
          }
        } else {
          const float* px = (const float*)X0v + (size_t)rA[rr] * K + kk;
          float v[8];
          if constexpr (XM == 1) {
            const float* py = (const float*)X1v + (size_t)rA[rr] * K + kk;
#pragma unroll
            for (int j = 0; j < 8; ++j) v[j] = a0[rr] * px[j] + a1[rr] * py[j];
          } else {
#pragma unroll
            for (int j = 0; j < 8; ++j) v[j] = px[j];
          }
#pragma unroll
          for (int j = 0; j < 8; ++j) af[rr][j] = f2bf(v[j]);
        }
      }
    }
    bf16x8 bfr[NT];
#pragma unroll
    for (int t = 0; t < NT; ++t) {
      if constexpr (LDSB) {
        int row = t * 16 + l16;
        int sseg = (kk >> 3) ^ (row & 7);
        bfr[t] = *(const bf16x8*)&sB[row * K + sseg * 8];
      } else {
        bfr[t] = *(const bf16x8*)(BT + (size_t)(t * 16 + l16) * K + kk);
      }
    }
#pragma unroll
    for (int rr = 0; rr < ROWS; ++rr)
#pragma unroll
      for (int t = 0; t < NT; ++t)
        acc[rr][t] = __builtin_amdgcn_mfma_f32_16x16x32_bf16(af[rr], bfr[t], acc[rr][t], 0, 0, 0);
  }
  float* pw = nullptr;
  if constexpr (STATS) pw = pstat + ((size_t)blockIdx.x * 4 + wave) * (2 * P);
#pragma unroll
  for (int t = 0; t < NT; ++t) {
    const int c = t * 16 + l16;
    float b = bias[c];
    float s = 0.f, s2 = 0.f;
#pragma unroll
    for (int rr = 0; rr < ROWS; ++rr) {
#pragma unroll
      for (int r = 0; r < 4; ++r) {
        int gr = rbase + rr * 64 + quad * 4 + r;
        if (gr < n) {
          float val = acc[rr][t][r] + b;
          stf(Y + (size_t)gr * P + c, val);
          if constexpr (STATS) {
            float vq = (sizeof(OT) == 2) ? bf2f(f2bf(val)) : val;
            s += vq;
            s2 += vq * vq;
          }
        }
      }
    }
    if constexpr (STATS) {
      s += __shfl_xor(s, 16, 64);
      s += __shfl_xor(s, 32, 64);
      s2 += __shfl_xor(s2, 16, 64);
      s2 += __shfl_xor(s2, 32, 64);
      if (quad == 0) {
        pw[c] = s;
        pw[P + c] = s2;
      }
    }
  }
}

// ---------- CSR build ----------
__global__ void k_count(const int* __restrict__ dst, int* __restrict__ counts, int E) {
  int e = blockIdx.x * blockDim.x + threadIdx.x;
  if (e < E) atomicAdd(&counts[dst[e]], 1);
}
__global__ void k_scan_reduce(const int* __restrict__ counts, int* __restrict__ bsum, int n) {
  __shared__ int red[256];
  int t = threadIdx.x;
  int base = blockIdx.x * 1024;
  int s = 0;
  for (int j = 0; j < 4; ++j) {
    int i = base + t * 4 + j;
    if (i < n) s += counts[i];
  }
  red[t] = s;
  __syncthreads();
  for (int o = 128; o > 0; o >>= 1) {
    if (t < o) red[t] += red[t + o];
    __syncthreads();
  }
  if (t == 0) bsum[blockIdx.x] = red[0];
}
__global__ void k_scan_top(int* __restrict__ bsum, int nb) {
  __shared__ int sh[128];
  int t = threadIdx.x;  // 128 threads
  int v = (t < nb) ? bsum[t] : 0;
  sh[t] = v;
  __syncthreads();
  for (int o = 1; o < 128; o <<= 1) {
    int x = (t >= o) ? sh[t - o] : 0;
    __syncthreads();
    sh[t] += x;
    __syncthreads();
  }
  if (t < nb) bsum[t] = sh[t] - v;  // exclusive
}
__global__ void k_scan_final(const int* __restrict__ counts, const int* __restrict__ bsum,
                             int* __restrict__ rowptr, int n, int E) {
  __shared__ int sh[256];
  int t = threadIdx.x;
  int base = blockIdx.x * 1024;
  int v[4];
  int s = 0;
  for (int j = 0; j < 4; ++j) {
    int i = base + t * 4 + j;
    v[j] = (i < n) ? counts[i] : 0;
    s += v[j];
  }
  sh[t] = s;
  __syncthreads();
  for (int o = 1; o < 256; o <<= 1) {
    int x = (t >= o) ? sh[t - o] : 0;
    __syncthreads();
    sh[t] += x;
    __syncthreads();
  }
  int off = bsum[blockIdx.x] + sh[t] - s;
  for (int j = 0; j < 4; ++j) {
    int i = base + t * 4 + j;
    if (i < n) rowptr[i] = off;
    off += v[j];
  }
  if (blockIdx.x == 0 && t == 0) rowptr[n] = E;
}
__global__ void k_copy_int(const int* __restrict__ a, int* __restrict__ b, int n) {
  int i = blockIdx.x * blockDim.x + threadIdx.x;
  if (i < n) b[i] = a[i];
}
__global__ void k_scatter(const int* __restrict__ dst, const int* __restrict__ srcA,
                          int* __restrict__ cursor, int* __restrict__ csr_src, int E) {
  int e = blockIdx.x * blockDim.x + threadIdx.x;
  if (e >= E) return;
  int d = dst[e];
  int pos = atomicAdd(&cursor[d], 1);
  csr_src[pos] = srcA[e];
}

// ---------- fused softmax aggregation v3: one wave per node ----------
__global__ __launch_bounds__(256) void k_node_agg(
    const int* __restrict__ rowptr, const int* __restrict__ csr_src,
    const float* __restrict__ elr, const unsigned* __restrict__ mgl,
    const ushortt* __restrict__ ft,
    float* __restrict__ agg, float* __restrict__ mOut, float* __restrict__ sOut, int n) {
  int node = blockIdx.x * 4 + (threadIdx.x >> 6);
  if (node >= n) return;
  int lane = threadIdx.x & 63;
  int h_p = lane & 7;    // head for p-compute role
  int e_loc = lane >> 3; // edge slot (0..7)
  int h_a = lane >> 3;   // head for accumulation role (cols 2*lane, 2*lane+1)
  int s0 = rowptr[node], s1 = rowptr[node + 1];
  if (s1 <= s0) {
    *(float2*)(agg + (size_t)node * CHD + lane * 2) = make_float2(0.f, 0.f);
    if (lane < 8) {
      mOut[(size_t)node * CH + lane] = -1e30f;
      sOut[(size_t)node * CH + lane] = 0.f;
    }
    return;
  }
  float erd_p = elr[(size_t)node * 16 + 8 + h_p];
  float xm = fdec(mgl[h_p]) + erd_p;
  float m_p = xm >= 0.f ? xm : CSLOPE * xm;  // upper bound on leaky(x) over edges
  float s_part = 0.f, a0 = 0.f, a1 = 0.f;
  for (int base = s0; base < s1; base += 8) {
    int cnt = s1 - base;
    int sj = 0;
    float p = 0.f;
    if (e_loc < cnt) {
      sj = csr_src[base + e_loc];
      float x = elr[(size_t)sj * 16 + h_p] + erd_p;
      x = x >= 0.f ? x : CSLOPE * x;
      p = __expf(x - m_p);
      s_part += p;
    }
#pragma unroll
    for (int e = 0; e < 8; ++e) {
      float pe = __shfl(p, e * 8 + h_a, 64);
      int se = __shfl(sj, e * 8, 64);
      unsigned ftv = *(const unsigned*)(ft + (size_t)se * CHD + lane * 2);
      a0 += pe * __uint_as_float(ftv << 16);
      a1 += pe * __uint_as_float(ftv & 0xffff0000u);
    }
  }
  s_part += __shfl_xor(s_part, 8, 64);
  s_part += __shfl_xor(s_part, 16, 64);
  s_part += __shfl_xor(s_part, 32, 64);
  float s_acc = __shfl(s_part, h_a, 64);  // lane h_a holds head h_p == h_a
  float inv = 1.f / s_acc;
  float2 o;
  o.x = a0 * inv;
  o.y = a1 * inv;
  *(float2*)(agg + (size_t)node * CHD + lane * 2) = o;
  if (lane < 8) {
    mOut[(size_t)node * CH + lane] = m_p;
    sOut[(size_t)node * CH + lane] = s_part;
  }
}

// ---------- BN apply + elu + residual, float4-vectorized (P=128) ----------
__global__ void k_bn_apply_f4(float* __restrict__ Y, const float* __restrict__ stats,
                              const float* __restrict__ hlast, int n) {
  int idx = blockIdx.x * blockDim.x + threadIdx.x;
  if (idx >= n * 32) return;  // 32 float4 groups per row
  int cg = (idx & 31) * 4;
  float invn = 1.f / (float)n;
  float4 y = ((const float4*)Y)[idx];
  float4 hl = ((const float4*)hlast)[idx];
  float yy[4] = {y.x, y.y, y.z, y.w};
  float hh[4] = {hl.x, hl.y, hl.z, hl.w};
  float o[4];
#pragma unroll
  for (int j = 0; j < 4; ++j) {
    float mu = stats[cg + j] * invn;
    float var = stats[128 + cg + j] * invn - mu * mu;
    float v = (yy[j] - mu) * rsqrtf(var + CEPS);
    v = v > 0.f ? v : (__expf(v) - 1.f);
    o[j] = v + hh[j];
  }
  ((float4*)Y)[idx] = make_float4(o[0], o[1], o[2], o[3]);
}

// ---------- attention recompute for loss ----------
__device__ __forceinline__ float attn_val(int e, int h, const int* __restrict__ src,
                                          const int* __restrict__ dst,
                                          const float* __restrict__ elr,
                                          const float* __restrict__ mOut,
                                          const float* __restrict__ sOut) {
  int ss = src[e], sd = dst[e];
  float x = elr[(size_t)ss * 16 + h] + elr[(size_t)sd * 16 + 8 + h];
  x = x >= 0.f ? x : CSLOPE * x;
  return __expf(x - mOut[(size_t)sd * CH + h]) / sOut[(size_t)sd * CH + h];
}

// per-block partials (no global atomics)
__global__ void k_pd(const int* __restrict__ src, const int* __restrict__ dst,
                     const float* __restrict__ elr, const float* __restrict__ mOut,
                     const float* __restrict__ sOut, const int* __restrict__ PEid,
                     const int* __restrict__ DEid, float* __restrict__ pdp,
                     int nPE, int nDE) {
  __shared__ float part[CH];
  if (threadIdx.x < CH) part[threadIdx.x] = 0.f;
  __syncthreads();
  int idx = blockIdx.x * blockDim.x + threadIdx.x;
  int j = idx >> 3, h = idx & 7;
  float acc = 0.f;
  if (j < nPE) acc += attn_val(PEid[j], h, src, dst, elr, mOut, sOut);
  if (j < nDE) acc -= attn_val(DEid[j], h, src, dst, elr, mOut, sOut);
  atomicAdd(&part[h], acc);
  __syncthreads();
  if (threadIdx.x < CH) pdp[(size_t)blockIdx.x * CH + threadIdx.x] = part[threadIdx.x];
}
__global__ void k_loss(const float* __restrict__ pdp, int nb,
                       const int* __restrict__ lenMn, float* __restrict__ out) {
  __shared__ float part[CH];
  int t = threadIdx.x;  // 256
  if (t < CH) part[t] = 0.f;
  __syncthreads();
  int h = t & 7;
  float acc = 0.f;
  for (int j = t >> 3; j < nb; j += 32) acc += pdp[(size_t)j * CH + h];
  atomicAdd(&part[h], acc);
  __syncthreads();
  if (t == 0) {
    float len = (float)lenMn[0];
    float s = 0.f;
    for (int hh = 0; hh < CH; ++hh) s += part[hh] / len;
    out[0] = -s / (float)CH;
  }
}

// ---------- branch driver ----------
static void run_branch(int n, int E, const float* h_last, const float* h0,
                       const int* src, const int* dst, const int* gid,
                       const float* acomb, const float* WQ, const float* bQ,
                       const ushortt* W_LT, const float* b_L,
                       const ushortt* W1T, const float* end_b1,
                       const ushortt* W2T, const float* end_b2,
                       float* U, float* elr, unsigned* mgl, float* mOut, float* sOut,
                       int* counts, int* rowptr, int* cursor, int* csr_src, int* bsum,
                       float* stats /*1024: [0..511]=BN256, [512..1023]=BN128*/,
                       float* bnpr /*512*/, float* pstat, float* out, hipStream_t stream) {
  ushortt* ftB = (ushortt*)U;   // n x 128 bf16
  ushortt* y1B = (ushortt*)U;   // n x 256 bf16 (ft dead by then)
  float* stats1 = stats;
  float* stats2 = stats + 512;
  int nChunks = (n + 1023) / 1024;
  int nbG1 = (n + 127) / 128;   // ROWS=2 grids
  int nbG2 = (n + 63) / 64;     // ROWS=1 grid (gemm2)
  // CSR build
  zero_launch(counts, n, stream);
  zero_launch(stats, 1024, stream);
  zero_launch(mgl, 8, stream);
  hipLaunchKernelGGL(k_count, dim3((E + 255) / 256), dim3(256), 0, stream, dst, counts, E);
  hipLaunchKernelGGL(k_scan_reduce, dim3(nChunks), dim3(256), 0, stream, counts, bsum, n);
  hipLaunchKernelGGL(k_scan_top, dim3(1), dim3(128), 0, stream, bsum, nChunks);
  hipLaunchKernelGGL(k_scan_final, dim3(nChunks), dim3(256), 0, stream, counts, bsum, rowptr, n, E);
  hipLaunchKernelGGL(k_copy_int, dim3((n + 255) / 256), dim3(256), 0, stream, rowptr, cursor, n);
  hipLaunchKernelGGL(k_scatter, dim3((E + 255) / 256), dim3(256), 0, stream, dst, src, cursor, csr_src, E);
  // elr + global per-head el max
  hipLaunchKernelGGL(k_eler, dim3((n * 16 + 255) / 256), dim3(256), 0, stream,
                     h_last, WQ, bQ, gid, elr, n);
  hipLaunchKernelGGL(k_elmax, dim3(8, 32), dim3(256), 0, stream, elr, mgl, n);
  // ft = (a0*h0 + a1*h_last) @ W_L + b_L -> bf16  (ROWS=2)
  hipLaunchKernelGGL((k_gemm_mfma<128, 128, 1, false, 2, false, ushortt>), dim3(nbG1),
                     dim3(256), 0, stream, h0, h_last, acomb, gid,
                     (const float*)nullptr, W_LT, b_L, ftB, (float*)nullptr, n);
  // fused softmax aggregation
  hipLaunchKernelGGL(k_node_agg, dim3((n + 3) / 4), dim3(256), 0, stream,
                     rowptr, csr_src, elr, mgl, ftB, out, mOut, sOut, n);
  // end FNN layer 1 (NT=16: LDS-staged B; per-wave stats partials)
  hipLaunchKernelGGL((k_gemm_mfma<128, 256, 0, true, 1, true, ushortt>), dim3(nbG2),
                     dim3(256), 0, stream, out, (const void*)nullptr,
                     (const float*)nullptr, (const int*)nullptr,
                     (const float*)nullptr, W1T, end_b1, y1B, pstat, n);
  hipLaunchKernelGGL((k_stats_reduce<512>), dim3(2, 64), dim3(256), 0, stream,
                     pstat, stats1, nbG2 * 4);
  hipLaunchKernelGGL((k_bn_prep<256>), dim3(1), dim3(256), 0, stream, stats1, bnpr, n);
  // layer 2 with fused BN+elu on load (LDS bn params, ROWS=2)
  hipLaunchKernelGGL((k_gemm_mfma<256, 128, 3, true, 2, false, float>), dim3(nbG1),
                     dim3(256), 0, stream, y1B, (const void*)nullptr,
                     (const float*)nullptr, (const int*)nullptr,
                     bnpr, W2T, end_b2, out, pstat, n);
  hipLaunchKernelGGL((k_stats_reduce<256>), dim3(1, 64), dim3(256), 0, stream,
                     pstat, stats2, nbG1 * 4);
  hipLaunchKernelGGL(k_bn_apply_f4, dim3((n * 32 + 255) / 256), dim3(256), 0, stream,
                     out, stats2, h_last, n);
}

extern "C" void kernel_launch(void* const* d_in, const int* in_sizes, int n_in,
                              void* d_out, int out_size, void* d_ws, size_t ws_size,
                              hipStream_t stream) {
  const float* h_da_last = (const float*)d_in[0];
  const float* h_q_last  = (const float*)d_in[1];
  const float* h_da_0    = (const float*)d_in[2];
  const float* h_q_0     = (const float*)d_in[3];
  const float* W_L       = (const float*)d_in[4];
  const float* b_L       = (const float*)d_in[5];
  const float* gateq_W   = (const float*)d_in[6];
  const float* gateq_b   = (const float*)d_in[7];
  const float* gate1_W   = (const float*)d_in[8];
  const float* gate1_b   = (const float*)d_in[9];
  const float* gate2_W   = (const float*)d_in[10];
  const float* gate2_b   = (const float*)d_in[11];
  const float* Q_comb    = (const float*)d_in[12];
  const float* Qf_W1     = (const float*)d_in[13];
  const float* Qf_b1     = (const float*)d_in[14];
  const float* Qf_W2     = (const float*)d_in[15];
  const float* Qf_b2     = (const float*)d_in[16];
  const float* end_W1    = (const float*)d_in[17];
  const float* end_b1    = (const float*)d_in[18];
  const float* end_W2    = (const float*)d_in[19];
  const float* end_b2    = (const float*)d_in[20];
  const int* src_da = (const int*)d_in[21];
  const int* dst_da = (const int*)d_in[22];
  const int* src_q  = (const int*)d_in[23];
  const int* dst_q  = (const int*)d_in[24];
  const int* gid_da = (const int*)d_in[25];
  const int* gid_q  = (const int*)d_in[26];
  const int* PEid   = (const int*)d_in[27];
  const int* DEid   = (const int*)d_in[28];
  const int* len_Mn = (const int*)d_in[29];

  float* out_da   = (float*)d_out;
  float* out_q    = (float*)d_out + (size_t)CNDA * CHD;
  float* out_loss = (float*)d_out + (size_t)CNDA * CHD + (size_t)CNQ * CHD;

  // ---- workspace arena (float units), ~84 MB ----
  float* ws = (float*)d_ws;
  size_t off = 0;
  auto alloc = [&](size_t cnt) { float* p = ws + off; off += cnt; return p; };
  float* U    = alloc((size_t)CNDA * 128);   // ft bf16 n*128 / y1 bf16 n*256 union
  float* elr  = alloc((size_t)CNDA * 16);
  float* mOut = alloc((size_t)CNDA * CH);
  float* sOut = alloc((size_t)CNDA * CH);
  int* counts  = (int*)alloc(CNDA);
  int* rowptr  = (int*)alloc(CNDA + 4);
  int* cursor  = (int*)alloc(CNDA);
  int* csr_src = (int*)alloc(CEDA);
  int* bsum    = (int*)alloc(128);
  ushortt* W_LT = (ushortt*)alloc(128 * 128 / 2);
  ushortt* W1T  = (ushortt*)alloc(128 * 256 / 2);
  ushortt* W2T  = (ushortt*)alloc(256 * 128 / 2);
  float* WQ   = alloc((size_t)CB * 2048);
  float* bQ   = alloc((size_t)CB * 16);
  // NOTE: gq..g2da must stay consecutive (k_gmax5 indexes off gq)
  float* gq   = alloc(CNQ);
  float* g1q  = alloc(CNQ);
  float* g2q  = alloc(CNQ);
  float* g1da = alloc(CNDA);
  float* g2da = alloc(CNDA);
  // NOTE: glq..k2da must stay consecutive (zeroed as one region; k_gap_norm5)
  float* glq  = alloc(CB * CHD);
  float* k1q  = alloc(CB * CHD);
  float* k2q  = alloc(CB * CHD);
  float* k1da = alloc(CB * CHD);
  float* k2da = alloc(CB * CHD);
  float* Qt   = alloc(CB * 256);
  float* Qm   = alloc(CB * 256);
  float* acq  = alloc(CB * 2);
  float* acda = alloc(CB * 2);
  float* stats = alloc(1024);     // [0..511] BN256 stats, [512..1023] BN128 stats
  float* bnpr  = alloc(512);      // mu/inv for BN256
  unsigned* mgl = (unsigned*)alloc(8);  // encoded global per-head el max
  float* mbuf  = alloc(5 * 64);   // [gq, g2q, g1q, g1da, g2da]
  float* sbuf  = alloc(5 * 64);   // same order
  int* startq  = (int*)alloc(68);
  int* startda = (int*)alloc(68);
  float* pstat = alloc(((size_t)(CNDA + 63) / 64) * 4 * 512);  // per-WAVE stats partials
  float* pdp   = alloc(((size_t)CNDA * CH + 255) / 256 * CH);  // k_pd partials
  (void)ws_size; (void)n_in; (void)out_size;

  // ---- weight transposes (bf16) ----
  hipLaunchKernelGGL(k_tcast, dim3((128 * 128 + 255) / 256), dim3(256), 0, stream, W_L, W_LT, 128, 128);
  hipLaunchKernelGGL(k_tcast, dim3((128 * 256 + 255) / 256), dim3(256), 0, stream, end_W1, W1T, 128, 256);
  hipLaunchKernelGGL(k_tcast, dim3((256 * 128 + 255) / 256), dim3(256), 0, stream, end_W2, W2T, 256, 128);

  // ---- group boundaries ----
  hipLaunchKernelGGL(k_binit, dim3(1), dim3(128), 0, stream, startq, CNQ);
  hipLaunchKernelGGL(k_binit, dim3(1), dim3(128), 0, stream, startda, CNDA);
  hipLaunchKernelGGL(k_bmark, dim3((CNQ + 255) / 256), dim3(256), 0, stream, gid_q, CNQ, startq);
  hipLaunchKernelGGL(k_bmark, dim3((CNDA + 255) / 256), dim3(256), 0, stream, gid_da, CNDA, startda);
  hipLaunchKernelGGL(k_bfix, dim3(1), dim3(64), 0, stream, startq);
  hipLaunchKernelGGL(k_bfix, dim3(1), dim3(64), 0, stream, startda);

  // ---- gate dots ----
  hipLaunchKernelGGL(k_gate_dot2, dim3((CNQ + 3) / 4), dim3(256), 0, stream,
                     h_q_last, gateq_W, gateq_b, gate2_W, gate2_b, gq, g2q, CNQ);
  hipLaunchKernelGGL(k_gate_dot, dim3((CNQ + 3) / 4), dim3(256), 0, stream, h_q_0, gate1_W, gate1_b, g1q, CNQ);
  hipLaunchKernelGGL(k_gate_dot, dim3((CNDA + 3) / 4), dim3(256), 0, stream, h_da_0, gate1_W, gate1_b, g1da, CNDA);
  hipLaunchKernelGGL(k_gate_dot, dim3((CNDA + 3) / 4), dim3(256), 0, stream, h_da_last, gate2_W, gate2_b, g2da, CNDA);

  // ---- GAPs (parallel 3-phase segmented softmax-pool) ----
  hipLaunchKernelGGL(k_gmax5, dim3(5 * CB), dim3(256), 0, stream, gq, startq, startda, mbuf);
  zero_launch(glq, 5 * (size_t)CB * CHD, stream);
  zero_launch(sbuf, 5 * 64, stream);
  hipLaunchKernelGGL((k_gap_partial<2>), dim3(CB, 32), dim3(128), 0, stream,
                     gq, g2q, h_q_last, startq, mbuf + 0, glq, k2q, sbuf + 0);
  hipLaunchKernelGGL((k_gap_partial<1>), dim3(CB, 32), dim3(128), 0, stream,
                     g1q, (const float*)nullptr, h_q_0, startq, mbuf + 128,
                     k1q, (float*)nullptr, sbuf + 128);
  hipLaunchKernelGGL((k_gap_partial<1>), dim3(CB, 32), dim3(128), 0, stream,
                     g1da, (const float*)nullptr, h_da_0, startda, mbuf + 192,
                     k1da, (float*)nullptr, sbuf + 192);
  hipLaunchKernelGGL((k_gap_partial<1>), dim3(CB, 32), dim3(128), 0, stream,
                     g2da, (const float*)nullptr, h_da_last, startda, mbuf + 256,
                     k2da, (float*)nullptr, sbuf + 256);
  hipLaunchKernelGGL(k_gap_norm5, dim3(5 * CB), dim3(128), 0, stream, glq, sbuf);

  // ---- Q = fnn(glq) ----
  hipLaunchKernelGGL(k_mm_small, dim3((CB * 256 + 255) / 256), dim3(256), 0, stream,
                     glq, Qf_W1, Qf_b1, Qt, CB, 128, 256);
  hipLaunchKernelGGL(k_bn_elu_small, dim3(1), dim3(256), 0, stream, Qt, CB, 256);
  hipLaunchKernelGGL(k_mm_small, dim3((CB * 256 + 255) / 256), dim3(256), 0, stream,
                     Qt, Qf_W2, Qf_b2, Qm, CB, 256, 256);
  hipLaunchKernelGGL(k_bn_elu_small, dim3(1), dim3(256), 0, stream, Qm, CB, 256);

  // ---- projected per-group Q matrices ----
  hipLaunchKernelGGL(k_wq, dim3(CB), dim3(256), 0, stream, W_L, b_L, Qm, WQ, bQ);

  // ---- att_comb scalars ----
  hipLaunchKernelGGL(k_attcomb, dim3(CB), dim3(64), 0, stream, k1q, k2q, Q_comb, acq);
  hipLaunchKernelGGL(k_attcomb, dim3(CB), dim3(64), 0, stream, k1da, k2da, Q_comb, acda);

  // ---- q branch ----
  run_branch(CNQ, CEQ, h_q_last, h_q_0, src_q, dst_q, gid_q, acq, WQ, bQ,
             W_LT, b_L, W1T, end_b1, W2T, end_b2,
             U, elr, mgl, mOut, sOut, counts, rowptr, cursor, csr_src, bsum,
             stats, bnpr, pstat, out_q, stream);

  // ---- da branch (elr/mOut/sOut end holding da state for the loss) ----
  run_branch(CNDA, CEDA, h_da_last, h_da_0, src_da, dst_da, gid_da, acda, WQ, bQ,
             W_LT, b_L, W1T, end_b1, W2T, end_b2,
             U, elr, mgl, mOut, sOut, counts, rowptr, cursor, csr_src, bsum,
             stats, bnpr, pstat, out_da, stream);

  // ---- loss from recomputed a_da ----
  int nPE = in_sizes[27], nDE = in_sizes[28];
  int nMax = nPE > nDE ? nPE : nDE;
  int nbPD = (nMax * CH + 255) / 256;
  hipLaunchKernelGGL(k_pd, dim3(nbPD), dim3(256), 0, stream,
                     src_da, dst_da, elr, mOut, sOut, PEid, DEid, pdp, nPE, nDE);
  hipLaunchKernelGGL(k_loss, dim3(1), dim3(256), 0, stream, pdp, nbPD, len_Mn, out_loss);
}